// Round 1
// baseline (2121.731 us; speedup 1.0000x reference)
//
#include <hip/hip_runtime.h>
#include <math.h>

// ---------------- device helpers ----------------
__device__ __forceinline__ float lrelu(float x) { return x >= 0.f ? x : 0.2f * x; }
__device__ __forceinline__ float eluf(float x)  { return x > 0.f ? x : __expf(x) - 1.f; }

// ---------------- CSR build ----------------
__global__ void k_deg(const int* __restrict__ dst, int* __restrict__ deg, int E) {
    int e = blockIdx.x * 256 + threadIdx.x;
    if (e < E) atomicAdd(&deg[dst[e]], 1);
}

// single-block scan over N (~100k) elements; writes offs[N+1] and cursor[N]
__global__ void k_scan(const int* __restrict__ deg, int* __restrict__ offs,
                       int* __restrict__ cursor, int N) {
    __shared__ int sm[1024];
    int t = threadIdx.x;
    int chunk = (N + 1023) >> 10;
    int s = t * chunk, e = min(s + chunk, N);
    int sum = 0;
    for (int i = s; i < e; ++i) sum += deg[i];
    sm[t] = sum;
    __syncthreads();
    for (int d = 1; d < 1024; d <<= 1) {
        int v = (t >= d) ? sm[t - d] : 0;
        __syncthreads();
        sm[t] += v;
        __syncthreads();
    }
    int pref = (t == 0) ? 0 : sm[t - 1];
    for (int i = s; i < e; ++i) {
        offs[i] = pref; cursor[i] = pref;
        pref += deg[i];
    }
    if (t == 1023) offs[N] = sm[1023];
}

__global__ void k_scatter(const int* __restrict__ src, const int* __restrict__ dst,
                          int* __restrict__ cur, int* __restrict__ csr, int E) {
    int e = blockIdx.x * 256 + threadIdx.x;
    if (e < E) {
        int p = atomicAdd(&cur[dst[e]], 1);
        csr[p] = src[e];
    }
}

// ---------------- GEMM + attention-score epilogues ----------------
// L1: x[N,21] @ w[21,256] -> h[N,256]; as/ad per (node, head) via 64-lane reduce
__global__ void k_gemm1(const float* __restrict__ x, const float* __restrict__ w,
                        const float* __restrict__ aw_s, const float* __restrict__ aw_d,
                        float* __restrict__ h, float* __restrict__ asb, float* __restrict__ adb,
                        int N) {
    int tid = threadIdx.x;
    int row0 = blockIdx.x * 8;
    __shared__ float xs[8][21];
    int nrows = min(8, N - row0);
    for (int i = tid; i < nrows * 21; i += 256) xs[i / 21][i % 21] = x[row0 * 21 + i];
    __syncthreads();
    float wreg[21];
#pragma unroll
    for (int k = 0; k < 21; ++k) wreg[k] = w[k * 256 + tid];
    float avs = aw_s[tid], avd = aw_d[tid];
    int head = tid >> 6;
    for (int r = 0; r < nrows; ++r) {
        float acc = 0.f;
#pragma unroll
        for (int k = 0; k < 21; ++k) acc = fmaf(xs[r][k], wreg[k], acc);
        h[(size_t)(row0 + r) * 256 + tid] = acc;
        float s1 = acc * avs, s2 = acc * avd;
#pragma unroll
        for (int m = 32; m; m >>= 1) { s1 += __shfl_xor(s1, m); s2 += __shfl_xor(s2, m); }
        if ((tid & 63) == 0) {
            asb[(row0 + r) * 4 + head] = s1;
            adb[(row0 + r) * 4 + head] = s2;
        }
    }
}

// L2: in[N,256] @ w[256,256] -> h[N,256]; 16 rows per block
__global__ void k_gemm2(const float* __restrict__ in, const float* __restrict__ w,
                        const float* __restrict__ aw_s, const float* __restrict__ aw_d,
                        float* __restrict__ h, float* __restrict__ asb, float* __restrict__ adb,
                        int N) {
    int tid = threadIdx.x;
    int row0 = blockIdx.x * 16;
    __shared__ __align__(16) float hs[16][256];
    int nrows = min(16, N - row0);
    for (int r = 0; r < nrows; ++r) hs[r][tid] = in[(size_t)(row0 + r) * 256 + tid];
    __syncthreads();
    float acc[16];
#pragma unroll
    for (int r = 0; r < 16; ++r) acc[r] = 0.f;
    for (int k = 0; k < 256; k += 4) {
        float w0 = w[(k + 0) * 256 + tid];
        float w1 = w[(k + 1) * 256 + tid];
        float w2 = w[(k + 2) * 256 + tid];
        float w3 = w[(k + 3) * 256 + tid];
#pragma unroll
        for (int r = 0; r < 16; ++r) {
            const float4 hv = *reinterpret_cast<const float4*>(&hs[r][k]);
            acc[r] = fmaf(hv.x, w0, fmaf(hv.y, w1, fmaf(hv.z, w2, fmaf(hv.w, w3, acc[r]))));
        }
    }
    float avs = aw_s[tid], avd = aw_d[tid];
    int head = tid >> 6;
    for (int r = 0; r < nrows; ++r) {
        h[(size_t)(row0 + r) * 256 + tid] = acc[r];
        float s1 = acc[r] * avs, s2 = acc[r] * avd;
#pragma unroll
        for (int m = 32; m; m >>= 1) { s1 += __shfl_xor(s1, m); s2 += __shfl_xor(s2, m); }
        if ((tid & 63) == 0) {
            asb[(row0 + r) * 4 + head] = s1;
            adb[(row0 + r) * 4 + head] = s2;
        }
    }
}

// L3: in[N,256] @ w[256,32] -> h[N,32]; 8 rows per block, 32 lanes per row; 1 head
__global__ void k_gemm3(const float* __restrict__ in, const float* __restrict__ w,
                        const float* __restrict__ aw_s, const float* __restrict__ aw_d,
                        float* __restrict__ h, float* __restrict__ asb, float* __restrict__ adb,
                        int N) {
    int tid = threadIdx.x;
    int row0 = blockIdx.x * 8;
    int r = tid >> 5, c = tid & 31;
    __shared__ __align__(16) float hs[8][256];
    for (int rr = 0; rr < 8; ++rr)
        if (row0 + rr < N) hs[rr][tid] = in[(size_t)(row0 + rr) * 256 + tid];
    __syncthreads();
    float acc = 0.f;
    for (int k = 0; k < 256; k += 4) {
        const float4 hv = *reinterpret_cast<const float4*>(&hs[r][k]);
        acc = fmaf(hv.x, w[(k + 0) * 32 + c],
              fmaf(hv.y, w[(k + 1) * 32 + c],
              fmaf(hv.z, w[(k + 2) * 32 + c],
              fmaf(hv.w, w[(k + 3) * 32 + c], acc))));
    }
    int row = row0 + r;
    if (row < N) {
        h[(size_t)row * 32 + c] = acc;
        float s1 = acc * aw_s[c], s2 = acc * aw_d[c];
#pragma unroll
        for (int m = 16; m; m >>= 1) { s1 += __shfl_xor(s1, m); s2 += __shfl_xor(s2, m); }
        if (c == 0) { asb[row] = s1; adb[row] = s2; }
    }
}

// ---------------- gather (attention aggregate), F=256, 4 heads ----------------
__global__ void k_gather256(const float* __restrict__ h, const float* __restrict__ asb,
                            const float* __restrict__ adb, const int* __restrict__ offs,
                            const int* __restrict__ csr, const float* __restrict__ bias,
                            float* __restrict__ out, int N) {
    int v = blockIdx.x;
    int tid = threadIdx.x;
    int head = tid >> 6;
    float ad = adb[v * 4 + head];
    // self loop
    float s0 = asb[v * 4 + head] + ad;
    float w0 = __expf(lrelu(s0));
    float den = w0;
    float acc = w0 * h[(size_t)v * 256 + tid];
    int beg = offs[v], end = offs[v + 1];
    for (int e = beg; e < end; ++e) {
        int u = csr[e];
        float su = asb[u * 4 + head] + ad;
        float wu = __expf(lrelu(su));
        den += wu;
        acc = fmaf(wu, h[(size_t)u * 256 + tid], acc);
    }
    float o = acc / (den + 1e-16f) + bias[tid];
    out[(size_t)v * 256 + tid] = eluf(o);
}

// ---------------- gather, F=32, 1 head; 8 nodes per 256-thread block ----------------
__global__ void k_gather32(const float* __restrict__ h, const float* __restrict__ asb,
                           const float* __restrict__ adb, const int* __restrict__ offs,
                           const int* __restrict__ csr, const float* __restrict__ bias,
                           float* __restrict__ out, int N) {
    int tid = threadIdx.x;
    int v = blockIdx.x * 8 + (tid >> 5);
    int c = tid & 31;
    if (v >= N) return;
    float ad = adb[v];
    float s0 = asb[v] + ad;
    float w0 = __expf(lrelu(s0));
    float den = w0;
    float acc = w0 * h[(size_t)v * 32 + c];
    int beg = offs[v], end = offs[v + 1];
    for (int e = beg; e < end; ++e) {
        int u = csr[e];
        float wu = __expf(lrelu(asb[u] + ad));
        den += wu;
        acc = fmaf(wu, h[(size_t)u * 32 + c], acc);
    }
    float o = acc / (den + 1e-16f) + bias[c];
    out[(size_t)v * 32 + c] = eluf(o);
}

// ---------------- global mean pool (atomic accumulate) ----------------
__global__ void k_pool(const float* __restrict__ h, const int* __restrict__ batch,
                       float* __restrict__ pool, float* __restrict__ cnt, int N) {
    int i = blockIdx.x * 256 + threadIdx.x;
    if (i >= N * 32) return;
    int node = i >> 5, f = i & 31;
    int b = batch[node];
    atomicAdd(&pool[b * 32 + f], h[i]);
    if (f == 0) atomicAdd(&cnt[b], 1.0f);
}

// ---------------- MLP head: one thread per graph ----------------
__global__ void k_head(const float* __restrict__ pool, const float* __restrict__ cnt,
                       const float* __restrict__ fw1, const float* __restrict__ fb1,
                       const float* __restrict__ fw2, const float* __restrict__ fb2,
                       const float* __restrict__ fw3, const float* __restrict__ fb3,
                       float* __restrict__ out, int G) {
    int g = threadIdx.x;
    if (g >= G) return;
    float inv = 1.f / fmaxf(cnt[g], 1.f);
    float p[32];
    for (int k = 0; k < 32; ++k) p[k] = pool[g * 32 + k] * inv;
    float t1[64];
    for (int j = 0; j < 64; ++j) {
        float a = fb1[j];
        for (int k = 0; k < 32; ++k) a = fmaf(p[k], fw1[k * 64 + j], a);
        t1[j] = fmaxf(a, 0.f);
    }
    float t2[32];
    for (int j = 0; j < 32; ++j) {
        float a = fb2[j];
        for (int k = 0; k < 64; ++k) a = fmaf(t1[k], fw2[k * 32 + j], a);
        t2[j] = fmaxf(a, 0.f);
    }
    float o = fb3[0];
    for (int k = 0; k < 32; ++k) o = fmaf(t2[k], fw3[k], o);
    out[g] = 1.f / (1.f + __expf(-o));
}

// ---------------- host ----------------
extern "C" void kernel_launch(void* const* d_in, const int* in_sizes, int n_in,
                              void* d_out, int out_size, void* d_ws, size_t ws_size,
                              hipStream_t stream) {
    const float* x    = (const float*)d_in[0];
    const int*   ei   = (const int*)d_in[1];   // [2,E]: row0 = src, row1 = dst
    const int*   batch= (const int*)d_in[2];
    const float* w1   = (const float*)d_in[3];
    const float* as1  = (const float*)d_in[4];
    const float* ad1  = (const float*)d_in[5];
    const float* b1   = (const float*)d_in[6];
    const float* w2   = (const float*)d_in[7];
    const float* as2  = (const float*)d_in[8];
    const float* ad2  = (const float*)d_in[9];
    const float* b2   = (const float*)d_in[10];
    const float* w3   = (const float*)d_in[11];
    const float* as3  = (const float*)d_in[12];
    const float* ad3  = (const float*)d_in[13];
    const float* b3   = (const float*)d_in[14];
    const float* fw1  = (const float*)d_in[15];
    const float* fb1  = (const float*)d_in[16];
    const float* fw2  = (const float*)d_in[17];
    const float* fb2  = (const float*)d_in[18];
    const float* fw3  = (const float*)d_in[19];
    const float* fb3  = (const float*)d_in[20];
    float* outp = (float*)d_out;

    const int N = in_sizes[0] / 21;
    const int E = in_sizes[1] / 2;
    const int G = out_size;

    // ---- workspace carve ----
    char* p = (char*)d_ws;
    auto alloc = [&](size_t bytes) -> void* {
        void* r = (void*)p;
        p += (bytes + 255) & ~(size_t)255;
        return r;
    };
    int*   deg  = (int*)alloc((size_t)N * 4);
    int*   offs = (int*)alloc((size_t)(N + 1) * 4);
    int*   cur  = (int*)alloc((size_t)N * 4);
    int*   csr  = (int*)alloc((size_t)E * 4);
    float* hA   = (float*)alloc((size_t)N * 256 * 4);
    float* hB   = (float*)alloc((size_t)N * 256 * 4);
    float* asb  = (float*)alloc((size_t)N * 4 * 4);
    float* adb  = (float*)alloc((size_t)N * 4 * 4);
    float* pl   = (float*)alloc((size_t)G * 33 * 4);   // pool[G*32] + cnt[G] contiguous
    float* cnt  = pl + (size_t)G * 32;

    const int* esrc = ei;
    const int* edst = ei + E;

    // ---- zero what needs zeroing (ws is poisoned, not re-zeroed between replays) ----
    hipMemsetAsync(deg, 0, (size_t)N * 4, stream);
    hipMemsetAsync(pl, 0, (size_t)G * 33 * 4, stream);

    const int eb = (E + 255) / 256;

    // ---- CSR build (shared by all 3 layers) ----
    k_deg<<<eb, 256, 0, stream>>>(edst, deg, E);
    k_scan<<<1, 1024, 0, stream>>>(deg, offs, cur, N);
    k_scatter<<<eb, 256, 0, stream>>>(esrc, edst, cur, csr, E);

    // ---- layer 1 ----
    k_gemm1<<<(N + 7) / 8, 256, 0, stream>>>(x, w1, as1, ad1, hA, asb, adb, N);
    k_gather256<<<N, 256, 0, stream>>>(hA, asb, adb, offs, csr, b1, hB, N);

    // ---- layer 2 ----
    k_gemm2<<<(N + 15) / 16, 256, 0, stream>>>(hB, w2, as2, ad2, hA, asb, adb, N);
    k_gather256<<<N, 256, 0, stream>>>(hA, asb, adb, offs, csr, b2, hB, N);

    // ---- layer 3 ----
    k_gemm3<<<(N + 7) / 8, 256, 0, stream>>>(hB, w3, as3, ad3, hA, asb, adb, N);
    k_gather32<<<(N + 7) / 8, 256, 0, stream>>>(hA, asb, adb, offs, csr, b3, hB, N);

    // ---- pool + head ----
    k_pool<<<((N * 32) + 255) / 256, 256, 0, stream>>>(hB, batch, pl, cnt, N);
    k_head<<<1, 256, 0, stream>>>(pl, cnt, fw1, fb1, fw2, fb2, fw3, fb3, outp, G);
}

// Round 2
// 1814.479 us; speedup vs baseline: 1.1693x; 1.1693x over previous
//
#include <hip/hip_runtime.h>
#include <math.h>

typedef float f4 __attribute__((ext_vector_type(4)));

// ---------------- device helpers ----------------
__device__ __forceinline__ float lrelu(float x) { return x >= 0.f ? x : 0.2f * x; }
__device__ __forceinline__ float eluf(float x)  { return x > 0.f ? x : __expf(x) - 1.f; }

__device__ __forceinline__ float bf2f(unsigned short u) {
    union { unsigned int i; float f; } c; c.i = ((unsigned int)u) << 16; return c.f;
}
__device__ __forceinline__ unsigned short f2bf(float f) {
    union { float f; unsigned int i; } c; c.f = f;
    unsigned int r = c.i + 0x7fffu + ((c.i >> 16) & 1u);   // RNE
    return (unsigned short)(r >> 16);
}

// ---------------- CSR build ----------------
__global__ void k_deg(const int* __restrict__ dst, int* __restrict__ deg, int E) {
    int e = blockIdx.x * 256 + threadIdx.x;
    if (e < E) atomicAdd(&deg[dst[e]], 1);
}

// single-block scan over N (~100k) elements; writes offs[N+1] and cursor[N]
__global__ void k_scan(const int* __restrict__ deg, int* __restrict__ offs,
                       int* __restrict__ cursor, int N) {
    __shared__ int sm[1024];
    int t = threadIdx.x;
    int chunk = (N + 1023) >> 10;
    int s = t * chunk, e = min(s + chunk, N);
    int sum = 0;
    for (int i = s; i < e; ++i) sum += deg[i];
    sm[t] = sum;
    __syncthreads();
    for (int d = 1; d < 1024; d <<= 1) {
        int v = (t >= d) ? sm[t - d] : 0;
        __syncthreads();
        sm[t] += v;
        __syncthreads();
    }
    int pref = (t == 0) ? 0 : sm[t - 1];
    for (int i = s; i < e; ++i) {
        offs[i] = pref; cursor[i] = pref;
        pref += deg[i];
    }
    if (t == 1023) offs[N] = sm[1023];
}

__global__ void k_scatter(const int* __restrict__ src, const int* __restrict__ dst,
                          int* __restrict__ cur, int* __restrict__ csr, int E) {
    int e = blockIdx.x * 256 + threadIdx.x;
    if (e < E) {
        int p = atomicAdd(&cur[dst[e]], 1);
        csr[p] = src[e];
    }
}

// ---------------- GEMM + attention-score epilogues ----------------
// L1: x[N,21] @ w[21,256] -> hbf[N,256] (bf16); scores fp32
__global__ void k_gemm1(const float* __restrict__ x, const float* __restrict__ w,
                        const float* __restrict__ aw_s, const float* __restrict__ aw_d,
                        unsigned short* __restrict__ hbf, float* __restrict__ asb,
                        float* __restrict__ adb, int N) {
    int tid = threadIdx.x;
    int row0 = blockIdx.x * 8;
    __shared__ float xs[8][21];
    int nrows = min(8, N - row0);
    for (int i = tid; i < nrows * 21; i += 256) xs[i / 21][i % 21] = x[row0 * 21 + i];
    __syncthreads();
    float wreg[21];
#pragma unroll
    for (int k = 0; k < 21; ++k) wreg[k] = w[k * 256 + tid];
    float avs = aw_s[tid], avd = aw_d[tid];
    int head = tid >> 6;
    for (int r = 0; r < nrows; ++r) {
        float acc = 0.f;
#pragma unroll
        for (int k = 0; k < 21; ++k) acc = fmaf(xs[r][k], wreg[k], acc);
        hbf[(size_t)(row0 + r) * 256 + tid] = f2bf(acc);
        float s1 = acc * avs, s2 = acc * avd;
#pragma unroll
        for (int m = 32; m; m >>= 1) { s1 += __shfl_xor(s1, m); s2 += __shfl_xor(s2, m); }
        if ((tid & 63) == 0) {
            asb[(row0 + r) * 4 + head] = s1;
            adb[(row0 + r) * 4 + head] = s2;
        }
    }
}

// L2: in[N,256] (fp32, streamed NT) @ w[256,256] -> hbf[N,256] (bf16)
__global__ void k_gemm2(const float* __restrict__ in, const float* __restrict__ w,
                        const float* __restrict__ aw_s, const float* __restrict__ aw_d,
                        unsigned short* __restrict__ hbf, float* __restrict__ asb,
                        float* __restrict__ adb, int N) {
    int tid = threadIdx.x;
    int row0 = blockIdx.x * 16;
    __shared__ __align__(16) float hs[16][256];
    int nrows = min(16, N - row0);
    const f4* inv4 = reinterpret_cast<const f4*>(in + (size_t)row0 * 256);
    f4* hsv = reinterpret_cast<f4*>(&hs[0][0]);
#pragma unroll
    for (int i = 0; i < 4; ++i) {
        int idx = i * 256 + tid;          // float4 index into [16][64]
        int r = idx >> 6;
        if (r < nrows) hsv[idx] = __builtin_nontemporal_load(inv4 + idx);
    }
    __syncthreads();
    float acc[16];
#pragma unroll
    for (int r = 0; r < 16; ++r) acc[r] = 0.f;
    for (int k = 0; k < 256; k += 4) {
        float w0 = w[(k + 0) * 256 + tid];
        float w1 = w[(k + 1) * 256 + tid];
        float w2 = w[(k + 2) * 256 + tid];
        float w3 = w[(k + 3) * 256 + tid];
#pragma unroll
        for (int r = 0; r < 16; ++r) {
            const f4 hv = *reinterpret_cast<const f4*>(&hs[r][k]);
            acc[r] = fmaf(hv.x, w0, fmaf(hv.y, w1, fmaf(hv.z, w2, fmaf(hv.w, w3, acc[r]))));
        }
    }
    float avs = aw_s[tid], avd = aw_d[tid];
    int head = tid >> 6;
    for (int r = 0; r < nrows; ++r) {
        hbf[(size_t)(row0 + r) * 256 + tid] = f2bf(acc[r]);
        float s1 = acc[r] * avs, s2 = acc[r] * avd;
#pragma unroll
        for (int m = 32; m; m >>= 1) { s1 += __shfl_xor(s1, m); s2 += __shfl_xor(s2, m); }
        if ((tid & 63) == 0) {
            asb[(row0 + r) * 4 + head] = s1;
            adb[(row0 + r) * 4 + head] = s2;
        }
    }
}

// L3: in[N,256] (NT) @ w[256,32] -> h3[N,32] fp32; 1 head
__global__ void k_gemm3(const float* __restrict__ in, const float* __restrict__ w,
                        const float* __restrict__ aw_s, const float* __restrict__ aw_d,
                        float* __restrict__ h, float* __restrict__ asb, float* __restrict__ adb,
                        int N) {
    int tid = threadIdx.x;
    int row0 = blockIdx.x * 8;
    int r = tid >> 5, c = tid & 31;
    __shared__ __align__(16) float hs[8][256];
    const f4* inv4 = reinterpret_cast<const f4*>(in + (size_t)row0 * 256);
    f4* hsv = reinterpret_cast<f4*>(&hs[0][0]);
#pragma unroll
    for (int i = 0; i < 2; ++i) {
        int idx = i * 256 + tid;          // float4 index into [8][64]
        int rr = idx >> 6;
        if (row0 + rr < N) hsv[idx] = __builtin_nontemporal_load(inv4 + idx);
    }
    __syncthreads();
    float acc = 0.f;
    for (int k = 0; k < 256; k += 4) {
        const f4 hv = *reinterpret_cast<const f4*>(&hs[r][k]);
        acc = fmaf(hv.x, w[(k + 0) * 32 + c],
              fmaf(hv.y, w[(k + 1) * 32 + c],
              fmaf(hv.z, w[(k + 2) * 32 + c],
              fmaf(hv.w, w[(k + 3) * 32 + c], acc))));
    }
    int row = row0 + r;
    if (row < N) {
        h[(size_t)row * 32 + c] = acc;
        float s1 = acc * aw_s[c], s2 = acc * aw_d[c];
#pragma unroll
        for (int m = 16; m; m >>= 1) { s1 += __shfl_xor(s1, m); s2 += __shfl_xor(s2, m); }
        if (c == 0) { asb[row] = s1; adb[row] = s2; }
    }
}

// ---------------- gather (attention aggregate), F=256 bf16, 4 heads ----------------
// one wave per node; lane handles 4 features (ushort4 = 8B loads)
__global__ void k_gather256(const unsigned short* __restrict__ hbf,
                            const float* __restrict__ asb, const float* __restrict__ adb,
                            const int* __restrict__ offs, const int* __restrict__ csr,
                            const float* __restrict__ bias, float* __restrict__ out, int N) {
    int tid = threadIdx.x;
    int lane = tid & 63;
    int v = blockIdx.x * 4 + (tid >> 6);
    if (v >= N) return;
    int head = lane >> 4;                 // feature 4*lane -> head = lane/16
    float ad = adb[v * 4 + head];
    float s0 = asb[v * 4 + head] + ad;
    float w0 = __expf(lrelu(s0));
    float den = w0;
    float a0, a1, a2, a3;
    {
        ushort4 hv = *reinterpret_cast<const ushort4*>(&hbf[(size_t)v * 256 + 4 * lane]);
        a0 = w0 * bf2f(hv.x); a1 = w0 * bf2f(hv.y);
        a2 = w0 * bf2f(hv.z); a3 = w0 * bf2f(hv.w);
    }
    int beg = offs[v], end = offs[v + 1];
    for (int e = beg; e < end; ++e) {
        int u = csr[e];
        float wu = __expf(lrelu(asb[u * 4 + head] + ad));
        den += wu;
        ushort4 hv = *reinterpret_cast<const ushort4*>(&hbf[(size_t)u * 256 + 4 * lane]);
        a0 = fmaf(wu, bf2f(hv.x), a0); a1 = fmaf(wu, bf2f(hv.y), a1);
        a2 = fmaf(wu, bf2f(hv.z), a2); a3 = fmaf(wu, bf2f(hv.w), a3);
    }
    float inv = 1.f / (den + 1e-16f);
    int f0 = 4 * lane;
    f4 o;
    o.x = eluf(a0 * inv + bias[f0 + 0]);
    o.y = eluf(a1 * inv + bias[f0 + 1]);
    o.z = eluf(a2 * inv + bias[f0 + 2]);
    o.w = eluf(a3 * inv + bias[f0 + 3]);
    __builtin_nontemporal_store(o, reinterpret_cast<f4*>(&out[(size_t)v * 256 + f0]));
}

// ---------------- gather, F=32 fp32, 1 head; 8 nodes per 256-thread block ----------------
__global__ void k_gather32(const float* __restrict__ h, const float* __restrict__ asb,
                           const float* __restrict__ adb, const int* __restrict__ offs,
                           const int* __restrict__ csr, const float* __restrict__ bias,
                           float* __restrict__ out, int N) {
    int tid = threadIdx.x;
    int v = blockIdx.x * 8 + (tid >> 5);
    int c = tid & 31;
    if (v >= N) return;
    float ad = adb[v];
    float s0 = asb[v] + ad;
    float w0 = __expf(lrelu(s0));
    float den = w0;
    float acc = w0 * h[(size_t)v * 32 + c];
    int beg = offs[v], end = offs[v + 1];
    for (int e = beg; e < end; ++e) {
        int u = csr[e];
        float wu = __expf(lrelu(asb[u] + ad));
        den += wu;
        acc = fmaf(wu, h[(size_t)u * 32 + c], acc);
    }
    float o = eluf(acc / (den + 1e-16f) + bias[c]);
    __builtin_nontemporal_store(o, &out[(size_t)v * 32 + c]);
}

// ---------------- global mean pool (atomic accumulate) ----------------
__global__ void k_pool(const float* __restrict__ h, const int* __restrict__ batch,
                       float* __restrict__ pool, float* __restrict__ cnt, int N) {
    int i = blockIdx.x * 256 + threadIdx.x;
    if (i >= N * 32) return;
    int node = i >> 5, f = i & 31;
    int b = batch[node];
    atomicAdd(&pool[b * 32 + f], h[i]);
    if (f == 0) atomicAdd(&cnt[b], 1.0f);
}

// ---------------- MLP head: one thread per graph ----------------
__global__ void k_head(const float* __restrict__ pool, const float* __restrict__ cnt,
                       const float* __restrict__ fw1, const float* __restrict__ fb1,
                       const float* __restrict__ fw2, const float* __restrict__ fb2,
                       const float* __restrict__ fw3, const float* __restrict__ fb3,
                       float* __restrict__ out, int G) {
    int g = threadIdx.x;
    if (g >= G) return;
    float inv = 1.f / fmaxf(cnt[g], 1.f);
    float p[32];
    for (int k = 0; k < 32; ++k) p[k] = pool[g * 32 + k] * inv;
    float t1[64];
    for (int j = 0; j < 64; ++j) {
        float a = fb1[j];
        for (int k = 0; k < 32; ++k) a = fmaf(p[k], fw1[k * 64 + j], a);
        t1[j] = fmaxf(a, 0.f);
    }
    float t2[32];
    for (int j = 0; j < 32; ++j) {
        float a = fb2[j];
        for (int k = 0; k < 64; ++k) a = fmaf(t1[k], fw2[k * 32 + j], a);
        t2[j] = fmaxf(a, 0.f);
    }
    float o = fb3[0];
    for (int k = 0; k < 32; ++k) o = fmaf(t2[k], fw3[k], o);
    out[g] = 1.f / (1.f + __expf(-o));
}

// ---------------- host ----------------
extern "C" void kernel_launch(void* const* d_in, const int* in_sizes, int n_in,
                              void* d_out, int out_size, void* d_ws, size_t ws_size,
                              hipStream_t stream) {
    const float* x    = (const float*)d_in[0];
    const int*   ei   = (const int*)d_in[1];
    const int*   batch= (const int*)d_in[2];
    const float* w1   = (const float*)d_in[3];
    const float* as1  = (const float*)d_in[4];
    const float* ad1  = (const float*)d_in[5];
    const float* b1   = (const float*)d_in[6];
    const float* w2   = (const float*)d_in[7];
    const float* as2  = (const float*)d_in[8];
    const float* ad2  = (const float*)d_in[9];
    const float* b2   = (const float*)d_in[10];
    const float* w3   = (const float*)d_in[11];
    const float* as3  = (const float*)d_in[12];
    const float* ad3  = (const float*)d_in[13];
    const float* b3   = (const float*)d_in[14];
    const float* fw1  = (const float*)d_in[15];
    const float* fb1  = (const float*)d_in[16];
    const float* fw2  = (const float*)d_in[17];
    const float* fb2  = (const float*)d_in[18];
    const float* fw3  = (const float*)d_in[19];
    const float* fb3  = (const float*)d_in[20];
    float* outp = (float*)d_out;

    const int N = in_sizes[0] / 21;
    const int E = in_sizes[1] / 2;
    const int G = out_size;

    // ---- workspace carve ----
    char* p = (char*)d_ws;
    auto alloc = [&](size_t bytes) -> void* {
        void* r = (void*)p;
        p += (bytes + 255) & ~(size_t)255;
        return r;
    };
    int*   deg  = (int*)alloc((size_t)N * 4);
    int*   offs = (int*)alloc((size_t)(N + 1) * 4);
    int*   cur  = (int*)alloc((size_t)N * 4);
    int*   csr  = (int*)alloc((size_t)E * 4);
    unsigned short* hbf = (unsigned short*)alloc((size_t)N * 256 * 2);  // bf16 gather operand
    float* hB   = (float*)alloc((size_t)N * 256 * 4);                   // fp32 gather output
    float* h3   = (float*)alloc((size_t)N * 32 * 4);
    float* asb  = (float*)alloc((size_t)N * 4 * 4);
    float* adb  = (float*)alloc((size_t)N * 4 * 4);
    float* pl   = (float*)alloc((size_t)G * 33 * 4);
    float* cnt  = pl + (size_t)G * 32;

    const int* esrc = ei;
    const int* edst = ei + E;

    hipMemsetAsync(deg, 0, (size_t)N * 4, stream);
    hipMemsetAsync(pl, 0, (size_t)G * 33 * 4, stream);

    const int eb = (E + 255) / 256;

    // ---- CSR build (shared by all 3 layers) ----
    k_deg<<<eb, 256, 0, stream>>>(edst, deg, E);
    k_scan<<<1, 1024, 0, stream>>>(deg, offs, cur, N);
    k_scatter<<<eb, 256, 0, stream>>>(esrc, edst, cur, csr, E);

    // ---- layer 1 ----
    k_gemm1<<<(N + 7) / 8, 256, 0, stream>>>(x, w1, as1, ad1, hbf, asb, adb, N);
    k_gather256<<<(N + 3) / 4, 256, 0, stream>>>(hbf, asb, adb, offs, csr, b1, hB, N);

    // ---- layer 2 ----
    k_gemm2<<<(N + 15) / 16, 256, 0, stream>>>(hB, w2, as2, ad2, hbf, asb, adb, N);
    k_gather256<<<(N + 3) / 4, 256, 0, stream>>>(hbf, asb, adb, offs, csr, b2, hB, N);

    // ---- layer 3 ----
    k_gemm3<<<(N + 15) / 16 * 2, 256, 0, stream>>>(hB, w3, as3, ad3, h3, asb, adb, N);
    k_gather32<<<(N + 7) / 8, 256, 0, stream>>>(h3, asb, adb, offs, csr, b3, hB, N);

    // ---- pool + head ----
    k_pool<<<((N * 32) + 255) / 256, 256, 0, stream>>>(hB, batch, pl, cnt, N);
    k_head<<<1, 256, 0, stream>>>(pl, cnt, fw1, fb1, fw2, fb2, fw3, fb3, outp, G);
}

// Round 4
// 1431.518 us; speedup vs baseline: 1.4822x; 1.2675x over previous
//
#include <hip/hip_runtime.h>
#include <math.h>

typedef float f4 __attribute__((ext_vector_type(4)));
typedef float f32x4 __attribute__((ext_vector_type(4)));
typedef short bf16x8 __attribute__((ext_vector_type(8)));
typedef unsigned short us4 __attribute__((ext_vector_type(4)));
typedef unsigned int u32x2 __attribute__((ext_vector_type(2)));

// ---------------- device helpers ----------------
__device__ __forceinline__ float lrelu(float x) { return x >= 0.f ? x : 0.2f * x; }
__device__ __forceinline__ float eluf(float x)  { return x > 0.f ? x : __expf(x) - 1.f; }

__device__ __forceinline__ float bf2f(unsigned short u) {
    union { unsigned int i; float f; } c; c.i = ((unsigned int)u) << 16; return c.f;
}
__device__ __forceinline__ unsigned short f2bf(float f) {
    union { float f; unsigned int i; } c; c.f = f;
    unsigned int r = c.i + 0x7fffu + ((c.i >> 16) & 1u);   // RNE
    return (unsigned short)(r >> 16);
}

// ---------------- CSR build ----------------
__global__ void k_deg(const int* __restrict__ dst, int* __restrict__ deg, int E) {
    int e = blockIdx.x * 256 + threadIdx.x;
    if (e < E) atomicAdd(&deg[dst[e]], 1);
}

__global__ void k_scan(const int* __restrict__ deg, int* __restrict__ offs,
                       int* __restrict__ cursor, int N) {
    __shared__ int sm[1024];
    int t = threadIdx.x;
    int chunk = (N + 1023) >> 10;
    int s = t * chunk, e = min(s + chunk, N);
    int sum = 0;
    for (int i = s; i < e; ++i) sum += deg[i];
    sm[t] = sum;
    __syncthreads();
    for (int d = 1; d < 1024; d <<= 1) {
        int v = (t >= d) ? sm[t - d] : 0;
        __syncthreads();
        sm[t] += v;
        __syncthreads();
    }
    int pref = (t == 0) ? 0 : sm[t - 1];
    for (int i = s; i < e; ++i) {
        offs[i] = pref; cursor[i] = pref;
        pref += deg[i];
    }
    if (t == 1023) offs[N] = sm[1023];
}

__global__ void k_scatter(const int* __restrict__ src, const int* __restrict__ dst,
                          int* __restrict__ cur, int* __restrict__ csr, int E) {
    int e = blockIdx.x * 256 + threadIdx.x;
    if (e < E) {
        int p = atomicAdd(&cur[dst[e]], 1);
        csr[p] = src[e];
    }
}

// ---------------- weight pack: w[K][C] fp32 -> wp[((k>>3)*C + c)*8 + (k&7)] bf16 ----------------
__global__ void k_pack(const float* __restrict__ w, unsigned short* __restrict__ wp,
                       int K, int C) {
    int i = blockIdx.x * 256 + threadIdx.x;
    if (i < K * C) {
        int k = i / C, c = i % C;
        wp[((size_t)(k >> 3) * C + c) * 8 + (k & 7)] = f2bf(w[i]);
    }
}

// ---------------- L1 GEMM (VALU, K=21) ----------------
__global__ void k_gemm1(const float* __restrict__ x, const float* __restrict__ w,
                        const float* __restrict__ aw_s, const float* __restrict__ aw_d,
                        unsigned short* __restrict__ hbf, float* __restrict__ asb,
                        float* __restrict__ adb, int N) {
    int tid = threadIdx.x;
    int row0 = blockIdx.x * 8;
    __shared__ float xs[8][21];
    int nrows = min(8, N - row0);
    for (int i = tid; i < nrows * 21; i += 256) xs[i / 21][i % 21] = x[row0 * 21 + i];
    __syncthreads();
    float wreg[21];
#pragma unroll
    for (int k = 0; k < 21; ++k) wreg[k] = w[k * 256 + tid];
    float avs = aw_s[tid], avd = aw_d[tid];
    int head = tid >> 6;
    for (int r = 0; r < nrows; ++r) {
        float acc = 0.f;
#pragma unroll
        for (int k = 0; k < 21; ++k) acc = fmaf(xs[r][k], wreg[k], acc);
        hbf[(size_t)(row0 + r) * 256 + tid] = f2bf(acc);
        float s1 = acc * avs, s2 = acc * avd;
#pragma unroll
        for (int m = 32; m; m >>= 1) { s1 += __shfl_xor(s1, m); s2 += __shfl_xor(s2, m); }
        if ((tid & 63) == 0) {
            asb[(row0 + r) * 4 + head] = s1;
            adb[(row0 + r) * 4 + head] = s2;
        }
    }
}

// ---------------- L2 GEMM via MFMA: in[N,256]bf16 @ w2p -> out[N,256]bf16 + scores ----------------
// 4 waves/block, wave owns 16 rows x 256 cols; K=256 in 8 steps of 32.
__global__ __launch_bounds__(256) void k_gemm2_mfma(
        const unsigned short* __restrict__ in, const unsigned short* __restrict__ w2p,
        const float* __restrict__ as2f, const float* __restrict__ ad2f,
        unsigned short* __restrict__ outbf, float* __restrict__ asb,
        float* __restrict__ adb, int N) {
    int tid = threadIdx.x;
    int wave = tid >> 6, lane = tid & 63;
    int g = lane >> 4, q = lane & 15;
    int row0 = blockIdx.x * 64 + wave * 16;

    f32x4 acc[16];
#pragma unroll
    for (int ct = 0; ct < 16; ++ct) acc[ct] = (f32x4)0.f;

    const unsigned short* aptr = in + (size_t)(row0 + q) * 256 + g * 8;
    const unsigned short* bptr = w2p + ((size_t)g * 256 + q) * 8;

#pragma unroll
    for (int kt = 0; kt < 8; ++kt) {
        bf16x8 a = *reinterpret_cast<const bf16x8*>(aptr + kt * 32);
#pragma unroll
        for (int ct = 0; ct < 16; ++ct) {
            bf16x8 b = *reinterpret_cast<const bf16x8*>(bptr + (size_t)kt * 8192 + ct * 128);
            acc[ct] = __builtin_amdgcn_mfma_f32_16x16x32_bf16(a, b, acc[ct], 0, 0, 0);
        }
    }

    // write bf16 output
#pragma unroll
    for (int ct = 0; ct < 16; ++ct) {
        int col = ct * 16 + q;
#pragma unroll
        for (int r = 0; r < 4; ++r) {
            int row = row0 + 4 * g + r;
            if (row < N) outbf[(size_t)row * 256 + col] = f2bf(acc[ct][r]);
        }
    }

    // per-head attention scores: s[row][h] = sum_c acc[row][c] * a[h][c]
#pragma unroll
    for (int h = 0; h < 4; ++h) {
        float s1[4] = {0.f, 0.f, 0.f, 0.f}, s2[4] = {0.f, 0.f, 0.f, 0.f};
#pragma unroll
        for (int cc = 0; cc < 4; ++cc) {
            int ct = h * 4 + cc;
            int col = ct * 16 + q;
            float ws_ = as2f[col], wd_ = ad2f[col];
#pragma unroll
            for (int r = 0; r < 4; ++r) {
                s1[r] = fmaf(acc[ct][r], ws_, s1[r]);
                s2[r] = fmaf(acc[ct][r], wd_, s2[r]);
            }
        }
#pragma unroll
        for (int m = 1; m < 16; m <<= 1) {
#pragma unroll
            for (int r = 0; r < 4; ++r) {
                s1[r] += __shfl_xor(s1[r], m);
                s2[r] += __shfl_xor(s2[r], m);
            }
        }
        if (q == 0) {
#pragma unroll
            for (int r = 0; r < 4; ++r) {
                int row = row0 + 4 * g + r;
                if (row < N) { asb[row * 4 + h] = s1[r]; adb[row * 4 + h] = s2[r]; }
            }
        }
    }
}

// ---------------- L3 GEMM via MFMA: in[N,256]bf16 @ w3p[256,32] -> h3[N,32]fp32 + scores ----------------
__global__ __launch_bounds__(256) void k_gemm3_mfma(
        const unsigned short* __restrict__ in, const unsigned short* __restrict__ w3p,
        const float* __restrict__ as3f, const float* __restrict__ ad3f,
        float* __restrict__ h3, float* __restrict__ asb, float* __restrict__ adb, int N) {
    int tid = threadIdx.x;
    int wave = tid >> 6, lane = tid & 63;
    int g = lane >> 4, q = lane & 15;
    int row0 = blockIdx.x * 64 + wave * 16;

    f32x4 acc[2];
    acc[0] = (f32x4)0.f; acc[1] = (f32x4)0.f;

    const unsigned short* aptr = in + (size_t)(row0 + q) * 256 + g * 8;
    const unsigned short* bptr = w3p + ((size_t)g * 32 + q) * 8;

#pragma unroll
    for (int kt = 0; kt < 8; ++kt) {
        bf16x8 a = *reinterpret_cast<const bf16x8*>(aptr + kt * 32);
#pragma unroll
        for (int ct = 0; ct < 2; ++ct) {
            bf16x8 b = *reinterpret_cast<const bf16x8*>(bptr + (size_t)kt * 1024 + ct * 128);
            acc[ct] = __builtin_amdgcn_mfma_f32_16x16x32_bf16(a, b, acc[ct], 0, 0, 0);
        }
    }

    float s1[4] = {0.f, 0.f, 0.f, 0.f}, s2[4] = {0.f, 0.f, 0.f, 0.f};
#pragma unroll
    for (int ct = 0; ct < 2; ++ct) {
        int col = ct * 16 + q;
        float ws_ = as3f[col], wd_ = ad3f[col];
#pragma unroll
        for (int r = 0; r < 4; ++r) {
            int row = row0 + 4 * g + r;
            if (row < N) h3[(size_t)row * 32 + col] = acc[ct][r];
            s1[r] = fmaf(acc[ct][r], ws_, s1[r]);
            s2[r] = fmaf(acc[ct][r], wd_, s2[r]);
        }
    }
#pragma unroll
    for (int m = 1; m < 16; m <<= 1) {
#pragma unroll
        for (int r = 0; r < 4; ++r) {
            s1[r] += __shfl_xor(s1[r], m);
            s2[r] += __shfl_xor(s2[r], m);
        }
    }
    if (q == 0) {
#pragma unroll
        for (int r = 0; r < 4; ++r) {
            int row = row0 + 4 * g + r;
            if (row < N) { asb[row] = s1[r]; adb[row] = s2[r]; }
        }
    }
}

// ---------------- gather (attention aggregate), F=256 bf16 -> bf16, 4 heads ----------------
__global__ void k_gather256(const unsigned short* __restrict__ hbf,
                            const float* __restrict__ asb, const float* __restrict__ adb,
                            const int* __restrict__ offs, const int* __restrict__ csr,
                            const float* __restrict__ bias, unsigned short* __restrict__ out,
                            int N) {
    int tid = threadIdx.x;
    int lane = tid & 63;
    int v = blockIdx.x * 4 + (tid >> 6);
    if (v >= N) return;
    int head = lane >> 4;
    float ad = adb[v * 4 + head];
    float s0 = asb[v * 4 + head] + ad;
    float w0 = __expf(lrelu(s0));
    float den = w0;
    float a0, a1, a2, a3;
    {
        us4 hv = *reinterpret_cast<const us4*>(&hbf[(size_t)v * 256 + 4 * lane]);
        a0 = w0 * bf2f(hv.x); a1 = w0 * bf2f(hv.y);
        a2 = w0 * bf2f(hv.z); a3 = w0 * bf2f(hv.w);
    }
    int beg = offs[v], end = offs[v + 1];
    for (int e = beg; e < end; ++e) {
        int u = csr[e];
        float wu = __expf(lrelu(asb[u * 4 + head] + ad));
        den += wu;
        us4 hv = *reinterpret_cast<const us4*>(&hbf[(size_t)u * 256 + 4 * lane]);
        a0 = fmaf(wu, bf2f(hv.x), a0); a1 = fmaf(wu, bf2f(hv.y), a1);
        a2 = fmaf(wu, bf2f(hv.z), a2); a3 = fmaf(wu, bf2f(hv.w), a3);
    }
    float inv = 1.f / (den + 1e-16f);
    int f0 = 4 * lane;
    unsigned int w01 = (unsigned int)f2bf(eluf(a0 * inv + bias[f0 + 0]))
                     | ((unsigned int)f2bf(eluf(a1 * inv + bias[f0 + 1])) << 16);
    unsigned int w23 = (unsigned int)f2bf(eluf(a2 * inv + bias[f0 + 2]))
                     | ((unsigned int)f2bf(eluf(a3 * inv + bias[f0 + 3])) << 16);
    u32x2 o; o.x = w01; o.y = w23;
    __builtin_nontemporal_store(o, reinterpret_cast<u32x2*>(&out[(size_t)v * 256 + f0]));
}

// ---------------- gather, F=32 fp32, 1 head ----------------
__global__ void k_gather32(const float* __restrict__ h, const float* __restrict__ asb,
                           const float* __restrict__ adb, const int* __restrict__ offs,
                           const int* __restrict__ csr, const float* __restrict__ bias,
                           float* __restrict__ out, int N) {
    int tid = threadIdx.x;
    int v = blockIdx.x * 8 + (tid >> 5);
    int c = tid & 31;
    if (v >= N) return;
    float ad = adb[v];
    float s0 = asb[v] + ad;
    float w0 = __expf(lrelu(s0));
    float den = w0;
    float acc = w0 * h[(size_t)v * 32 + c];
    int beg = offs[v], end = offs[v + 1];
    for (int e = beg; e < end; ++e) {
        int u = csr[e];
        float wu = __expf(lrelu(asb[u] + ad));
        den += wu;
        acc = fmaf(wu, h[(size_t)u * 32 + c], acc);
    }
    float o = eluf(acc / (den + 1e-16f) + bias[c]);
    __builtin_nontemporal_store(o, &out[(size_t)v * 32 + c]);
}

// ---------------- global mean pool ----------------
__global__ void k_pool(const float* __restrict__ h, const int* __restrict__ batch,
                       float* __restrict__ pool, float* __restrict__ cnt, int N) {
    int i = blockIdx.x * 256 + threadIdx.x;
    if (i >= N * 32) return;
    int node = i >> 5, f = i & 31;
    int b = batch[node];
    atomicAdd(&pool[b * 32 + f], h[i]);
    if (f == 0) atomicAdd(&cnt[b], 1.0f);
}

// ---------------- MLP head ----------------
__global__ void k_head(const float* __restrict__ pool, const float* __restrict__ cnt,
                       const float* __restrict__ fw1, const float* __restrict__ fb1,
                       const float* __restrict__ fw2, const float* __restrict__ fb2,
                       const float* __restrict__ fw3, const float* __restrict__ fb3,
                       float* __restrict__ out, int G) {
    int g = threadIdx.x;
    if (g >= G) return;
    float inv = 1.f / fmaxf(cnt[g], 1.f);
    float p[32];
    for (int k = 0; k < 32; ++k) p[k] = pool[g * 32 + k] * inv;
    float t1[64];
    for (int j = 0; j < 64; ++j) {
        float a = fb1[j];
        for (int k = 0; k < 32; ++k) a = fmaf(p[k], fw1[k * 64 + j], a);
        t1[j] = fmaxf(a, 0.f);
    }
    float t2[32];
    for (int j = 0; j < 32; ++j) {
        float a = fb2[j];
        for (int k = 0; k < 64; ++k) a = fmaf(t1[k], fw2[k * 32 + j], a);
        t2[j] = fmaxf(a, 0.f);
    }
    float o = fb3[0];
    for (int k = 0; k < 32; ++k) o = fmaf(t2[k], fw3[k], o);
    out[g] = 1.f / (1.f + __expf(-o));
}

// ---------------- host ----------------
extern "C" void kernel_launch(void* const* d_in, const int* in_sizes, int n_in,
                              void* d_out, int out_size, void* d_ws, size_t ws_size,
                              hipStream_t stream) {
    const float* x    = (const float*)d_in[0];
    const int*   ei   = (const int*)d_in[1];
    const int*   batch= (const int*)d_in[2];
    const float* w1   = (const float*)d_in[3];
    const float* as1  = (const float*)d_in[4];
    const float* ad1  = (const float*)d_in[5];
    const float* b1   = (const float*)d_in[6];
    const float* w2   = (const float*)d_in[7];
    const float* as2  = (const float*)d_in[8];
    const float* ad2  = (const float*)d_in[9];
    const float* b2   = (const float*)d_in[10];
    const float* w3   = (const float*)d_in[11];
    const float* as3  = (const float*)d_in[12];
    const float* ad3  = (const float*)d_in[13];
    const float* b3   = (const float*)d_in[14];
    const float* fw1  = (const float*)d_in[15];
    const float* fb1  = (const float*)d_in[16];
    const float* fw2  = (const float*)d_in[17];
    const float* fb2  = (const float*)d_in[18];
    const float* fw3  = (const float*)d_in[19];
    const float* fb3  = (const float*)d_in[20];
    float* outp = (float*)d_out;

    const int N = in_sizes[0] / 21;
    const int E = in_sizes[1] / 2;
    const int G = out_size;

    // ---- workspace carve ----
    char* p = (char*)d_ws;
    auto alloc = [&](size_t bytes) -> void* {
        void* r = (void*)p;
        p += (bytes + 255) & ~(size_t)255;
        return r;
    };
    int*   deg  = (int*)alloc((size_t)N * 4);
    int*   offs = (int*)alloc((size_t)(N + 1) * 4);
    int*   cur  = (int*)alloc((size_t)N * 4);
    int*   csr  = (int*)alloc((size_t)E * 4);
    unsigned short* hbfA = (unsigned short*)alloc((size_t)N * 256 * 2);
    unsigned short* hbfB = (unsigned short*)alloc((size_t)N * 256 * 2);
    float* h3   = (float*)alloc((size_t)N * 32 * 4);
    float* hP   = (float*)alloc((size_t)N * 32 * 4);
    float* asb  = (float*)alloc((size_t)N * 4 * 4);
    float* adb  = (float*)alloc((size_t)N * 4 * 4);
    unsigned short* w2p = (unsigned short*)alloc((size_t)256 * 256 * 2);
    unsigned short* w3p = (unsigned short*)alloc((size_t)256 * 32 * 2);
    float* pl   = (float*)alloc((size_t)G * 33 * 4);
    float* cnt  = pl + (size_t)G * 32;

    const int* esrc = ei;
    const int* edst = ei + E;

    (void)hipMemsetAsync(deg, 0, (size_t)N * 4, stream);
    (void)hipMemsetAsync(pl, 0, (size_t)G * 33 * 4, stream);

    const int eb = (E + 255) / 256;

    // ---- CSR build + weight packs ----
    k_deg<<<eb, 256, 0, stream>>>(edst, deg, E);
    k_pack<<<(256 * 256 + 255) / 256, 256, 0, stream>>>(w2, w2p, 256, 256);
    k_pack<<<(256 * 32 + 255) / 256, 256, 0, stream>>>(w3, w3p, 256, 32);
    k_scan<<<1, 1024, 0, stream>>>(deg, offs, cur, N);
    k_scatter<<<eb, 256, 0, stream>>>(esrc, edst, cur, csr, E);

    const int gblk = (N + 63) / 64;

    // ---- layer 1 ----
    k_gemm1<<<(N + 7) / 8, 256, 0, stream>>>(x, w1, as1, ad1, hbfA, asb, adb, N);
    k_gather256<<<(N + 3) / 4, 256, 0, stream>>>(hbfA, asb, adb, offs, csr, b1, hbfB, N);

    // ---- layer 2 ----
    k_gemm2_mfma<<<gblk, 256, 0, stream>>>(hbfB, w2p, as2, ad2, hbfA, asb, adb, N);
    k_gather256<<<(N + 3) / 4, 256, 0, stream>>>(hbfA, asb, adb, offs, csr, b2, hbfB, N);

    // ---- layer 3 ----
    k_gemm3_mfma<<<gblk, 256, 0, stream>>>(hbfB, w3p, as3, ad3, h3, asb, adb, N);
    k_gather32<<<(N + 7) / 8, 256, 0, stream>>>(h3, asb, adb, offs, csr, b3, hP, N);

    // ---- pool + head ----
    k_pool<<<((N * 32) + 255) / 256, 256, 0, stream>>>(hP, batch, pl, cnt, N);
    k_head<<<1, 256, 0, stream>>>(pl, cnt, fw1, fb1, fw2, fb2, fw3, fb3, outp, G);
}

// Round 5
// 1118.114 us; speedup vs baseline: 1.8976x; 1.2803x over previous
//
#include <hip/hip_runtime.h>
#include <math.h>

typedef float f4 __attribute__((ext_vector_type(4)));
typedef float f32x4 __attribute__((ext_vector_type(4)));
typedef short bf16x8 __attribute__((ext_vector_type(8)));
typedef unsigned short us4 __attribute__((ext_vector_type(4)));
typedef unsigned int u32x2 __attribute__((ext_vector_type(2)));

// ---------------- device helpers ----------------
__device__ __forceinline__ float lrelu(float x) { return x >= 0.f ? x : 0.2f * x; }
__device__ __forceinline__ float eluf(float x)  { return x > 0.f ? x : __expf(x) - 1.f; }

__device__ __forceinline__ float bf2f(unsigned short u) {
    union { unsigned int i; float f; } c; c.i = ((unsigned int)u) << 16; return c.f;
}
__device__ __forceinline__ unsigned short f2bf(float f) {
    union { float f; unsigned int i; } c; c.f = f;
    unsigned int r = c.i + 0x7fffu + ((c.i >> 16) & 1u);   // RNE
    return (unsigned short)(r >> 16);
}

// ---------------- CSR build ----------------
__global__ void k_deg(const int* __restrict__ dst, int* __restrict__ deg, int E) {
    int e = blockIdx.x * 256 + threadIdx.x;
    if (e < E) atomicAdd(&deg[dst[e]], 1);
}

__global__ void k_scan(const int* __restrict__ deg, int* __restrict__ offs,
                       int* __restrict__ cursor, int N) {
    __shared__ int sm[1024];
    int t = threadIdx.x;
    int chunk = (N + 1023) >> 10;
    int s = t * chunk, e = min(s + chunk, N);
    int sum = 0;
    for (int i = s; i < e; ++i) sum += deg[i];
    sm[t] = sum;
    __syncthreads();
    for (int d = 1; d < 1024; d <<= 1) {
        int v = (t >= d) ? sm[t - d] : 0;
        __syncthreads();
        sm[t] += v;
        __syncthreads();
    }
    int pref = (t == 0) ? 0 : sm[t - 1];
    for (int i = s; i < e; ++i) {
        offs[i] = pref; cursor[i] = pref;
        pref += deg[i];
    }
    if (t == 1023) offs[N] = sm[1023];
}

__global__ void k_scatter(const int* __restrict__ src, const int* __restrict__ dst,
                          int* __restrict__ cur, int* __restrict__ csr, int E) {
    int e = blockIdx.x * 256 + threadIdx.x;
    if (e < E) {
        int p = atomicAdd(&cur[dst[e]], 1);
        csr[p] = src[e];
    }
}

// ---------------- weight pack: w[K][C] fp32 -> wp[((k>>3)*C + c)*8 + (k&7)] bf16 ----------------
__global__ void k_pack(const float* __restrict__ w, unsigned short* __restrict__ wp,
                       int K, int C) {
    int i = blockIdx.x * 256 + threadIdx.x;
    if (i < K * C) {
        int k = i / C, c = i % C;
        wp[((size_t)(k >> 3) * C + c) * 8 + (k & 7)] = f2bf(w[i]);
    }
}

// ---------------- L1 GEMM (VALU, K=21) ----------------
__global__ void k_gemm1(const float* __restrict__ x, const float* __restrict__ w,
                        const float* __restrict__ aw_s, const float* __restrict__ aw_d,
                        unsigned short* __restrict__ hbf, float* __restrict__ asb,
                        float* __restrict__ adb, int N) {
    int tid = threadIdx.x;
    int row0 = blockIdx.x * 8;
    __shared__ float xs[8][21];
    int nrows = min(8, N - row0);
    for (int i = tid; i < nrows * 21; i += 256) xs[i / 21][i % 21] = x[row0 * 21 + i];
    __syncthreads();
    float wreg[21];
#pragma unroll
    for (int k = 0; k < 21; ++k) wreg[k] = w[k * 256 + tid];
    float avs = aw_s[tid], avd = aw_d[tid];
    int head = tid >> 6;
    for (int r = 0; r < nrows; ++r) {
        float acc = 0.f;
#pragma unroll
        for (int k = 0; k < 21; ++k) acc = fmaf(xs[r][k], wreg[k], acc);
        hbf[(size_t)(row0 + r) * 256 + tid] = f2bf(acc);
        float s1 = acc * avs, s2 = acc * avd;
#pragma unroll
        for (int m = 32; m; m >>= 1) { s1 += __shfl_xor(s1, m); s2 += __shfl_xor(s2, m); }
        if ((tid & 63) == 0) {
            asb[(row0 + r) * 4 + head] = s1;
            adb[(row0 + r) * 4 + head] = s2;
        }
    }
}

// ---------------- L2 GEMM via MFMA ----------------
__global__ __launch_bounds__(256) void k_gemm2_mfma(
        const unsigned short* __restrict__ in, const unsigned short* __restrict__ w2p,
        const float* __restrict__ as2f, const float* __restrict__ ad2f,
        unsigned short* __restrict__ outbf, float* __restrict__ asb,
        float* __restrict__ adb, int N) {
    int tid = threadIdx.x;
    int wave = tid >> 6, lane = tid & 63;
    int g = lane >> 4, q = lane & 15;
    int row0 = blockIdx.x * 64 + wave * 16;

    f32x4 acc[16];
#pragma unroll
    for (int ct = 0; ct < 16; ++ct) acc[ct] = (f32x4)0.f;

    const unsigned short* aptr = in + (size_t)(row0 + q) * 256 + g * 8;
    const unsigned short* bptr = w2p + ((size_t)g * 256 + q) * 8;

#pragma unroll
    for (int kt = 0; kt < 8; ++kt) {
        bf16x8 a = *reinterpret_cast<const bf16x8*>(aptr + kt * 32);
#pragma unroll
        for (int ct = 0; ct < 16; ++ct) {
            bf16x8 b = *reinterpret_cast<const bf16x8*>(bptr + (size_t)kt * 8192 + ct * 128);
            acc[ct] = __builtin_amdgcn_mfma_f32_16x16x32_bf16(a, b, acc[ct], 0, 0, 0);
        }
    }

#pragma unroll
    for (int ct = 0; ct < 16; ++ct) {
        int col = ct * 16 + q;
#pragma unroll
        for (int r = 0; r < 4; ++r) {
            int row = row0 + 4 * g + r;
            if (row < N) outbf[(size_t)row * 256 + col] = f2bf(acc[ct][r]);
        }
    }

#pragma unroll
    for (int h = 0; h < 4; ++h) {
        float s1[4] = {0.f, 0.f, 0.f, 0.f}, s2[4] = {0.f, 0.f, 0.f, 0.f};
#pragma unroll
        for (int cc = 0; cc < 4; ++cc) {
            int ct = h * 4 + cc;
            int col = ct * 16 + q;
            float ws_ = as2f[col], wd_ = ad2f[col];
#pragma unroll
            for (int r = 0; r < 4; ++r) {
                s1[r] = fmaf(acc[ct][r], ws_, s1[r]);
                s2[r] = fmaf(acc[ct][r], wd_, s2[r]);
            }
        }
#pragma unroll
        for (int m = 1; m < 16; m <<= 1) {
#pragma unroll
            for (int r = 0; r < 4; ++r) {
                s1[r] += __shfl_xor(s1[r], m);
                s2[r] += __shfl_xor(s2[r], m);
            }
        }
        if (q == 0) {
#pragma unroll
            for (int r = 0; r < 4; ++r) {
                int row = row0 + 4 * g + r;
                if (row < N) { asb[row * 4 + h] = s1[r]; adb[row * 4 + h] = s2[r]; }
            }
        }
    }
}

// ---------------- L3 GEMM via MFMA ----------------
__global__ __launch_bounds__(256) void k_gemm3_mfma(
        const unsigned short* __restrict__ in, const unsigned short* __restrict__ w3p,
        const float* __restrict__ as3f, const float* __restrict__ ad3f,
        float* __restrict__ h3, float* __restrict__ asb, float* __restrict__ adb, int N) {
    int tid = threadIdx.x;
    int wave = tid >> 6, lane = tid & 63;
    int g = lane >> 4, q = lane & 15;
    int row0 = blockIdx.x * 64 + wave * 16;

    f32x4 acc[2];
    acc[0] = (f32x4)0.f; acc[1] = (f32x4)0.f;

    const unsigned short* aptr = in + (size_t)(row0 + q) * 256 + g * 8;
    const unsigned short* bptr = w3p + ((size_t)g * 32 + q) * 8;

#pragma unroll
    for (int kt = 0; kt < 8; ++kt) {
        bf16x8 a = *reinterpret_cast<const bf16x8*>(aptr + kt * 32);
#pragma unroll
        for (int ct = 0; ct < 2; ++ct) {
            bf16x8 b = *reinterpret_cast<const bf16x8*>(bptr + (size_t)kt * 1024 + ct * 128);
            acc[ct] = __builtin_amdgcn_mfma_f32_16x16x32_bf16(a, b, acc[ct], 0, 0, 0);
        }
    }

    float s1[4] = {0.f, 0.f, 0.f, 0.f}, s2[4] = {0.f, 0.f, 0.f, 0.f};
#pragma unroll
    for (int ct = 0; ct < 2; ++ct) {
        int col = ct * 16 + q;
        float ws_ = as3f[col], wd_ = ad3f[col];
#pragma unroll
        for (int r = 0; r < 4; ++r) {
            int row = row0 + 4 * g + r;
            if (row < N) h3[(size_t)row * 32 + col] = acc[ct][r];
            s1[r] = fmaf(acc[ct][r], ws_, s1[r]);
            s2[r] = fmaf(acc[ct][r], wd_, s2[r]);
        }
    }
#pragma unroll
    for (int m = 1; m < 16; m <<= 1) {
#pragma unroll
        for (int r = 0; r < 4; ++r) {
            s1[r] += __shfl_xor(s1[r], m);
            s2[r] += __shfl_xor(s2[r], m);
        }
    }
    if (q == 0) {
#pragma unroll
        for (int r = 0; r < 4; ++r) {
            int row = row0 + 4 * g + r;
            if (row < N) { asb[row] = s1[r]; adb[row] = s2[r]; }
        }
    }
}

// ---------------- gather (attention aggregate), F=256 bf16 -> bf16, 4 heads ----------------
__global__ void k_gather256(const unsigned short* __restrict__ hbf,
                            const float* __restrict__ asb, const float* __restrict__ adb,
                            const int* __restrict__ offs, const int* __restrict__ csr,
                            const float* __restrict__ bias, unsigned short* __restrict__ out,
                            int N) {
    int tid = threadIdx.x;
    int lane = tid & 63;
    int v = blockIdx.x * 4 + (tid >> 6);
    if (v >= N) return;
    int head = lane >> 4;
    float ad = adb[v * 4 + head];
    float s0 = asb[v * 4 + head] + ad;
    float w0 = __expf(lrelu(s0));
    float den = w0;
    float a0, a1, a2, a3;
    {
        us4 hv = *reinterpret_cast<const us4*>(&hbf[(size_t)v * 256 + 4 * lane]);
        a0 = w0 * bf2f(hv.x); a1 = w0 * bf2f(hv.y);
        a2 = w0 * bf2f(hv.z); a3 = w0 * bf2f(hv.w);
    }
    int beg = offs[v], end = offs[v + 1];
    for (int e = beg; e < end; ++e) {
        int u = csr[e];
        float wu = __expf(lrelu(asb[u * 4 + head] + ad));
        den += wu;
        us4 hv = *reinterpret_cast<const us4*>(&hbf[(size_t)u * 256 + 4 * lane]);
        a0 = fmaf(wu, bf2f(hv.x), a0); a1 = fmaf(wu, bf2f(hv.y), a1);
        a2 = fmaf(wu, bf2f(hv.z), a2); a3 = fmaf(wu, bf2f(hv.w), a3);
    }
    float inv = 1.f / (den + 1e-16f);
    int f0 = 4 * lane;
    unsigned int w01 = (unsigned int)f2bf(eluf(a0 * inv + bias[f0 + 0]))
                     | ((unsigned int)f2bf(eluf(a1 * inv + bias[f0 + 1])) << 16);
    unsigned int w23 = (unsigned int)f2bf(eluf(a2 * inv + bias[f0 + 2]))
                     | ((unsigned int)f2bf(eluf(a3 * inv + bias[f0 + 3])) << 16);
    u32x2 o; o.x = w01; o.y = w23;
    __builtin_nontemporal_store(o, reinterpret_cast<u32x2*>(&out[(size_t)v * 256 + f0]));
}

// ---------------- gather, F=32 fp32, 1 head ----------------
__global__ void k_gather32(const float* __restrict__ h, const float* __restrict__ asb,
                           const float* __restrict__ adb, const int* __restrict__ offs,
                           const int* __restrict__ csr, const float* __restrict__ bias,
                           float* __restrict__ out, int N) {
    int tid = threadIdx.x;
    int v = blockIdx.x * 8 + (tid >> 5);
    int c = tid & 31;
    if (v >= N) return;
    float ad = adb[v];
    float s0 = asb[v] + ad;
    float w0 = __expf(lrelu(s0));
    float den = w0;
    float acc = w0 * h[(size_t)v * 32 + c];
    int beg = offs[v], end = offs[v + 1];
    for (int e = beg; e < end; ++e) {
        int u = csr[e];
        float wu = __expf(lrelu(asb[u] + ad));
        den += wu;
        acc = fmaf(wu, h[(size_t)u * 32 + c], acc);
    }
    float o = eluf(acc / (den + 1e-16f) + bias[c]);
    __builtin_nontemporal_store(o, &out[(size_t)v * 32 + c]);
}

// ---------------- fused mean-pool + MLP head: one block per graph ----------------
// batch is sorted, so graph g's nodes are a contiguous range found by binary search.
__global__ __launch_bounds__(256) void k_pool_head(
        const float* __restrict__ h, const int* __restrict__ batch, int N,
        const float* __restrict__ fw1, const float* __restrict__ fb1,
        const float* __restrict__ fw2, const float* __restrict__ fb2,
        const float* __restrict__ fw3, const float* __restrict__ fb3,
        float* __restrict__ out, int G) {
    int g = blockIdx.x;
    int tid = threadIdx.x;
    __shared__ int bounds[2];
    __shared__ float red[8][32];
    __shared__ float pooled[32];
    __shared__ float t1[64];
    __shared__ float t2[32];

    if (tid < 2) {
        int target = g + tid;
        int lo = 0, hi = N;
        while (lo < hi) {
            int mid = (lo + hi) >> 1;
            if (batch[mid] < target) lo = mid + 1; else hi = mid;
        }
        bounds[tid] = lo;
    }
    __syncthreads();
    int beg = bounds[0], end = bounds[1];

    int f = tid & 31, r = tid >> 5;
    float s = 0.f;
    for (int i = beg + r; i < end; i += 8) s += h[(size_t)i * 32 + f];
    red[r][f] = s;
    __syncthreads();

    if (tid < 32) {
        float t = 0.f;
#pragma unroll
        for (int k = 0; k < 8; ++k) t += red[k][tid];
        float invc = 1.f / fmaxf((float)(end - beg), 1.f);
        pooled[tid] = t * invc;
    }
    __syncthreads();

    if (tid < 64) {
        float a = fb1[tid];
#pragma unroll
        for (int k = 0; k < 32; ++k) a = fmaf(pooled[k], fw1[k * 64 + tid], a);
        t1[tid] = fmaxf(a, 0.f);
    }
    __syncthreads();
    if (tid < 32) {
        float a = fb2[tid];
#pragma unroll
        for (int k = 0; k < 64; ++k) a = fmaf(t1[k], fw2[k * 32 + tid], a);
        t2[tid] = fmaxf(a, 0.f);
    }
    __syncthreads();
    if (tid == 0) {
        float o = fb3[0];
#pragma unroll
        for (int k = 0; k < 32; ++k) o = fmaf(t2[k], fw3[k], o);
        out[g] = 1.f / (1.f + __expf(-o));
    }
}

// ---------------- host ----------------
extern "C" void kernel_launch(void* const* d_in, const int* in_sizes, int n_in,
                              void* d_out, int out_size, void* d_ws, size_t ws_size,
                              hipStream_t stream) {
    const float* x    = (const float*)d_in[0];
    const int*   ei   = (const int*)d_in[1];
    const int*   batch= (const int*)d_in[2];
    const float* w1   = (const float*)d_in[3];
    const float* as1  = (const float*)d_in[4];
    const float* ad1  = (const float*)d_in[5];
    const float* b1   = (const float*)d_in[6];
    const float* w2   = (const float*)d_in[7];
    const float* as2  = (const float*)d_in[8];
    const float* ad2  = (const float*)d_in[9];
    const float* b2   = (const float*)d_in[10];
    const float* w3   = (const float*)d_in[11];
    const float* as3  = (const float*)d_in[12];
    const float* ad3  = (const float*)d_in[13];
    const float* b3   = (const float*)d_in[14];
    const float* fw1  = (const float*)d_in[15];
    const float* fb1  = (const float*)d_in[16];
    const float* fw2  = (const float*)d_in[17];
    const float* fb2  = (const float*)d_in[18];
    const float* fw3  = (const float*)d_in[19];
    const float* fb3  = (const float*)d_in[20];
    float* outp = (float*)d_out;

    const int N = in_sizes[0] / 21;
    const int E = in_sizes[1] / 2;
    const int G = out_size;

    // ---- workspace carve ----
    char* p = (char*)d_ws;
    auto alloc = [&](size_t bytes) -> void* {
        void* r = (void*)p;
        p += (bytes + 255) & ~(size_t)255;
        return r;
    };
    int*   deg  = (int*)alloc((size_t)N * 4);
    int*   offs = (int*)alloc((size_t)(N + 1) * 4);
    int*   cur  = (int*)alloc((size_t)N * 4);
    int*   csr  = (int*)alloc((size_t)E * 4);
    unsigned short* hbfA = (unsigned short*)alloc((size_t)N * 256 * 2);
    unsigned short* hbfB = (unsigned short*)alloc((size_t)N * 256 * 2);
    float* h3   = (float*)alloc((size_t)N * 32 * 4);
    float* hP   = (float*)alloc((size_t)N * 32 * 4);
    float* asb  = (float*)alloc((size_t)N * 4 * 4);
    float* adb  = (float*)alloc((size_t)N * 4 * 4);
    unsigned short* w2p = (unsigned short*)alloc((size_t)256 * 256 * 2);
    unsigned short* w3p = (unsigned short*)alloc((size_t)256 * 32 * 2);

    const int* esrc = ei;
    const int* edst = ei + E;

    (void)hipMemsetAsync(deg, 0, (size_t)N * 4, stream);

    const int eb = (E + 255) / 256;

    // ---- CSR build + weight packs ----
    k_deg<<<eb, 256, 0, stream>>>(edst, deg, E);
    k_pack<<<(256 * 256 + 255) / 256, 256, 0, stream>>>(w2, w2p, 256, 256);
    k_pack<<<(256 * 32 + 255) / 256, 256, 0, stream>>>(w3, w3p, 256, 32);
    k_scan<<<1, 1024, 0, stream>>>(deg, offs, cur, N);
    k_scatter<<<eb, 256, 0, stream>>>(esrc, edst, cur, csr, E);

    const int gblk = (N + 63) / 64;

    // ---- layer 1 ----
    k_gemm1<<<(N + 7) / 8, 256, 0, stream>>>(x, w1, as1, ad1, hbfA, asb, adb, N);
    k_gather256<<<(N + 3) / 4, 256, 0, stream>>>(hbfA, asb, adb, offs, csr, b1, hbfB, N);

    // ---- layer 2 ----
    k_gemm2_mfma<<<gblk, 256, 0, stream>>>(hbfB, w2p, as2, ad2, hbfA, asb, adb, N);
    k_gather256<<<(N + 3) / 4, 256, 0, stream>>>(hbfA, asb, adb, offs, csr, b2, hbfB, N);

    // ---- layer 3 ----
    k_gemm3_mfma<<<gblk, 256, 0, stream>>>(hbfB, w3p, as3, ad3, h3, asb, adb, N);
    k_gather32<<<(N + 7) / 8, 256, 0, stream>>>(h3, asb, adb, offs, csr, b3, hP, N);

    // ---- fused pool + head ----
    k_pool_head<<<G, 256, 0, stream>>>(hP, batch, N, fw1, fb1, fw2, fb2, fw3, fb3, outp, G);
}

// Round 6
// 905.536 us; speedup vs baseline: 2.3431x; 1.2348x over previous
//
#include <hip/hip_runtime.h>
#include <math.h>

typedef float f4 __attribute__((ext_vector_type(4)));
typedef float f32x4 __attribute__((ext_vector_type(4)));
typedef short bf16x8 __attribute__((ext_vector_type(8)));
typedef unsigned short us4 __attribute__((ext_vector_type(4)));
typedef unsigned int u32x2 __attribute__((ext_vector_type(2)));

// ---------------- device helpers ----------------
__device__ __forceinline__ float lrelu(float x) { return x >= 0.f ? x : 0.2f * x; }
__device__ __forceinline__ float eluf(float x)  { return x > 0.f ? x : __expf(x) - 1.f; }

__device__ __forceinline__ float bf2f(unsigned short u) {
    union { unsigned int i; float f; } c; c.i = ((unsigned int)u) << 16; return c.f;
}
__device__ __forceinline__ unsigned short f2bf(float f) {
    union { float f; unsigned int i; } c; c.f = f;
    unsigned int r = c.i + 0x7fffu + ((c.i >> 16) & 1u);   // RNE
    return (unsigned short)(r >> 16);
}

// ---------------- CSR build ----------------
__global__ void k_deg(const int* __restrict__ dst, int* __restrict__ deg, int E) {
    int e = blockIdx.x * 256 + threadIdx.x;
    if (e < E) atomicAdd(&deg[dst[e]], 1);
}

// ---- multi-block exclusive scan over deg[N] -> offs[N+1], cursor[N] ----
// phase 1: per-block (1024-elem) sums
__global__ __launch_bounds__(1024) void k_scan1(const int* __restrict__ deg,
                                                int* __restrict__ bsum, int N) {
    int t = threadIdx.x;
    int i = blockIdx.x * 1024 + t;
    int v = (i < N) ? deg[i] : 0;
#pragma unroll
    for (int m = 32; m; m >>= 1) v += __shfl_xor(v, m);
    __shared__ int ws[16];
    if ((t & 63) == 0) ws[t >> 6] = v;
    __syncthreads();
    if (t < 16) {
        int s = ws[t];
#pragma unroll
        for (int m = 8; m; m >>= 1) s += __shfl_xor(s, m);
        if (t == 0) bsum[blockIdx.x] = s;
    }
}

// phase 2: exclusive scan of block sums (B <= 256), one block
__global__ void k_scan2(int* __restrict__ bsum, int B) {
    __shared__ int sm[256];
    int t = threadIdx.x;
    int v = (t < B) ? bsum[t] : 0;
    sm[t] = v;
    __syncthreads();
    for (int d = 1; d < 256; d <<= 1) {
        int x = (t >= d) ? sm[t - d] : 0;
        __syncthreads();
        sm[t] += x;
        __syncthreads();
    }
    if (t < B) bsum[t] = sm[t] - v;   // exclusive prefix of block sums
}

// phase 3: block-local exclusive scan + block prefix -> offs, cursor
__global__ __launch_bounds__(1024) void k_scan3(const int* __restrict__ deg,
                                                const int* __restrict__ bsum,
                                                int* __restrict__ offs,
                                                int* __restrict__ cursor, int N) {
    __shared__ int sm[1024];
    int t = threadIdx.x;
    int i = blockIdx.x * 1024 + t;
    int v = (i < N) ? deg[i] : 0;
    sm[t] = v;
    __syncthreads();
    for (int d = 1; d < 1024; d <<= 1) {
        int x = (t >= d) ? sm[t - d] : 0;
        __syncthreads();
        sm[t] += x;
        __syncthreads();
    }
    int pref = bsum[blockIdx.x] + sm[t] - v;   // exclusive
    if (i < N) { offs[i] = pref; cursor[i] = pref; }
    if (i == N - 1) offs[N] = pref + v;
}

__global__ void k_scatter(const int* __restrict__ src, const int* __restrict__ dst,
                          int* __restrict__ cur, int* __restrict__ csr, int E) {
    int e = blockIdx.x * 256 + threadIdx.x;
    if (e < E) {
        int p = atomicAdd(&cur[dst[e]], 1);
        csr[p] = src[e];
    }
}

// ---------------- weight pack: w[K][C] fp32 -> wp[((k>>3)*C + c)*8 + (k&7)] bf16 ----------------
__global__ void k_pack(const float* __restrict__ w, unsigned short* __restrict__ wp,
                       int K, int C) {
    int i = blockIdx.x * 256 + threadIdx.x;
    if (i < K * C) {
        int k = i / C, c = i % C;
        wp[((size_t)(k >> 3) * C + c) * 8 + (k & 7)] = f2bf(w[i]);
    }
}

// ---------------- L1 GEMM (VALU, K=21) ----------------
__global__ void k_gemm1(const float* __restrict__ x, const float* __restrict__ w,
                        const float* __restrict__ aw_s, const float* __restrict__ aw_d,
                        unsigned short* __restrict__ hbf, float* __restrict__ asb,
                        float* __restrict__ adb, int N) {
    int tid = threadIdx.x;
    int row0 = blockIdx.x * 8;
    __shared__ float xs[8][21];
    int nrows = min(8, N - row0);
    for (int i = tid; i < nrows * 21; i += 256) xs[i / 21][i % 21] = x[row0 * 21 + i];
    __syncthreads();
    float wreg[21];
#pragma unroll
    for (int k = 0; k < 21; ++k) wreg[k] = w[k * 256 + tid];
    float avs = aw_s[tid], avd = aw_d[tid];
    int head = tid >> 6;
    for (int r = 0; r < nrows; ++r) {
        float acc = 0.f;
#pragma unroll
        for (int k = 0; k < 21; ++k) acc = fmaf(xs[r][k], wreg[k], acc);
        hbf[(size_t)(row0 + r) * 256 + tid] = f2bf(acc);
        float s1 = acc * avs, s2 = acc * avd;
#pragma unroll
        for (int m = 32; m; m >>= 1) { s1 += __shfl_xor(s1, m); s2 += __shfl_xor(s2, m); }
        if ((tid & 63) == 0) {
            asb[(row0 + r) * 4 + head] = s1;
            adb[(row0 + r) * 4 + head] = s2;
        }
    }
}

// ---------------- L2 GEMM via MFMA ----------------
__global__ __launch_bounds__(256) void k_gemm2_mfma(
        const unsigned short* __restrict__ in, const unsigned short* __restrict__ w2p,
        const float* __restrict__ as2f, const float* __restrict__ ad2f,
        unsigned short* __restrict__ outbf, float* __restrict__ asb,
        float* __restrict__ adb, int N) {
    int tid = threadIdx.x;
    int wave = tid >> 6, lane = tid & 63;
    int g = lane >> 4, q = lane & 15;
    int row0 = blockIdx.x * 64 + wave * 16;

    f32x4 acc[16];
#pragma unroll
    for (int ct = 0; ct < 16; ++ct) acc[ct] = (f32x4)0.f;

    const unsigned short* aptr = in + (size_t)(row0 + q) * 256 + g * 8;
    const unsigned short* bptr = w2p + ((size_t)g * 256 + q) * 8;

#pragma unroll
    for (int kt = 0; kt < 8; ++kt) {
        bf16x8 a = *reinterpret_cast<const bf16x8*>(aptr + kt * 32);
#pragma unroll
        for (int ct = 0; ct < 16; ++ct) {
            bf16x8 b = *reinterpret_cast<const bf16x8*>(bptr + (size_t)kt * 8192 + ct * 128);
            acc[ct] = __builtin_amdgcn_mfma_f32_16x16x32_bf16(a, b, acc[ct], 0, 0, 0);
        }
    }

#pragma unroll
    for (int ct = 0; ct < 16; ++ct) {
        int col = ct * 16 + q;
#pragma unroll
        for (int r = 0; r < 4; ++r) {
            int row = row0 + 4 * g + r;
            if (row < N) outbf[(size_t)row * 256 + col] = f2bf(acc[ct][r]);
        }
    }

#pragma unroll
    for (int h = 0; h < 4; ++h) {
        float s1[4] = {0.f, 0.f, 0.f, 0.f}, s2[4] = {0.f, 0.f, 0.f, 0.f};
#pragma unroll
        for (int cc = 0; cc < 4; ++cc) {
            int ct = h * 4 + cc;
            int col = ct * 16 + q;
            float ws_ = as2f[col], wd_ = ad2f[col];
#pragma unroll
            for (int r = 0; r < 4; ++r) {
                s1[r] = fmaf(acc[ct][r], ws_, s1[r]);
                s2[r] = fmaf(acc[ct][r], wd_, s2[r]);
            }
        }
#pragma unroll
        for (int m = 1; m < 16; m <<= 1) {
#pragma unroll
            for (int r = 0; r < 4; ++r) {
                s1[r] += __shfl_xor(s1[r], m);
                s2[r] += __shfl_xor(s2[r], m);
            }
        }
        if (q == 0) {
#pragma unroll
            for (int r = 0; r < 4; ++r) {
                int row = row0 + 4 * g + r;
                if (row < N) { asb[row * 4 + h] = s1[r]; adb[row * 4 + h] = s2[r]; }
            }
        }
    }
}

// ---------------- L3 GEMM via MFMA ----------------
__global__ __launch_bounds__(256) void k_gemm3_mfma(
        const unsigned short* __restrict__ in, const unsigned short* __restrict__ w3p,
        const float* __restrict__ as3f, const float* __restrict__ ad3f,
        float* __restrict__ h3, float* __restrict__ asb, float* __restrict__ adb, int N) {
    int tid = threadIdx.x;
    int wave = tid >> 6, lane = tid & 63;
    int g = lane >> 4, q = lane & 15;
    int row0 = blockIdx.x * 64 + wave * 16;

    f32x4 acc[2];
    acc[0] = (f32x4)0.f; acc[1] = (f32x4)0.f;

    const unsigned short* aptr = in + (size_t)(row0 + q) * 256 + g * 8;
    const unsigned short* bptr = w3p + ((size_t)g * 32 + q) * 8;

#pragma unroll
    for (int kt = 0; kt < 8; ++kt) {
        bf16x8 a = *reinterpret_cast<const bf16x8*>(aptr + kt * 32);
#pragma unroll
        for (int ct = 0; ct < 2; ++ct) {
            bf16x8 b = *reinterpret_cast<const bf16x8*>(bptr + (size_t)kt * 1024 + ct * 128);
            acc[ct] = __builtin_amdgcn_mfma_f32_16x16x32_bf16(a, b, acc[ct], 0, 0, 0);
        }
    }

    float s1[4] = {0.f, 0.f, 0.f, 0.f}, s2[4] = {0.f, 0.f, 0.f, 0.f};
#pragma unroll
    for (int ct = 0; ct < 2; ++ct) {
        int col = ct * 16 + q;
        float ws_ = as3f[col], wd_ = ad3f[col];
#pragma unroll
        for (int r = 0; r < 4; ++r) {
            int row = row0 + 4 * g + r;
            if (row < N) h3[(size_t)row * 32 + col] = acc[ct][r];
            s1[r] = fmaf(acc[ct][r], ws_, s1[r]);
            s2[r] = fmaf(acc[ct][r], wd_, s2[r]);
        }
    }
#pragma unroll
    for (int m = 1; m < 16; m <<= 1) {
#pragma unroll
        for (int r = 0; r < 4; ++r) {
            s1[r] += __shfl_xor(s1[r], m);
            s2[r] += __shfl_xor(s2[r], m);
        }
    }
    if (q == 0) {
#pragma unroll
        for (int r = 0; r < 4; ++r) {
            int row = row0 + 4 * g + r;
            if (row < N) { asb[row] = s1[r]; adb[row] = s2[r]; }
        }
    }
}

// ---------------- gather (attention aggregate), F=256 bf16 -> bf16, 4 heads ----------------
__global__ void k_gather256(const unsigned short* __restrict__ hbf,
                            const float* __restrict__ asb, const float* __restrict__ adb,
                            const int* __restrict__ offs, const int* __restrict__ csr,
                            const float* __restrict__ bias, unsigned short* __restrict__ out,
                            int N) {
    int tid = threadIdx.x;
    int lane = tid & 63;
    int v = blockIdx.x * 4 + (tid >> 6);
    if (v >= N) return;
    int head = lane >> 4;
    float ad = adb[v * 4 + head];
    float s0 = asb[v * 4 + head] + ad;
    float w0 = __expf(lrelu(s0));
    float den = w0;
    float a0, a1, a2, a3;
    {
        us4 hv = *reinterpret_cast<const us4*>(&hbf[(size_t)v * 256 + 4 * lane]);
        a0 = w0 * bf2f(hv.x); a1 = w0 * bf2f(hv.y);
        a2 = w0 * bf2f(hv.z); a3 = w0 * bf2f(hv.w);
    }
    int beg = offs[v], end = offs[v + 1];
    for (int e = beg; e < end; ++e) {
        int u = csr[e];
        float wu = __expf(lrelu(asb[u * 4 + head] + ad));
        den += wu;
        us4 hv = *reinterpret_cast<const us4*>(&hbf[(size_t)u * 256 + 4 * lane]);
        a0 = fmaf(wu, bf2f(hv.x), a0); a1 = fmaf(wu, bf2f(hv.y), a1);
        a2 = fmaf(wu, bf2f(hv.z), a2); a3 = fmaf(wu, bf2f(hv.w), a3);
    }
    float inv = 1.f / (den + 1e-16f);
    int f0 = 4 * lane;
    unsigned int w01 = (unsigned int)f2bf(eluf(a0 * inv + bias[f0 + 0]))
                     | ((unsigned int)f2bf(eluf(a1 * inv + bias[f0 + 1])) << 16);
    unsigned int w23 = (unsigned int)f2bf(eluf(a2 * inv + bias[f0 + 2]))
                     | ((unsigned int)f2bf(eluf(a3 * inv + bias[f0 + 3])) << 16);
    u32x2 o; o.x = w01; o.y = w23;
    __builtin_nontemporal_store(o, reinterpret_cast<u32x2*>(&out[(size_t)v * 256 + f0]));
}

// ---------------- gather, F=32 fp32, 1 head ----------------
__global__ void k_gather32(const float* __restrict__ h, const float* __restrict__ asb,
                           const float* __restrict__ adb, const int* __restrict__ offs,
                           const int* __restrict__ csr, const float* __restrict__ bias,
                           float* __restrict__ out, int N) {
    int tid = threadIdx.x;
    int v = blockIdx.x * 8 + (tid >> 5);
    int c = tid & 31;
    if (v >= N) return;
    float ad = adb[v];
    float s0 = asb[v] + ad;
    float w0 = __expf(lrelu(s0));
    float den = w0;
    float acc = w0 * h[(size_t)v * 32 + c];
    int beg = offs[v], end = offs[v + 1];
    for (int e = beg; e < end; ++e) {
        int u = csr[e];
        float wu = __expf(lrelu(asb[u] + ad));
        den += wu;
        acc = fmaf(wu, h[(size_t)u * 32 + c], acc);
    }
    float o = eluf(acc / (den + 1e-16f) + bias[c]);
    __builtin_nontemporal_store(o, &out[(size_t)v * 32 + c]);
}

// ---------------- fused mean-pool + MLP head: one block per graph ----------------
__global__ __launch_bounds__(256) void k_pool_head(
        const float* __restrict__ h, const int* __restrict__ batch, int N,
        const float* __restrict__ fw1, const float* __restrict__ fb1,
        const float* __restrict__ fw2, const float* __restrict__ fb2,
        const float* __restrict__ fw3, const float* __restrict__ fb3,
        float* __restrict__ out, int G) {
    int g = blockIdx.x;
    int tid = threadIdx.x;
    __shared__ int bounds[2];
    __shared__ float red[8][32];
    __shared__ float pooled[32];
    __shared__ float t1[64];
    __shared__ float t2[32];

    if (tid < 2) {
        int target = g + tid;
        int lo = 0, hi = N;
        while (lo < hi) {
            int mid = (lo + hi) >> 1;
            if (batch[mid] < target) lo = mid + 1; else hi = mid;
        }
        bounds[tid] = lo;
    }
    __syncthreads();
    int beg = bounds[0], end = bounds[1];

    int f = tid & 31, r = tid >> 5;
    float s = 0.f;
    for (int i = beg + r; i < end; i += 8) s += h[(size_t)i * 32 + f];
    red[r][f] = s;
    __syncthreads();

    if (tid < 32) {
        float t = 0.f;
#pragma unroll
        for (int k = 0; k < 8; ++k) t += red[k][tid];
        float invc = 1.f / fmaxf((float)(end - beg), 1.f);
        pooled[tid] = t * invc;
    }
    __syncthreads();

    if (tid < 64) {
        float a = fb1[tid];
#pragma unroll
        for (int k = 0; k < 32; ++k) a = fmaf(pooled[k], fw1[k * 64 + tid], a);
        t1[tid] = fmaxf(a, 0.f);
    }
    __syncthreads();
    if (tid < 32) {
        float a = fb2[tid];
#pragma unroll
        for (int k = 0; k < 64; ++k) a = fmaf(t1[k], fw2[k * 32 + tid], a);
        t2[tid] = fmaxf(a, 0.f);
    }
    __syncthreads();
    if (tid == 0) {
        float o = fb3[0];
#pragma unroll
        for (int k = 0; k < 32; ++k) o = fmaf(t2[k], fw3[k], o);
        out[g] = 1.f / (1.f + __expf(-o));
    }
}

// ---------------- host ----------------
extern "C" void kernel_launch(void* const* d_in, const int* in_sizes, int n_in,
                              void* d_out, int out_size, void* d_ws, size_t ws_size,
                              hipStream_t stream) {
    const float* x    = (const float*)d_in[0];
    const int*   ei   = (const int*)d_in[1];
    const int*   batch= (const int*)d_in[2];
    const float* w1   = (const float*)d_in[3];
    const float* as1  = (const float*)d_in[4];
    const float* ad1  = (const float*)d_in[5];
    const float* b1   = (const float*)d_in[6];
    const float* w2   = (const float*)d_in[7];
    const float* as2  = (const float*)d_in[8];
    const float* ad2  = (const float*)d_in[9];
    const float* b2   = (const float*)d_in[10];
    const float* w3   = (const float*)d_in[11];
    const float* as3  = (const float*)d_in[12];
    const float* ad3  = (const float*)d_in[13];
    const float* b3   = (const float*)d_in[14];
    const float* fw1  = (const float*)d_in[15];
    const float* fb1  = (const float*)d_in[16];
    const float* fw2  = (const float*)d_in[17];
    const float* fb2  = (const float*)d_in[18];
    const float* fw3  = (const float*)d_in[19];
    const float* fb3  = (const float*)d_in[20];
    float* outp = (float*)d_out;

    const int N = in_sizes[0] / 21;
    const int E = in_sizes[1] / 2;
    const int G = out_size;

    // ---- workspace carve ----
    char* p = (char*)d_ws;
    auto alloc = [&](size_t bytes) -> void* {
        void* r = (void*)p;
        p += (bytes + 255) & ~(size_t)255;
        return r;
    };
    int*   deg  = (int*)alloc((size_t)N * 4);
    int*   offs = (int*)alloc((size_t)(N + 1) * 4);
    int*   cur  = (int*)alloc((size_t)N * 4);
    int*   csr  = (int*)alloc((size_t)E * 4);
    int*   bsum = (int*)alloc((size_t)256 * 4);
    unsigned short* hbfA = (unsigned short*)alloc((size_t)N * 256 * 2);
    unsigned short* hbfB = (unsigned short*)alloc((size_t)N * 256 * 2);
    float* h3   = (float*)alloc((size_t)N * 32 * 4);
    float* hP   = (float*)alloc((size_t)N * 32 * 4);
    float* asb  = (float*)alloc((size_t)N * 4 * 4);
    float* adb  = (float*)alloc((size_t)N * 4 * 4);
    unsigned short* w2p = (unsigned short*)alloc((size_t)256 * 256 * 2);
    unsigned short* w3p = (unsigned short*)alloc((size_t)256 * 32 * 2);

    const int* esrc = ei;
    const int* edst = ei + E;

    (void)hipMemsetAsync(deg, 0, (size_t)N * 4, stream);

    const int eb = (E + 255) / 256;
    const int sb = (N + 1023) / 1024;   // scan blocks (<= 256)

    // ---- CSR build + weight packs ----
    k_deg<<<eb, 256, 0, stream>>>(edst, deg, E);
    k_pack<<<(256 * 256 + 255) / 256, 256, 0, stream>>>(w2, w2p, 256, 256);
    k_pack<<<(256 * 32 + 255) / 256, 256, 0, stream>>>(w3, w3p, 256, 32);
    k_scan1<<<sb, 1024, 0, stream>>>(deg, bsum, N);
    k_scan2<<<1, 256, 0, stream>>>(bsum, sb);
    k_scan3<<<sb, 1024, 0, stream>>>(deg, bsum, offs, cur, N);
    k_scatter<<<eb, 256, 0, stream>>>(esrc, edst, cur, csr, E);

    const int gblk = (N + 63) / 64;

    // ---- layer 1 ----
    k_gemm1<<<(N + 7) / 8, 256, 0, stream>>>(x, w1, as1, ad1, hbfA, asb, adb, N);
    k_gather256<<<(N + 3) / 4, 256, 0, stream>>>(hbfA, asb, adb, offs, csr, b1, hbfB, N);

    // ---- layer 2 ----
    k_gemm2_mfma<<<gblk, 256, 0, stream>>>(hbfB, w2p, as2, ad2, hbfA, asb, adb, N);
    k_gather256<<<(N + 3) / 4, 256, 0, stream>>>(hbfA, asb, adb, offs, csr, b2, hbfB, N);

    // ---- layer 3 ----
    k_gemm3_mfma<<<gblk, 256, 0, stream>>>(hbfB, w3p, as3, ad3, h3, asb, adb, N);
    k_gather32<<<(N + 7) / 8, 256, 0, stream>>>(h3, asb, adb, offs, csr, b3, hP, N);

    // ---- fused pool + head ----
    k_pool_head<<<G, 256, 0, stream>>>(hP, batch, N, fw1, fb1, fw2, fb2, fw3, fb3, outp, G);
}

// Round 7
// 785.348 us; speedup vs baseline: 2.7016x; 1.1530x over previous
//
#include <hip/hip_runtime.h>
#include <math.h>

typedef float f4 __attribute__((ext_vector_type(4)));
typedef float f32x4 __attribute__((ext_vector_type(4)));
typedef short bf16x8 __attribute__((ext_vector_type(8)));
typedef unsigned short us4 __attribute__((ext_vector_type(4)));
typedef unsigned int u32x2 __attribute__((ext_vector_type(2)));

// ---------------- device helpers ----------------
__device__ __forceinline__ float lrelu(float x) { return x >= 0.f ? x : 0.2f * x; }
__device__ __forceinline__ float eluf(float x)  { return x > 0.f ? x : __expf(x) - 1.f; }

__device__ __forceinline__ float bf2f(unsigned short u) {
    union { unsigned int i; float f; } c; c.i = ((unsigned int)u) << 16; return c.f;
}
__device__ __forceinline__ unsigned short f2bf(float f) {
    union { float f; unsigned int i; } c; c.f = f;
    unsigned int r = c.i + 0x7fffu + ((c.i >> 16) & 1u);   // RNE
    return (unsigned short)(r >> 16);
}

// ---------------- CSR build ----------------
__global__ void k_deg(const int* __restrict__ dst, int* __restrict__ deg, int E) {
    int e = blockIdx.x * 256 + threadIdx.x;
    if (e < E) atomicAdd(&deg[dst[e]], 1);
}

// ---- multi-block exclusive scan over deg[N] -> offs[N+1], cursor[N] ----
__global__ __launch_bounds__(1024) void k_scan1(const int* __restrict__ deg,
                                                int* __restrict__ bsum, int N) {
    int t = threadIdx.x;
    int i = blockIdx.x * 1024 + t;
    int v = (i < N) ? deg[i] : 0;
#pragma unroll
    for (int m = 32; m; m >>= 1) v += __shfl_xor(v, m);
    __shared__ int ws[16];
    if ((t & 63) == 0) ws[t >> 6] = v;
    __syncthreads();
    if (t < 16) {
        int s = ws[t];
#pragma unroll
        for (int m = 8; m; m >>= 1) s += __shfl_xor(s, m);
        if (t == 0) bsum[blockIdx.x] = s;
    }
}

__global__ void k_scan2(int* __restrict__ bsum, int B) {
    __shared__ int sm[256];
    int t = threadIdx.x;
    int v = (t < B) ? bsum[t] : 0;
    sm[t] = v;
    __syncthreads();
    for (int d = 1; d < 256; d <<= 1) {
        int x = (t >= d) ? sm[t - d] : 0;
        __syncthreads();
        sm[t] += x;
        __syncthreads();
    }
    if (t < B) bsum[t] = sm[t] - v;
}

__global__ __launch_bounds__(1024) void k_scan3(const int* __restrict__ deg,
                                                const int* __restrict__ bsum,
                                                int* __restrict__ offs,
                                                int* __restrict__ cursor, int N) {
    __shared__ int sm[1024];
    int t = threadIdx.x;
    int i = blockIdx.x * 1024 + t;
    int v = (i < N) ? deg[i] : 0;
    sm[t] = v;
    __syncthreads();
    for (int d = 1; d < 1024; d <<= 1) {
        int x = (t >= d) ? sm[t - d] : 0;
        __syncthreads();
        sm[t] += x;
        __syncthreads();
    }
    int pref = bsum[blockIdx.x] + sm[t] - v;
    if (i < N) { offs[i] = pref; cursor[i] = pref; }
    if (i == N - 1) offs[N] = pref + v;
}

__global__ void k_scatter(const int* __restrict__ src, const int* __restrict__ dst,
                          int* __restrict__ cur, int* __restrict__ csr, int E) {
    int e = blockIdx.x * 256 + threadIdx.x;
    if (e < E) {
        int p = atomicAdd(&cur[dst[e]], 1);
        csr[p] = src[e];
    }
}

// ---------------- weight pack ----------------
__global__ void k_pack(const float* __restrict__ w, unsigned short* __restrict__ wp,
                       int K, int C) {
    int i = blockIdx.x * 256 + threadIdx.x;
    if (i < K * C) {
        int k = i / C, c = i % C;
        wp[((size_t)(k >> 3) * C + c) * 8 + (k & 7)] = f2bf(w[i]);
    }
}

// ---------------- L1 GEMM (VALU, K=21) ----------------
__global__ void k_gemm1(const float* __restrict__ x, const float* __restrict__ w,
                        const float* __restrict__ aw_s, const float* __restrict__ aw_d,
                        unsigned short* __restrict__ hbf, float* __restrict__ asb,
                        float* __restrict__ adb, int N) {
    int tid = threadIdx.x;
    int row0 = blockIdx.x * 8;
    __shared__ float xs[8][21];
    int nrows = min(8, N - row0);
    for (int i = tid; i < nrows * 21; i += 256) xs[i / 21][i % 21] = x[row0 * 21 + i];
    __syncthreads();
    float wreg[21];
#pragma unroll
    for (int k = 0; k < 21; ++k) wreg[k] = w[k * 256 + tid];
    float avs = aw_s[tid], avd = aw_d[tid];
    int head = tid >> 6;
    for (int r = 0; r < nrows; ++r) {
        float acc = 0.f;
#pragma unroll
        for (int k = 0; k < 21; ++k) acc = fmaf(xs[r][k], wreg[k], acc);
        hbf[(size_t)(row0 + r) * 256 + tid] = f2bf(acc);
        float s1 = acc * avs, s2 = acc * avd;
#pragma unroll
        for (int m = 32; m; m >>= 1) { s1 += __shfl_xor(s1, m); s2 += __shfl_xor(s2, m); }
        if ((tid & 63) == 0) {
            asb[(row0 + r) * 4 + head] = s1;
            adb[(row0 + r) * 4 + head] = s2;
        }
    }
}

// ---------------- L2 GEMM via MFMA ----------------
__global__ __launch_bounds__(256) void k_gemm2_mfma(
        const unsigned short* __restrict__ in, const unsigned short* __restrict__ w2p,
        const float* __restrict__ as2f, const float* __restrict__ ad2f,
        unsigned short* __restrict__ outbf, float* __restrict__ asb,
        float* __restrict__ adb, int N) {
    int tid = threadIdx.x;
    int wave = tid >> 6, lane = tid & 63;
    int g = lane >> 4, q = lane & 15;
    int row0 = blockIdx.x * 64 + wave * 16;

    f32x4 acc[16];
#pragma unroll
    for (int ct = 0; ct < 16; ++ct) acc[ct] = (f32x4)0.f;

    const unsigned short* aptr = in + (size_t)(row0 + q) * 256 + g * 8;
    const unsigned short* bptr = w2p + ((size_t)g * 256 + q) * 8;

#pragma unroll
    for (int kt = 0; kt < 8; ++kt) {
        bf16x8 a = *reinterpret_cast<const bf16x8*>(aptr + kt * 32);
#pragma unroll
        for (int ct = 0; ct < 16; ++ct) {
            bf16x8 b = *reinterpret_cast<const bf16x8*>(bptr + (size_t)kt * 8192 + ct * 128);
            acc[ct] = __builtin_amdgcn_mfma_f32_16x16x32_bf16(a, b, acc[ct], 0, 0, 0);
        }
    }

#pragma unroll
    for (int ct = 0; ct < 16; ++ct) {
        int col = ct * 16 + q;
#pragma unroll
        for (int r = 0; r < 4; ++r) {
            int row = row0 + 4 * g + r;
            if (row < N) outbf[(size_t)row * 256 + col] = f2bf(acc[ct][r]);
        }
    }

#pragma unroll
    for (int h = 0; h < 4; ++h) {
        float s1[4] = {0.f, 0.f, 0.f, 0.f}, s2[4] = {0.f, 0.f, 0.f, 0.f};
#pragma unroll
        for (int cc = 0; cc < 4; ++cc) {
            int ct = h * 4 + cc;
            int col = ct * 16 + q;
            float ws_ = as2f[col], wd_ = ad2f[col];
#pragma unroll
            for (int r = 0; r < 4; ++r) {
                s1[r] = fmaf(acc[ct][r], ws_, s1[r]);
                s2[r] = fmaf(acc[ct][r], wd_, s2[r]);
            }
        }
#pragma unroll
        for (int m = 1; m < 16; m <<= 1) {
#pragma unroll
            for (int r = 0; r < 4; ++r) {
                s1[r] += __shfl_xor(s1[r], m);
                s2[r] += __shfl_xor(s2[r], m);
            }
        }
        if (q == 0) {
#pragma unroll
            for (int r = 0; r < 4; ++r) {
                int row = row0 + 4 * g + r;
                if (row < N) { asb[row * 4 + h] = s1[r]; adb[row * 4 + h] = s2[r]; }
            }
        }
    }
}

// ---------------- L3 GEMM via MFMA ----------------
__global__ __launch_bounds__(256) void k_gemm3_mfma(
        const unsigned short* __restrict__ in, const unsigned short* __restrict__ w3p,
        const float* __restrict__ as3f, const float* __restrict__ ad3f,
        float* __restrict__ h3, float* __restrict__ asb, float* __restrict__ adb, int N) {
    int tid = threadIdx.x;
    int wave = tid >> 6, lane = tid & 63;
    int g = lane >> 4, q = lane & 15;
    int row0 = blockIdx.x * 64 + wave * 16;

    f32x4 acc[2];
    acc[0] = (f32x4)0.f; acc[1] = (f32x4)0.f;

    const unsigned short* aptr = in + (size_t)(row0 + q) * 256 + g * 8;
    const unsigned short* bptr = w3p + ((size_t)g * 32 + q) * 8;

#pragma unroll
    for (int kt = 0; kt < 8; ++kt) {
        bf16x8 a = *reinterpret_cast<const bf16x8*>(aptr + kt * 32);
#pragma unroll
        for (int ct = 0; ct < 2; ++ct) {
            bf16x8 b = *reinterpret_cast<const bf16x8*>(bptr + (size_t)kt * 1024 + ct * 128);
            acc[ct] = __builtin_amdgcn_mfma_f32_16x16x32_bf16(a, b, acc[ct], 0, 0, 0);
        }
    }

    float s1[4] = {0.f, 0.f, 0.f, 0.f}, s2[4] = {0.f, 0.f, 0.f, 0.f};
#pragma unroll
    for (int ct = 0; ct < 2; ++ct) {
        int col = ct * 16 + q;
        float ws_ = as3f[col], wd_ = ad3f[col];
#pragma unroll
        for (int r = 0; r < 4; ++r) {
            int row = row0 + 4 * g + r;
            if (row < N) h3[(size_t)row * 32 + col] = acc[ct][r];
            s1[r] = fmaf(acc[ct][r], ws_, s1[r]);
            s2[r] = fmaf(acc[ct][r], wd_, s2[r]);
        }
    }
#pragma unroll
    for (int m = 1; m < 16; m <<= 1) {
#pragma unroll
        for (int r = 0; r < 4; ++r) {
            s1[r] += __shfl_xor(s1[r], m);
            s2[r] += __shfl_xor(s2[r], m);
        }
    }
    if (q == 0) {
#pragma unroll
        for (int r = 0; r < 4; ++r) {
            int row = row0 + 4 * g + r;
            if (row < N) { asb[row] = s1[r]; adb[row] = s2[r]; }
        }
    }
}

// ---------------- gather (attention aggregate), F=256 bf16 -> bf16, 4 heads ----------------
// chunked edge loop: lane (h*16+j) computes weight of edge c+j for head h; then the
// 16-step unrolled inner loop shfl-broadcasts (w,u) and issues 16 independent row loads.
__global__ void k_gather256(const unsigned short* __restrict__ hbf,
                            const float* __restrict__ asb, const float* __restrict__ adb,
                            const int* __restrict__ offs, const int* __restrict__ csr,
                            const float* __restrict__ bias, unsigned short* __restrict__ out,
                            int N) {
    int tid = threadIdx.x;
    int lane = tid & 63;
    int v = blockIdx.x * 4 + (tid >> 6);
    if (v >= N) return;
    int head = lane >> 4;
    int j16 = lane & 15;
    int gbase = lane & 48;          // head-group base lane
    float ad = adb[v * 4 + head];
    float s0 = asb[v * 4 + head] + ad;
    float w0 = __expf(lrelu(s0));
    float den = w0;
    float a0, a1, a2, a3;
    {
        us4 hv = *reinterpret_cast<const us4*>(&hbf[(size_t)v * 256 + 4 * lane]);
        a0 = w0 * bf2f(hv.x); a1 = w0 * bf2f(hv.y);
        a2 = w0 * bf2f(hv.z); a3 = w0 * bf2f(hv.w);
    }
    int beg = offs[v], end = offs[v + 1];
    for (int c = beg; c < end; c += 16) {
        int idx = c + j16;
        int u = 0;
        float w = 0.f;
        if (idx < end) {
            u = csr[idx];
            w = __expf(lrelu(asb[u * 4 + head] + ad));
        }
#pragma unroll
        for (int j = 0; j < 16; ++j) {
            float wj = __shfl(w, gbase | j);
            int   uj = __shfl(u, gbase | j);
            den += wj;
            us4 hj = *reinterpret_cast<const us4*>(&hbf[(size_t)uj * 256 + 4 * lane]);
            a0 = fmaf(wj, bf2f(hj.x), a0); a1 = fmaf(wj, bf2f(hj.y), a1);
            a2 = fmaf(wj, bf2f(hj.z), a2); a3 = fmaf(wj, bf2f(hj.w), a3);
        }
    }
    float inv = 1.f / (den + 1e-16f);
    int f0 = 4 * lane;
    unsigned int w01 = (unsigned int)f2bf(eluf(a0 * inv + bias[f0 + 0]))
                     | ((unsigned int)f2bf(eluf(a1 * inv + bias[f0 + 1])) << 16);
    unsigned int w23 = (unsigned int)f2bf(eluf(a2 * inv + bias[f0 + 2]))
                     | ((unsigned int)f2bf(eluf(a3 * inv + bias[f0 + 3])) << 16);
    u32x2 o; o.x = w01; o.y = w23;
    __builtin_nontemporal_store(o, reinterpret_cast<u32x2*>(&out[(size_t)v * 256 + f0]));
}

// ---------------- gather, F=32 fp32, 1 head ----------------
__global__ void k_gather32(const float* __restrict__ h, const float* __restrict__ asb,
                           const float* __restrict__ adb, const int* __restrict__ offs,
                           const int* __restrict__ csr, const float* __restrict__ bias,
                           float* __restrict__ out, int N) {
    int tid = threadIdx.x;
    int v = blockIdx.x * 8 + (tid >> 5);
    int c = tid & 31;
    if (v >= N) return;
    float ad = adb[v];
    float s0 = asb[v] + ad;
    float w0 = __expf(lrelu(s0));
    float den = w0;
    float acc = w0 * h[(size_t)v * 32 + c];
    int beg = offs[v], end = offs[v + 1];
    for (int e = beg; e < end; ++e) {
        int u = csr[e];
        float wu = __expf(lrelu(asb[u] + ad));
        den += wu;
        acc = fmaf(wu, h[(size_t)u * 32 + c], acc);
    }
    float o = eluf(acc / (den + 1e-16f) + bias[c]);
    __builtin_nontemporal_store(o, &out[(size_t)v * 32 + c]);
}

// ---------------- fused mean-pool + MLP head ----------------
__global__ __launch_bounds__(256) void k_pool_head(
        const float* __restrict__ h, const int* __restrict__ batch, int N,
        const float* __restrict__ fw1, const float* __restrict__ fb1,
        const float* __restrict__ fw2, const float* __restrict__ fb2,
        const float* __restrict__ fw3, const float* __restrict__ fb3,
        float* __restrict__ out, int G) {
    int g = blockIdx.x;
    int tid = threadIdx.x;
    __shared__ int bounds[2];
    __shared__ float red[8][32];
    __shared__ float pooled[32];
    __shared__ float t1[64];
    __shared__ float t2[32];

    if (tid < 2) {
        int target = g + tid;
        int lo = 0, hi = N;
        while (lo < hi) {
            int mid = (lo + hi) >> 1;
            if (batch[mid] < target) lo = mid + 1; else hi = mid;
        }
        bounds[tid] = lo;
    }
    __syncthreads();
    int beg = bounds[0], end = bounds[1];

    int f = tid & 31, r = tid >> 5;
    float s = 0.f;
    for (int i = beg + r; i < end; i += 8) s += h[(size_t)i * 32 + f];
    red[r][f] = s;
    __syncthreads();

    if (tid < 32) {
        float t = 0.f;
#pragma unroll
        for (int k = 0; k < 8; ++k) t += red[k][tid];
        float invc = 1.f / fmaxf((float)(end - beg), 1.f);
        pooled[tid] = t * invc;
    }
    __syncthreads();

    if (tid < 64) {
        float a = fb1[tid];
#pragma unroll
        for (int k = 0; k < 32; ++k) a = fmaf(pooled[k], fw1[k * 64 + tid], a);
        t1[tid] = fmaxf(a, 0.f);
    }
    __syncthreads();
    if (tid < 32) {
        float a = fb2[tid];
#pragma unroll
        for (int k = 0; k < 64; ++k) a = fmaf(t1[k], fw2[k * 32 + tid], a);
        t2[tid] = fmaxf(a, 0.f);
    }
    __syncthreads();
    if (tid == 0) {
        float o = fb3[0];
#pragma unroll
        for (int k = 0; k < 32; ++k) o = fmaf(t2[k], fw3[k], o);
        out[g] = 1.f / (1.f + __expf(-o));
    }
}

// ---------------- host ----------------
extern "C" void kernel_launch(void* const* d_in, const int* in_sizes, int n_in,
                              void* d_out, int out_size, void* d_ws, size_t ws_size,
                              hipStream_t stream) {
    const float* x    = (const float*)d_in[0];
    const int*   ei   = (const int*)d_in[1];
    const int*   batch= (const int*)d_in[2];
    const float* w1   = (const float*)d_in[3];
    const float* as1  = (const float*)d_in[4];
    const float* ad1  = (const float*)d_in[5];
    const float* b1   = (const float*)d_in[6];
    const float* w2   = (const float*)d_in[7];
    const float* as2  = (const float*)d_in[8];
    const float* ad2  = (const float*)d_in[9];
    const float* b2   = (const float*)d_in[10];
    const float* w3   = (const float*)d_in[11];
    const float* as3  = (const float*)d_in[12];
    const float* ad3  = (const float*)d_in[13];
    const float* b3   = (const float*)d_in[14];
    const float* fw1  = (const float*)d_in[15];
    const float* fb1  = (const float*)d_in[16];
    const float* fw2  = (const float*)d_in[17];
    const float* fb2  = (const float*)d_in[18];
    const float* fw3  = (const float*)d_in[19];
    const float* fb3  = (const float*)d_in[20];
    float* outp = (float*)d_out;

    const int N = in_sizes[0] / 21;
    const int E = in_sizes[1] / 2;
    const int G = out_size;

    // ---- workspace carve ----
    char* p = (char*)d_ws;
    auto alloc = [&](size_t bytes) -> void* {
        void* r = (void*)p;
        p += (bytes + 255) & ~(size_t)255;
        return r;
    };
    int*   deg  = (int*)alloc((size_t)N * 4);
    int*   offs = (int*)alloc((size_t)(N + 1) * 4);
    int*   cur  = (int*)alloc((size_t)N * 4);
    int*   csr  = (int*)alloc((size_t)E * 4);
    int*   bsum = (int*)alloc((size_t)256 * 4);
    unsigned short* hbfA = (unsigned short*)alloc((size_t)N * 256 * 2);
    unsigned short* hbfB = (unsigned short*)alloc((size_t)N * 256 * 2);
    float* h3   = (float*)alloc((size_t)N * 32 * 4);
    float* hP   = (float*)alloc((size_t)N * 32 * 4);
    float* asb  = (float*)alloc((size_t)N * 4 * 4);
    float* adb  = (float*)alloc((size_t)N * 4 * 4);
    unsigned short* w2p = (unsigned short*)alloc((size_t)256 * 256 * 2);
    unsigned short* w3p = (unsigned short*)alloc((size_t)256 * 32 * 2);

    const int* esrc = ei;
    const int* edst = ei + E;

    (void)hipMemsetAsync(deg, 0, (size_t)N * 4, stream);

    const int eb = (E + 255) / 256;
    const int sb = (N + 1023) / 1024;

    // ---- CSR build + weight packs ----
    k_deg<<<eb, 256, 0, stream>>>(edst, deg, E);
    k_pack<<<(256 * 256 + 255) / 256, 256, 0, stream>>>(w2, w2p, 256, 256);
    k_pack<<<(256 * 32 + 255) / 256, 256, 0, stream>>>(w3, w3p, 256, 32);
    k_scan1<<<sb, 1024, 0, stream>>>(deg, bsum, N);
    k_scan2<<<1, 256, 0, stream>>>(bsum, sb);
    k_scan3<<<sb, 1024, 0, stream>>>(deg, bsum, offs, cur, N);
    k_scatter<<<eb, 256, 0, stream>>>(esrc, edst, cur, csr, E);

    const int gblk = (N + 63) / 64;

    // ---- layer 1 ----
    k_gemm1<<<(N + 7) / 8, 256, 0, stream>>>(x, w1, as1, ad1, hbfA, asb, adb, N);
    k_gather256<<<(N + 3) / 4, 256, 0, stream>>>(hbfA, asb, adb, offs, csr, b1, hbfB, N);

    // ---- layer 2 ----
    k_gemm2_mfma<<<gblk, 256, 0, stream>>>(hbfB, w2p, as2, ad2, hbfA, asb, adb, N);
    k_gather256<<<(N + 3) / 4, 256, 0, stream>>>(hbfA, asb, adb, offs, csr, b2, hbfB, N);

    // ---- layer 3 ----
    k_gemm3_mfma<<<gblk, 256, 0, stream>>>(hbfB, w3p, as3, ad3, h3, asb, adb, N);
    k_gather32<<<(N + 7) / 8, 256, 0, stream>>>(h3, asb, adb, offs, csr, b3, hP, N);

    // ---- fused pool + head ----
    k_pool_head<<<G, 256, 0, stream>>>(hP, batch, N, fw1, fb1, fw2, fb2, fw3, fb3, outp, G);
}

// Round 8
// 666.406 us; speedup vs baseline: 3.1838x; 1.1785x over previous
//
#include <hip/hip_runtime.h>
#include <math.h>

typedef float f4 __attribute__((ext_vector_type(4)));
typedef float f32x4 __attribute__((ext_vector_type(4)));
typedef float f32x2 __attribute__((ext_vector_type(2)));
typedef short bf16x8 __attribute__((ext_vector_type(8)));
typedef unsigned int u32x2 __attribute__((ext_vector_type(2)));

// ---------------- device helpers ----------------
__device__ __forceinline__ float lrelu(float x) { return x >= 0.f ? x : 0.2f * x; }
__device__ __forceinline__ float eluf(float x)  { return x > 0.f ? x : __expf(x) - 1.f; }

__device__ __forceinline__ float bf2f(unsigned short u) {
    union { unsigned int i; float f; } c; c.i = ((unsigned int)u) << 16; return c.f;
}
__device__ __forceinline__ unsigned short f2bf(float f) {
    union { float f; unsigned int i; } c; c.f = f;
    unsigned int r = c.i + 0x7fffu + ((c.i >> 16) & 1u);   // RNE
    return (unsigned short)(r >> 16);
}
__device__ __forceinline__ unsigned char f2f8(float f) {
    return (unsigned char)(__builtin_amdgcn_cvt_pk_fp8_f32(f, f, 0u, false) & 0xffu);
}

// ---------------- CSR build ----------------
__global__ void k_deg(const int* __restrict__ dst, int* __restrict__ deg, int E) {
    int e = blockIdx.x * 256 + threadIdx.x;
    if (e < E) atomicAdd(&deg[dst[e]], 1);
}

// ---- multi-block exclusive scan over deg[N] -> offs[N+1], cursor[N] ----
__global__ __launch_bounds__(1024) void k_scan1(const int* __restrict__ deg,
                                                int* __restrict__ bsum, int N) {
    int t = threadIdx.x;
    int i = blockIdx.x * 1024 + t;
    int v = (i < N) ? deg[i] : 0;
#pragma unroll
    for (int m = 32; m; m >>= 1) v += __shfl_xor(v, m);
    __shared__ int ws[16];
    if ((t & 63) == 0) ws[t >> 6] = v;
    __syncthreads();
    if (t < 16) {
        int s = ws[t];
#pragma unroll
        for (int m = 8; m; m >>= 1) s += __shfl_xor(s, m);
        if (t == 0) bsum[blockIdx.x] = s;
    }
}

__global__ void k_scan2(int* __restrict__ bsum, int B) {
    __shared__ int sm[256];
    int t = threadIdx.x;
    int v = (t < B) ? bsum[t] : 0;
    sm[t] = v;
    __syncthreads();
    for (int d = 1; d < 256; d <<= 1) {
        int x = (t >= d) ? sm[t - d] : 0;
        __syncthreads();
        sm[t] += x;
        __syncthreads();
    }
    if (t < B) bsum[t] = sm[t] - v;
}

__global__ __launch_bounds__(1024) void k_scan3(const int* __restrict__ deg,
                                                const int* __restrict__ bsum,
                                                int* __restrict__ offs,
                                                int* __restrict__ cursor, int N) {
    __shared__ int sm[1024];
    int t = threadIdx.x;
    int i = blockIdx.x * 1024 + t;
    int v = (i < N) ? deg[i] : 0;
    sm[t] = v;
    __syncthreads();
    for (int d = 1; d < 1024; d <<= 1) {
        int x = (t >= d) ? sm[t - d] : 0;
        __syncthreads();
        sm[t] += x;
        __syncthreads();
    }
    int pref = bsum[blockIdx.x] + sm[t] - v;
    if (i < N) { offs[i] = pref; cursor[i] = pref; }
    if (i == N - 1) offs[N] = pref + v;
}

__global__ void k_scatter(const int* __restrict__ src, const int* __restrict__ dst,
                          int* __restrict__ cur, int* __restrict__ csr, int E) {
    int e = blockIdx.x * 256 + threadIdx.x;
    if (e < E) {
        int p = atomicAdd(&cur[dst[e]], 1);
        csr[p] = src[e];
    }
}

// ---------------- weight pack ----------------
__global__ void k_pack(const float* __restrict__ w, unsigned short* __restrict__ wp,
                       int K, int C) {
    int i = blockIdx.x * 256 + threadIdx.x;
    if (i < K * C) {
        int k = i / C, c = i % C;
        wp[((size_t)(k >> 3) * C + c) * 8 + (k & 7)] = f2bf(w[i]);
    }
}

// ---------------- L1 GEMM (VALU, K=21) -> h fp8 + scores ----------------
__global__ void k_gemm1(const float* __restrict__ x, const float* __restrict__ w,
                        const float* __restrict__ aw_s, const float* __restrict__ aw_d,
                        unsigned char* __restrict__ h8, float* __restrict__ asb,
                        float* __restrict__ adb, int N) {
    int tid = threadIdx.x;
    int row0 = blockIdx.x * 8;
    __shared__ float xs[8][21];
    int nrows = min(8, N - row0);
    for (int i = tid; i < nrows * 21; i += 256) xs[i / 21][i % 21] = x[row0 * 21 + i];
    __syncthreads();
    float wreg[21];
#pragma unroll
    for (int k = 0; k < 21; ++k) wreg[k] = w[k * 256 + tid];
    float avs = aw_s[tid], avd = aw_d[tid];
    int head = tid >> 6;
    for (int r = 0; r < nrows; ++r) {
        float acc = 0.f;
#pragma unroll
        for (int k = 0; k < 21; ++k) acc = fmaf(xs[r][k], wreg[k], acc);
        h8[(size_t)(row0 + r) * 256 + tid] = f2f8(acc);
        float s1 = acc * avs, s2 = acc * avd;
#pragma unroll
        for (int m = 32; m; m >>= 1) { s1 += __shfl_xor(s1, m); s2 += __shfl_xor(s2, m); }
        if ((tid & 63) == 0) {
            asb[(row0 + r) * 4 + head] = s1;
            adb[(row0 + r) * 4 + head] = s2;
        }
    }
}

// ---------------- L2 GEMM via MFMA: in bf16 -> h fp8 + scores ----------------
__global__ __launch_bounds__(256) void k_gemm2_mfma(
        const unsigned short* __restrict__ in, const unsigned short* __restrict__ w2p,
        const float* __restrict__ as2f, const float* __restrict__ ad2f,
        unsigned char* __restrict__ h8, float* __restrict__ asb,
        float* __restrict__ adb, int N) {
    int tid = threadIdx.x;
    int wave = tid >> 6, lane = tid & 63;
    int g = lane >> 4, q = lane & 15;
    int row0 = blockIdx.x * 64 + wave * 16;

    f32x4 acc[16];
#pragma unroll
    for (int ct = 0; ct < 16; ++ct) acc[ct] = (f32x4)0.f;

    const unsigned short* aptr = in + (size_t)(row0 + q) * 256 + g * 8;
    const unsigned short* bptr = w2p + ((size_t)g * 256 + q) * 8;

#pragma unroll
    for (int kt = 0; kt < 8; ++kt) {
        bf16x8 a = *reinterpret_cast<const bf16x8*>(aptr + kt * 32);
#pragma unroll
        for (int ct = 0; ct < 16; ++ct) {
            bf16x8 b = *reinterpret_cast<const bf16x8*>(bptr + (size_t)kt * 8192 + ct * 128);
            acc[ct] = __builtin_amdgcn_mfma_f32_16x16x32_bf16(a, b, acc[ct], 0, 0, 0);
        }
    }

#pragma unroll
    for (int ct = 0; ct < 16; ++ct) {
        int col = ct * 16 + q;
#pragma unroll
        for (int r = 0; r < 4; ++r) {
            int row = row0 + 4 * g + r;
            if (row < N) h8[(size_t)row * 256 + col] = f2f8(acc[ct][r]);
        }
    }

#pragma unroll
    for (int h = 0; h < 4; ++h) {
        float s1[4] = {0.f, 0.f, 0.f, 0.f}, s2[4] = {0.f, 0.f, 0.f, 0.f};
#pragma unroll
        for (int cc = 0; cc < 4; ++cc) {
            int ct = h * 4 + cc;
            int col = ct * 16 + q;
            float ws_ = as2f[col], wd_ = ad2f[col];
#pragma unroll
            for (int r = 0; r < 4; ++r) {
                s1[r] = fmaf(acc[ct][r], ws_, s1[r]);
                s2[r] = fmaf(acc[ct][r], wd_, s2[r]);
            }
        }
#pragma unroll
        for (int m = 1; m < 16; m <<= 1) {
#pragma unroll
            for (int r = 0; r < 4; ++r) {
                s1[r] += __shfl_xor(s1[r], m);
                s2[r] += __shfl_xor(s2[r], m);
            }
        }
        if (q == 0) {
#pragma unroll
            for (int r = 0; r < 4; ++r) {
                int row = row0 + 4 * g + r;
                if (row < N) { asb[row * 4 + h] = s1[r]; adb[row * 4 + h] = s2[r]; }
            }
        }
    }
}

// ---------------- L3 GEMM via MFMA -> h3 fp32 + scores ----------------
__global__ __launch_bounds__(256) void k_gemm3_mfma(
        const unsigned short* __restrict__ in, const unsigned short* __restrict__ w3p,
        const float* __restrict__ as3f, const float* __restrict__ ad3f,
        float* __restrict__ h3, float* __restrict__ asb, float* __restrict__ adb, int N) {
    int tid = threadIdx.x;
    int wave = tid >> 6, lane = tid & 63;
    int g = lane >> 4, q = lane & 15;
    int row0 = blockIdx.x * 64 + wave * 16;

    f32x4 acc[2];
    acc[0] = (f32x4)0.f; acc[1] = (f32x4)0.f;

    const unsigned short* aptr = in + (size_t)(row0 + q) * 256 + g * 8;
    const unsigned short* bptr = w3p + ((size_t)g * 32 + q) * 8;

#pragma unroll
    for (int kt = 0; kt < 8; ++kt) {
        bf16x8 a = *reinterpret_cast<const bf16x8*>(aptr + kt * 32);
#pragma unroll
        for (int ct = 0; ct < 2; ++ct) {
            bf16x8 b = *reinterpret_cast<const bf16x8*>(bptr + (size_t)kt * 1024 + ct * 128);
            acc[ct] = __builtin_amdgcn_mfma_f32_16x16x32_bf16(a, b, acc[ct], 0, 0, 0);
        }
    }

    float s1[4] = {0.f, 0.f, 0.f, 0.f}, s2[4] = {0.f, 0.f, 0.f, 0.f};
#pragma unroll
    for (int ct = 0; ct < 2; ++ct) {
        int col = ct * 16 + q;
        float ws_ = as3f[col], wd_ = ad3f[col];
#pragma unroll
        for (int r = 0; r < 4; ++r) {
            int row = row0 + 4 * g + r;
            if (row < N) h3[(size_t)row * 32 + col] = acc[ct][r];
            s1[r] = fmaf(acc[ct][r], ws_, s1[r]);
            s2[r] = fmaf(acc[ct][r], wd_, s2[r]);
        }
    }
#pragma unroll
    for (int m = 1; m < 16; m <<= 1) {
#pragma unroll
        for (int r = 0; r < 4; ++r) {
            s1[r] += __shfl_xor(s1[r], m);
            s2[r] += __shfl_xor(s2[r], m);
        }
    }
    if (q == 0) {
#pragma unroll
        for (int r = 0; r < 4; ++r) {
            int row = row0 + 4 * g + r;
            if (row < N) { asb[row] = s1[r]; adb[row] = s2[r]; }
        }
    }
}

// ---------------- gather (attention aggregate), F=256 fp8 -> bf16, 4 heads ----------------
// chunked edge loop: lane (h*16+j) computes weight of edge c+j for head h; inner 16-step
// loop shfl-broadcasts (w,u), loads 1 dword (4 fp8 features) per lane, HW-decodes.
__global__ void k_gather256(const unsigned int* __restrict__ h8,
                            const float* __restrict__ asb, const float* __restrict__ adb,
                            const int* __restrict__ offs, const int* __restrict__ csr,
                            const float* __restrict__ bias, unsigned short* __restrict__ out,
                            int N) {
    int tid = threadIdx.x;
    int lane = tid & 63;
    int v = blockIdx.x * 4 + (tid >> 6);
    if (v >= N) return;
    int head = lane >> 4;
    int j16 = lane & 15;
    int gbase = lane & 48;          // head-group base lane
    float ad = adb[v * 4 + head];
    float w0 = __expf(lrelu(asb[v * 4 + head] + ad));
    float den = w0;
    float a0, a1, a2, a3;
    {
        unsigned int hv = h8[(size_t)v * 64 + lane];
        f32x2 lo = __builtin_amdgcn_cvt_pk_f32_fp8(hv, false);
        f32x2 hi = __builtin_amdgcn_cvt_pk_f32_fp8(hv, true);
        a0 = w0 * lo.x; a1 = w0 * lo.y; a2 = w0 * hi.x; a3 = w0 * hi.y;
    }
    int beg = offs[v], end = offs[v + 1];
    for (int c = beg; c < end; c += 16) {
        int idx = c + j16;
        int u = 0;
        float w = 0.f;
        if (idx < end) {
            u = csr[idx];
            w = __expf(lrelu(asb[u * 4 + head] + ad));
        }
#pragma unroll
        for (int j = 0; j < 16; ++j) {
            float wj = __shfl(w, gbase | j);
            int   uj = __shfl(u, gbase | j);
            den += wj;
            unsigned int hv = h8[(size_t)uj * 64 + lane];
            f32x2 lo = __builtin_amdgcn_cvt_pk_f32_fp8(hv, false);
            f32x2 hi = __builtin_amdgcn_cvt_pk_f32_fp8(hv, true);
            a0 = fmaf(wj, lo.x, a0); a1 = fmaf(wj, lo.y, a1);
            a2 = fmaf(wj, hi.x, a2); a3 = fmaf(wj, hi.y, a3);
        }
    }
    float inv = 1.f / (den + 1e-16f);
    int f0 = 4 * lane;
    unsigned int w01 = (unsigned int)f2bf(eluf(a0 * inv + bias[f0 + 0]))
                     | ((unsigned int)f2bf(eluf(a1 * inv + bias[f0 + 1])) << 16);
    unsigned int w23 = (unsigned int)f2bf(eluf(a2 * inv + bias[f0 + 2]))
                     | ((unsigned int)f2bf(eluf(a3 * inv + bias[f0 + 3])) << 16);
    u32x2 o; o.x = w01; o.y = w23;
    __builtin_nontemporal_store(o, reinterpret_cast<u32x2*>(&out[(size_t)v * 256 + f0]));
}

// ---------------- gather, F=32 fp32, 1 head ----------------
__global__ void k_gather32(const float* __restrict__ h, const float* __restrict__ asb,
                           const float* __restrict__ adb, const int* __restrict__ offs,
                           const int* __restrict__ csr, const float* __restrict__ bias,
                           float* __restrict__ out, int N) {
    int tid = threadIdx.x;
    int v = blockIdx.x * 8 + (tid >> 5);
    int c = tid & 31;
    if (v >= N) return;
    float ad = adb[v];
    float w0 = __expf(lrelu(asb[v] + ad));
    float den = w0;
    float acc = w0 * h[(size_t)v * 32 + c];
    int beg = offs[v], end = offs[v + 1];
    for (int e = beg; e < end; ++e) {
        int u = csr[e];
        float wu = __expf(lrelu(asb[u] + ad));
        den += wu;
        acc = fmaf(wu, h[(size_t)u * 32 + c], acc);
    }
    float o = eluf(acc / (den + 1e-16f) + bias[c]);
    __builtin_nontemporal_store(o, &out[(size_t)v * 32 + c]);
}

// ---------------- fused mean-pool + MLP head ----------------
__global__ __launch_bounds__(256) void k_pool_head(
        const float* __restrict__ h, const int* __restrict__ batch, int N,
        const float* __restrict__ fw1, const float* __restrict__ fb1,
        const float* __restrict__ fw2, const float* __restrict__ fb2,
        const float* __restrict__ fw3, const float* __restrict__ fb3,
        float* __restrict__ out, int G) {
    int g = blockIdx.x;
    int tid = threadIdx.x;
    __shared__ int bounds[2];
    __shared__ float red[8][32];
    __shared__ float pooled[32];
    __shared__ float t1[64];
    __shared__ float t2[32];

    if (tid < 2) {
        int target = g + tid;
        int lo = 0, hi = N;
        while (lo < hi) {
            int mid = (lo + hi) >> 1;
            if (batch[mid] < target) lo = mid + 1; else hi = mid;
        }
        bounds[tid] = lo;
    }
    __syncthreads();
    int beg = bounds[0], end = bounds[1];

    int f = tid & 31, r = tid >> 5;
    float s = 0.f;
    for (int i = beg + r; i < end; i += 8) s += h[(size_t)i * 32 + f];
    red[r][f] = s;
    __syncthreads();

    if (tid < 32) {
        float t = 0.f;
#pragma unroll
        for (int k = 0; k < 8; ++k) t += red[k][tid];
        float invc = 1.f / fmaxf((float)(end - beg), 1.f);
        pooled[tid] = t * invc;
    }
    __syncthreads();

    if (tid < 64) {
        float a = fb1[tid];
#pragma unroll
        for (int k = 0; k < 32; ++k) a = fmaf(pooled[k], fw1[k * 64 + tid], a);
        t1[tid] = fmaxf(a, 0.f);
    }
    __syncthreads();
    if (tid < 32) {
        float a = fb2[tid];
#pragma unroll
        for (int k = 0; k < 64; ++k) a = fmaf(t1[k], fw2[k * 32 + tid], a);
        t2[tid] = fmaxf(a, 0.f);
    }
    __syncthreads();
    if (tid == 0) {
        float o = fb3[0];
#pragma unroll
        for (int k = 0; k < 32; ++k) o = fmaf(t2[k], fw3[k], o);
        out[g] = 1.f / (1.f + __expf(-o));
    }
}

// ---------------- host ----------------
extern "C" void kernel_launch(void* const* d_in, const int* in_sizes, int n_in,
                              void* d_out, int out_size, void* d_ws, size_t ws_size,
                              hipStream_t stream) {
    const float* x    = (const float*)d_in[0];
    const int*   ei   = (const int*)d_in[1];
    const int*   batch= (const int*)d_in[2];
    const float* w1   = (const float*)d_in[3];
    const float* as1  = (const float*)d_in[4];
    const float* ad1  = (const float*)d_in[5];
    const float* b1   = (const float*)d_in[6];
    const float* w2   = (const float*)d_in[7];
    const float* as2  = (const float*)d_in[8];
    const float* ad2  = (const float*)d_in[9];
    const float* b2   = (const float*)d_in[10];
    const float* w3   = (const float*)d_in[11];
    const float* as3  = (const float*)d_in[12];
    const float* ad3  = (const float*)d_in[13];
    const float* b3   = (const float*)d_in[14];
    const float* fw1  = (const float*)d_in[15];
    const float* fb1  = (const float*)d_in[16];
    const float* fw2  = (const float*)d_in[17];
    const float* fb2  = (const float*)d_in[18];
    const float* fw3  = (const float*)d_in[19];
    const float* fb3  = (const float*)d_in[20];
    float* outp = (float*)d_out;

    const int N = in_sizes[0] / 21;
    const int E = in_sizes[1] / 2;
    const int G = out_size;

    // ---- workspace carve ----
    char* p = (char*)d_ws;
    auto alloc = [&](size_t bytes) -> void* {
        void* r = (void*)p;
        p += (bytes + 255) & ~(size_t)255;
        return r;
    };
    int*   deg  = (int*)alloc((size_t)N * 4);
    int*   offs = (int*)alloc((size_t)(N + 1) * 4);
    int*   cur  = (int*)alloc((size_t)N * 4);
    int*   csr  = (int*)alloc((size_t)E * 4);
    int*   bsum = (int*)alloc((size_t)256 * 4);
    unsigned char*  h8  = (unsigned char*)alloc((size_t)N * 256);       // fp8 gather operand
    unsigned short* hbf = (unsigned short*)alloc((size_t)N * 256 * 2);  // bf16 gather output
    float* h3   = (float*)alloc((size_t)N * 32 * 4);
    float* hP   = (float*)alloc((size_t)N * 32 * 4);
    float* asb  = (float*)alloc((size_t)N * 4 * 4);
    float* adb  = (float*)alloc((size_t)N * 4 * 4);
    unsigned short* w2p = (unsigned short*)alloc((size_t)256 * 256 * 2);
    unsigned short* w3p = (unsigned short*)alloc((size_t)256 * 32 * 2);

    const int* esrc = ei;
    const int* edst = ei + E;

    (void)hipMemsetAsync(deg, 0, (size_t)N * 4, stream);

    const int eb = (E + 255) / 256;
    const int sb = (N + 1023) / 1024;

    // ---- CSR build + weight packs ----
    k_deg<<<eb, 256, 0, stream>>>(edst, deg, E);
    k_pack<<<(256 * 256 + 255) / 256, 256, 0, stream>>>(w2, w2p, 256, 256);
    k_pack<<<(256 * 32 + 255) / 256, 256, 0, stream>>>(w3, w3p, 256, 32);
    k_scan1<<<sb, 1024, 0, stream>>>(deg, bsum, N);
    k_scan2<<<1, 256, 0, stream>>>(bsum, sb);
    k_scan3<<<sb, 1024, 0, stream>>>(deg, bsum, offs, cur, N);
    k_scatter<<<eb, 256, 0, stream>>>(esrc, edst, cur, csr, E);

    const int gblk = (N + 63) / 64;

    // ---- layer 1 ----
    k_gemm1<<<(N + 7) / 8, 256, 0, stream>>>(x, w1, as1, ad1, h8, asb, adb, N);
    k_gather256<<<(N + 3) / 4, 256, 0, stream>>>((const unsigned int*)h8, asb, adb, offs, csr, b1, hbf, N);

    // ---- layer 2 ----
    k_gemm2_mfma<<<gblk, 256, 0, stream>>>(hbf, w2p, as2, ad2, h8, asb, adb, N);
    k_gather256<<<(N + 3) / 4, 256, 0, stream>>>((const unsigned int*)h8, asb, adb, offs, csr, b2, hbf, N);

    // ---- layer 3 ----
    k_gemm3_mfma<<<gblk, 256, 0, stream>>>(hbf, w3p, as3, ad3, h3, asb, adb, N);
    k_gather32<<<(N + 7) / 8, 256, 0, stream>>>(h3, asb, adb, offs, csr, b3, hP, N);

    // ---- fused pool + head ----
    k_pool_head<<<G, 256, 0, stream>>>(hP, batch, N, fw1, fb1, fw2, fb2, fw3, fb3, outp, G);
}

// Round 9
// 662.855 us; speedup vs baseline: 3.2009x; 1.0054x over previous
//
#include <hip/hip_runtime.h>
#include <math.h>

typedef float f4 __attribute__((ext_vector_type(4)));
typedef float f32x4 __attribute__((ext_vector_type(4)));
typedef float f32x2 __attribute__((ext_vector_type(2)));
typedef short bf16x8 __attribute__((ext_vector_type(8)));
typedef unsigned int u32x2 __attribute__((ext_vector_type(2)));
typedef int i32x4 __attribute__((ext_vector_type(4)));

// ---------------- device helpers ----------------
__device__ __forceinline__ float lrelu(float x) { return x >= 0.f ? x : 0.2f * x; }
__device__ __forceinline__ float eluf(float x)  { return x > 0.f ? x : __expf(x) - 1.f; }

__device__ __forceinline__ float bf2f(unsigned short u) {
    union { unsigned int i; float f; } c; c.i = ((unsigned int)u) << 16; return c.f;
}
__device__ __forceinline__ unsigned short f2bf(float f) {
    union { float f; unsigned int i; } c; c.f = f;
    unsigned int r = c.i + 0x7fffu + ((c.i >> 16) & 1u);   // RNE
    return (unsigned short)(r >> 16);
}
__device__ __forceinline__ unsigned char f2f8(float f) {
    return (unsigned char)(__builtin_amdgcn_cvt_pk_fp8_f32(f, f, 0u, false) & 0xffu);
}

// ---------------- fused: deg histogram (4-edge ILP) + weight packs ----------------
__global__ void k_deg_pack(const int* __restrict__ edst, int* __restrict__ deg, int E, int DB,
                           const float* __restrict__ w2, unsigned short* __restrict__ w2p,
                           const float* __restrict__ w3, unsigned short* __restrict__ w3p) {
    int b = blockIdx.x;
    int tid = threadIdx.x;
    if (b < DB) {
        int base = (b * 256 + tid) * 4;
        if (base + 3 < E) {
            i32x4 d = *reinterpret_cast<const i32x4*>(&edst[base]);
            atomicAdd(&deg[d.x], 1); atomicAdd(&deg[d.y], 1);
            atomicAdd(&deg[d.z], 1); atomicAdd(&deg[d.w], 1);
        } else {
            for (int e = base; e < E; ++e) atomicAdd(&deg[edst[e]], 1);
        }
    } else if (b < DB + 256) {
        int i = (b - DB) * 256 + tid;          // w2: 256x256
        int k = i >> 8, c = i & 255;
        w2p[((size_t)(k >> 3) * 256 + c) * 8 + (k & 7)] = f2bf(w2[i]);
    } else {
        int i = (b - DB - 256) * 256 + tid;    // w3: 256x32
        int k = i >> 5, c = i & 31;
        w3p[((size_t)(k >> 3) * 32 + c) * 8 + (k & 7)] = f2bf(w3[i]);
    }
}

// ---- multi-block exclusive scan over deg[N] -> offs[N+1], cursor[N] ----
__global__ __launch_bounds__(1024) void k_scan1(const int* __restrict__ deg,
                                                int* __restrict__ bsum, int N) {
    int t = threadIdx.x;
    int i = blockIdx.x * 1024 + t;
    int v = (i < N) ? deg[i] : 0;
#pragma unroll
    for (int m = 32; m; m >>= 1) v += __shfl_xor(v, m);
    __shared__ int ws[16];
    if ((t & 63) == 0) ws[t >> 6] = v;
    __syncthreads();
    if (t < 16) {
        int s = ws[t];
#pragma unroll
        for (int m = 8; m; m >>= 1) s += __shfl_xor(s, m);
        if (t == 0) bsum[blockIdx.x] = s;
    }
}

__global__ void k_scan2(int* __restrict__ bsum, int B) {
    __shared__ int sm[256];
    int t = threadIdx.x;
    int v = (t < B) ? bsum[t] : 0;
    sm[t] = v;
    __syncthreads();
    for (int d = 1; d < 256; d <<= 1) {
        int x = (t >= d) ? sm[t - d] : 0;
        __syncthreads();
        sm[t] += x;
        __syncthreads();
    }
    if (t < B) bsum[t] = sm[t] - v;
}

__global__ __launch_bounds__(1024) void k_scan3(const int* __restrict__ deg,
                                                const int* __restrict__ bsum,
                                                int* __restrict__ offs,
                                                int* __restrict__ cursor, int N) {
    __shared__ int sm[1024];
    int t = threadIdx.x;
    int i = blockIdx.x * 1024 + t;
    int v = (i < N) ? deg[i] : 0;
    sm[t] = v;
    __syncthreads();
    for (int d = 1; d < 1024; d <<= 1) {
        int x = (t >= d) ? sm[t - d] : 0;
        __syncthreads();
        sm[t] += x;
        __syncthreads();
    }
    int pref = bsum[blockIdx.x] + sm[t] - v;
    if (i < N) { offs[i] = pref; cursor[i] = pref; }
    if (i == N - 1) offs[N] = pref + v;
}

// ---------------- fused: scatter (4-edge ILP, NT csr stores) + L1 GEMM ----------------
__global__ __launch_bounds__(256) void k_scatter_gemm1(
        const int* __restrict__ esrc, const int* __restrict__ edst,
        int* __restrict__ cur, int* __restrict__ csr, int E, int SB,
        const float* __restrict__ x, const float* __restrict__ w1,
        const float* __restrict__ aw_s, const float* __restrict__ aw_d,
        unsigned char* __restrict__ h8, float* __restrict__ asb,
        float* __restrict__ adb, int N) {
    int b = blockIdx.x;
    int tid = threadIdx.x;
    if (b < SB) {
        // ---- scatter: 4 edges per thread ----
        int base = (b * 256 + tid) * 4;
        if (base + 3 < E) {
            i32x4 s = *reinterpret_cast<const i32x4*>(&esrc[base]);
            i32x4 d = *reinterpret_cast<const i32x4*>(&edst[base]);
            int p0 = atomicAdd(&cur[d.x], 1);
            int p1 = atomicAdd(&cur[d.y], 1);
            int p2 = atomicAdd(&cur[d.z], 1);
            int p3 = atomicAdd(&cur[d.w], 1);
            __builtin_nontemporal_store(s.x, &csr[p0]);
            __builtin_nontemporal_store(s.y, &csr[p1]);
            __builtin_nontemporal_store(s.z, &csr[p2]);
            __builtin_nontemporal_store(s.w, &csr[p3]);
        } else {
            for (int e = base; e < E; ++e) {
                int p = atomicAdd(&cur[edst[e]], 1);
                __builtin_nontemporal_store(esrc[e], &csr[p]);
            }
        }
        return;
    }
    // ---- L1 GEMM: x[N,21] @ w1[21,256] -> h8 fp8 + scores ----
    int row0 = (b - SB) * 8;
    __shared__ float xs[8][21];
    int nrows = min(8, N - row0);
    for (int i = tid; i < nrows * 21; i += 256) xs[i / 21][i % 21] = x[row0 * 21 + i];
    __syncthreads();
    float wreg[21];
#pragma unroll
    for (int k = 0; k < 21; ++k) wreg[k] = w1[k * 256 + tid];
    float avs = aw_s[tid], avd = aw_d[tid];
    int head = tid >> 6;
    for (int r = 0; r < nrows; ++r) {
        float acc = 0.f;
#pragma unroll
        for (int k = 0; k < 21; ++k) acc = fmaf(xs[r][k], wreg[k], acc);
        h8[(size_t)(row0 + r) * 256 + tid] = f2f8(acc);
        float s1 = acc * avs, s2 = acc * avd;
#pragma unroll
        for (int m = 32; m; m >>= 1) { s1 += __shfl_xor(s1, m); s2 += __shfl_xor(s2, m); }
        if ((tid & 63) == 0) {
            asb[(row0 + r) * 4 + head] = s1;
            adb[(row0 + r) * 4 + head] = s2;
        }
    }
}

// ---------------- L2 GEMM via MFMA: in bf16 -> h fp8 + scores ----------------
__global__ __launch_bounds__(256) void k_gemm2_mfma(
        const unsigned short* __restrict__ in, const unsigned short* __restrict__ w2p,
        const float* __restrict__ as2f, const float* __restrict__ ad2f,
        unsigned char* __restrict__ h8, float* __restrict__ asb,
        float* __restrict__ adb, int N) {
    int tid = threadIdx.x;
    int wave = tid >> 6, lane = tid & 63;
    int g = lane >> 4, q = lane & 15;
    int row0 = blockIdx.x * 64 + wave * 16;

    f32x4 acc[16];
#pragma unroll
    for (int ct = 0; ct < 16; ++ct) acc[ct] = (f32x4)0.f;

    const unsigned short* aptr = in + (size_t)(row0 + q) * 256 + g * 8;
    const unsigned short* bptr = w2p + ((size_t)g * 256 + q) * 8;

#pragma unroll
    for (int kt = 0; kt < 8; ++kt) {
        bf16x8 a = *reinterpret_cast<const bf16x8*>(aptr + kt * 32);
#pragma unroll
        for (int ct = 0; ct < 16; ++ct) {
            bf16x8 b = *reinterpret_cast<const bf16x8*>(bptr + (size_t)kt * 8192 + ct * 128);
            acc[ct] = __builtin_amdgcn_mfma_f32_16x16x32_bf16(a, b, acc[ct], 0, 0, 0);
        }
    }

#pragma unroll
    for (int ct = 0; ct < 16; ++ct) {
        int col = ct * 16 + q;
#pragma unroll
        for (int r = 0; r < 4; ++r) {
            int row = row0 + 4 * g + r;
            if (row < N) h8[(size_t)row * 256 + col] = f2f8(acc[ct][r]);
        }
    }

#pragma unroll
    for (int h = 0; h < 4; ++h) {
        float s1[4] = {0.f, 0.f, 0.f, 0.f}, s2[4] = {0.f, 0.f, 0.f, 0.f};
#pragma unroll
        for (int cc = 0; cc < 4; ++cc) {
            int ct = h * 4 + cc;
            int col = ct * 16 + q;
            float ws_ = as2f[col], wd_ = ad2f[col];
#pragma unroll
            for (int r = 0; r < 4; ++r) {
                s1[r] = fmaf(acc[ct][r], ws_, s1[r]);
                s2[r] = fmaf(acc[ct][r], wd_, s2[r]);
            }
        }
#pragma unroll
        for (int m = 1; m < 16; m <<= 1) {
#pragma unroll
            for (int r = 0; r < 4; ++r) {
                s1[r] += __shfl_xor(s1[r], m);
                s2[r] += __shfl_xor(s2[r], m);
            }
        }
        if (q == 0) {
#pragma unroll
            for (int r = 0; r < 4; ++r) {
                int row = row0 + 4 * g + r;
                if (row < N) { asb[row * 4 + h] = s1[r]; adb[row * 4 + h] = s2[r]; }
            }
        }
    }
}

// ---------------- L3 GEMM via MFMA -> h3 fp32 + scores ----------------
__global__ __launch_bounds__(256) void k_gemm3_mfma(
        const unsigned short* __restrict__ in, const unsigned short* __restrict__ w3p,
        const float* __restrict__ as3f, const float* __restrict__ ad3f,
        float* __restrict__ h3, float* __restrict__ asb, float* __restrict__ adb, int N) {
    int tid = threadIdx.x;
    int wave = tid >> 6, lane = tid & 63;
    int g = lane >> 4, q = lane & 15;
    int row0 = blockIdx.x * 64 + wave * 16;

    f32x4 acc[2];
    acc[0] = (f32x4)0.f; acc[1] = (f32x4)0.f;

    const unsigned short* aptr = in + (size_t)(row0 + q) * 256 + g * 8;
    const unsigned short* bptr = w3p + ((size_t)g * 32 + q) * 8;

#pragma unroll
    for (int kt = 0; kt < 8; ++kt) {
        bf16x8 a = *reinterpret_cast<const bf16x8*>(aptr + kt * 32);
#pragma unroll
        for (int ct = 0; ct < 2; ++ct) {
            bf16x8 b = *reinterpret_cast<const bf16x8*>(bptr + (size_t)kt * 1024 + ct * 128);
            acc[ct] = __builtin_amdgcn_mfma_f32_16x16x32_bf16(a, b, acc[ct], 0, 0, 0);
        }
    }

    float s1[4] = {0.f, 0.f, 0.f, 0.f}, s2[4] = {0.f, 0.f, 0.f, 0.f};
#pragma unroll
    for (int ct = 0; ct < 2; ++ct) {
        int col = ct * 16 + q;
        float ws_ = as3f[col], wd_ = ad3f[col];
#pragma unroll
        for (int r = 0; r < 4; ++r) {
            int row = row0 + 4 * g + r;
            if (row < N) h3[(size_t)row * 32 + col] = acc[ct][r];
            s1[r] = fmaf(acc[ct][r], ws_, s1[r]);
            s2[r] = fmaf(acc[ct][r], wd_, s2[r]);
        }
    }
#pragma unroll
    for (int m = 1; m < 16; m <<= 1) {
#pragma unroll
        for (int r = 0; r < 4; ++r) {
            s1[r] += __shfl_xor(s1[r], m);
            s2[r] += __shfl_xor(s2[r], m);
        }
    }
    if (q == 0) {
#pragma unroll
        for (int r = 0; r < 4; ++r) {
            int row = row0 + 4 * g + r;
            if (row < N) { asb[row] = s1[r]; adb[row] = s2[r]; }
        }
    }
}

// ---------------- gather (attention aggregate), F=256 fp8 -> bf16, 4 heads ----------------
__global__ void k_gather256(const unsigned int* __restrict__ h8,
                            const float* __restrict__ asb, const float* __restrict__ adb,
                            const int* __restrict__ offs, const int* __restrict__ csr,
                            const float* __restrict__ bias, unsigned short* __restrict__ out,
                            int N) {
    int tid = threadIdx.x;
    int lane = tid & 63;
    int v = blockIdx.x * 4 + (tid >> 6);
    if (v >= N) return;
    int head = lane >> 4;
    int j16 = lane & 15;
    int gbase = lane & 48;          // head-group base lane
    float ad = adb[v * 4 + head];
    float w0 = __expf(lrelu(asb[v * 4 + head] + ad));
    float den = w0;
    float a0, a1, a2, a3;
    {
        unsigned int hv = h8[(size_t)v * 64 + lane];
        f32x2 lo = __builtin_amdgcn_cvt_pk_f32_fp8(hv, false);
        f32x2 hi = __builtin_amdgcn_cvt_pk_f32_fp8(hv, true);
        a0 = w0 * lo.x; a1 = w0 * lo.y; a2 = w0 * hi.x; a3 = w0 * hi.y;
    }
    int beg = offs[v], end = offs[v + 1];
    for (int c = beg; c < end; c += 16) {
        int idx = c + j16;
        int u = 0;
        float w = 0.f;
        if (idx < end) {
            u = csr[idx];
            w = __expf(lrelu(asb[u * 4 + head] + ad));
        }
#pragma unroll
        for (int j = 0; j < 16; ++j) {
            float wj = __shfl(w, gbase | j);
            int   uj = __shfl(u, gbase | j);
            den += wj;
            unsigned int hv = h8[(size_t)uj * 64 + lane];
            f32x2 lo = __builtin_amdgcn_cvt_pk_f32_fp8(hv, false);
            f32x2 hi = __builtin_amdgcn_cvt_pk_f32_fp8(hv, true);
            a0 = fmaf(wj, lo.x, a0); a1 = fmaf(wj, lo.y, a1);
            a2 = fmaf(wj, hi.x, a2); a3 = fmaf(wj, hi.y, a3);
        }
    }
    float inv = 1.f / (den + 1e-16f);
    int f0 = 4 * lane;
    unsigned int w01 = (unsigned int)f2bf(eluf(a0 * inv + bias[f0 + 0]))
                     | ((unsigned int)f2bf(eluf(a1 * inv + bias[f0 + 1])) << 16);
    unsigned int w23 = (unsigned int)f2bf(eluf(a2 * inv + bias[f0 + 2]))
                     | ((unsigned int)f2bf(eluf(a3 * inv + bias[f0 + 3])) << 16);
    u32x2 o; o.x = w01; o.y = w23;
    __builtin_nontemporal_store(o, reinterpret_cast<u32x2*>(&out[(size_t)v * 256 + f0]));
}

// ---------------- gather, F=32 fp32, 1 head ----------------
__global__ void k_gather32(const float* __restrict__ h, const float* __restrict__ asb,
                           const float* __restrict__ adb, const int* __restrict__ offs,
                           const int* __restrict__ csr, const float* __restrict__ bias,
                           float* __restrict__ out, int N) {
    int tid = threadIdx.x;
    int v = blockIdx.x * 8 + (tid >> 5);
    int c = tid & 31;
    if (v >= N) return;
    float ad = adb[v];
    float w0 = __expf(lrelu(asb[v] + ad));
    float den = w0;
    float acc = w0 * h[(size_t)v * 32 + c];
    int beg = offs[v], end = offs[v + 1];
    for (int e = beg; e < end; ++e) {
        int u = csr[e];
        float wu = __expf(lrelu(asb[u] + ad));
        den += wu;
        acc = fmaf(wu, h[(size_t)u * 32 + c], acc);
    }
    float o = eluf(acc / (den + 1e-16f) + bias[c]);
    __builtin_nontemporal_store(o, &out[(size_t)v * 32 + c]);
}

// ---------------- fused mean-pool + MLP head ----------------
__global__ __launch_bounds__(256) void k_pool_head(
        const float* __restrict__ h, const int* __restrict__ batch, int N,
        const float* __restrict__ fw1, const float* __restrict__ fb1,
        const float* __restrict__ fw2, const float* __restrict__ fb2,
        const float* __restrict__ fw3, const float* __restrict__ fb3,
        float* __restrict__ out, int G) {
    int g = blockIdx.x;
    int tid = threadIdx.x;
    __shared__ int bounds[2];
    __shared__ float red[8][32];
    __shared__ float pooled[32];
    __shared__ float t1[64];
    __shared__ float t2[32];

    if (tid < 2) {
        int target = g + tid;
        int lo = 0, hi = N;
        while (lo < hi) {
            int mid = (lo + hi) >> 1;
            if (batch[mid] < target) lo = mid + 1; else hi = mid;
        }
        bounds[tid] = lo;
    }
    __syncthreads();
    int beg = bounds[0], end = bounds[1];

    int f = tid & 31, r = tid >> 5;
    float s = 0.f;
    for (int i = beg + r; i < end; i += 8) s += h[(size_t)i * 32 + f];
    red[r][f] = s;
    __syncthreads();

    if (tid < 32) {
        float t = 0.f;
#pragma unroll
        for (int k = 0; k < 8; ++k) t += red[k][tid];
        float invc = 1.f / fmaxf((float)(end - beg), 1.f);
        pooled[tid] = t * invc;
    }
    __syncthreads();

    if (tid < 64) {
        float a = fb1[tid];
#pragma unroll
        for (int k = 0; k < 32; ++k) a = fmaf(pooled[k], fw1[k * 64 + tid], a);
        t1[tid] = fmaxf(a, 0.f);
    }
    __syncthreads();
    if (tid < 32) {
        float a = fb2[tid];
#pragma unroll
        for (int k = 0; k < 64; ++k) a = fmaf(t1[k], fw2[k * 32 + tid], a);
        t2[tid] = fmaxf(a, 0.f);
    }
    __syncthreads();
    if (tid == 0) {
        float o = fb3[0];
#pragma unroll
        for (int k = 0; k < 32; ++k) o = fmaf(t2[k], fw3[k], o);
        out[g] = 1.f / (1.f + __expf(-o));
    }
}

// ---------------- host ----------------
extern "C" void kernel_launch(void* const* d_in, const int* in_sizes, int n_in,
                              void* d_out, int out_size, void* d_ws, size_t ws_size,
                              hipStream_t stream) {
    const float* x    = (const float*)d_in[0];
    const int*   ei   = (const int*)d_in[1];
    const int*   batch= (const int*)d_in[2];
    const float* w1   = (const float*)d_in[3];
    const float* as1  = (const float*)d_in[4];
    const float* ad1  = (const float*)d_in[5];
    const float* b1   = (const float*)d_in[6];
    const float* w2   = (const float*)d_in[7];
    const float* as2  = (const float*)d_in[8];
    const float* ad2  = (const float*)d_in[9];
    const float* b2   = (const float*)d_in[10];
    const float* w3   = (const float*)d_in[11];
    const float* as3  = (const float*)d_in[12];
    const float* ad3  = (const float*)d_in[13];
    const float* b3   = (const float*)d_in[14];
    const float* fw1  = (const float*)d_in[15];
    const float* fb1  = (const float*)d_in[16];
    const float* fw2  = (const float*)d_in[17];
    const float* fb2  = (const float*)d_in[18];
    const float* fw3  = (const float*)d_in[19];
    const float* fb3  = (const float*)d_in[20];
    float* outp = (float*)d_out;

    const int N = in_sizes[0] / 21;
    const int E = in_sizes[1] / 2;
    const int G = out_size;

    // ---- workspace carve ----
    char* p = (char*)d_ws;
    auto alloc = [&](size_t bytes) -> void* {
        void* r = (void*)p;
        p += (bytes + 255) & ~(size_t)255;
        return r;
    };
    int*   deg  = (int*)alloc((size_t)N * 4);
    int*   offs = (int*)alloc((size_t)(N + 1) * 4);
    int*   cur  = (int*)alloc((size_t)N * 4);
    int*   csr  = (int*)alloc((size_t)E * 4);
    int*   bsum = (int*)alloc((size_t)256 * 4);
    unsigned char*  h8  = (unsigned char*)alloc((size_t)N * 256);       // fp8 gather operand
    unsigned short* hbf = (unsigned short*)alloc((size_t)N * 256 * 2);  // bf16 gather output
    float* h3   = (float*)alloc((size_t)N * 32 * 4);
    float* hP   = (float*)alloc((size_t)N * 32 * 4);
    float* asb  = (float*)alloc((size_t)N * 4 * 4);
    float* adb  = (float*)alloc((size_t)N * 4 * 4);
    unsigned short* w2p = (unsigned short*)alloc((size_t)256 * 256 * 2);
    unsigned short* w3p = (unsigned short*)alloc((size_t)256 * 32 * 2);

    const int* esrc = ei;
    const int* edst = ei + E;

    (void)hipMemsetAsync(deg, 0, (size_t)N * 4, stream);

    const int sb = (N + 1023) / 1024;          // scan blocks (<= 256)
    const int DB = (E + 1023) / 1024;          // deg blocks (4 edges/thread)
    const int SB = (E + 1023) / 1024;          // scatter blocks (4 edges/thread)
    const int GB1 = (N + 7) / 8;               // gemm1 blocks

    // ---- fused deg + weight packs ----
    k_deg_pack<<<DB + 256 + 32, 256, 0, stream>>>(edst, deg, E, DB, w2, w2p, w3, w3p);
    k_scan1<<<sb, 1024, 0, stream>>>(deg, bsum, N);
    k_scan2<<<1, 256, 0, stream>>>(bsum, sb);
    k_scan3<<<sb, 1024, 0, stream>>>(deg, bsum, offs, cur, N);

    // ---- fused scatter + layer-1 GEMM (independent work overlapped) ----
    k_scatter_gemm1<<<SB + GB1, 256, 0, stream>>>(esrc, edst, cur, csr, E, SB,
                                                  x, w1, as1, ad1, h8, asb, adb, N);

    const int gblk = (N + 63) / 64;

    // ---- layer 1 gather ----
    k_gather256<<<(N + 3) / 4, 256, 0, stream>>>((const unsigned int*)h8, asb, adb, offs, csr, b1, hbf, N);

    // ---- layer 2 ----
    k_gemm2_mfma<<<gblk, 256, 0, stream>>>(hbf, w2p, as2, ad2, h8, asb, adb, N);
    k_gather256<<<(N + 3) / 4, 256, 0, stream>>>((const unsigned int*)h8, asb, adb, offs, csr, b2, hbf, N);

    // ---- layer 3 ----
    k_gemm3_mfma<<<gblk, 256, 0, stream>>>(hbf, w3p, as3, ad3, h3, asb, adb, N);
    k_gather32<<<(N + 7) / 8, 256, 0, stream>>>(h3, asb, adb, offs, csr, b3, hP, N);

    // ---- fused pool + head ----
    k_pool_head<<<G, 256, 0, stream>>>(hP, batch, N, fw1, fb1, fw2, fb2, fw3, fb3, outp, G);
}

// Round 10
// 554.795 us; speedup vs baseline: 3.8244x; 1.1948x over previous
//
#include <hip/hip_runtime.h>
#include <math.h>

typedef float f4 __attribute__((ext_vector_type(4)));
typedef float f32x4 __attribute__((ext_vector_type(4)));
typedef float f32x2 __attribute__((ext_vector_type(2)));
typedef short bf16x8 __attribute__((ext_vector_type(8)));
typedef unsigned int u32x2 __attribute__((ext_vector_type(2)));
typedef int i32x4 __attribute__((ext_vector_type(4)));
typedef unsigned short u16x4 __attribute__((ext_vector_type(4)));

// ---------------- device helpers ----------------
__device__ __forceinline__ float lrelu(float x) { return x >= 0.f ? x : 0.2f * x; }
__device__ __forceinline__ float eluf(float x)  { return x > 0.f ? x : __expf(x) - 1.f; }

__device__ __forceinline__ float bf2f(unsigned short u) {
    union { unsigned int i; float f; } c; c.i = ((unsigned int)u) << 16; return c.f;
}
__device__ __forceinline__ unsigned short f2bf(float f) {
    union { float f; unsigned int i; } c; c.f = f;
    unsigned int r = c.i + 0x7fffu + ((c.i >> 16) & 1u);   // RNE
    return (unsigned short)(r >> 16);
}
__device__ __forceinline__ unsigned char f2f8(float f) {
    return (unsigned char)(__builtin_amdgcn_cvt_pk_fp8_f32(f, f, 0u, false) & 0xffu);
}

// ---------------- fused: deg histogram + rank capture + weight packs ----------------
// rank[e] = atomicAdd(&deg[dst],1) — the edge's within-node slot, reused by the
// scatter so it needs NO atomics (halves total atomic work).
__global__ void k_deg_pack(const int* __restrict__ edst, int* __restrict__ deg,
                           unsigned short* __restrict__ rank, int E, int DB,
                           const float* __restrict__ w2, unsigned short* __restrict__ w2p,
                           const float* __restrict__ w3, unsigned short* __restrict__ w3p) {
    int b = blockIdx.x;
    int tid = threadIdx.x;
    if (b < DB) {
        int base = (b * 256 + tid) * 4;
        if (base + 3 < E) {
            i32x4 d = *reinterpret_cast<const i32x4*>(&edst[base]);
            u16x4 r;
            r.x = (unsigned short)atomicAdd(&deg[d.x], 1);
            r.y = (unsigned short)atomicAdd(&deg[d.y], 1);
            r.z = (unsigned short)atomicAdd(&deg[d.z], 1);
            r.w = (unsigned short)atomicAdd(&deg[d.w], 1);
            *reinterpret_cast<u16x4*>(&rank[base]) = r;
        } else {
            for (int e = base; e < E; ++e)
                rank[e] = (unsigned short)atomicAdd(&deg[edst[e]], 1);
        }
    } else if (b < DB + 256) {
        int i = (b - DB) * 256 + tid;          // w2: 256x256
        int k = i >> 8, c = i & 255;
        w2p[((size_t)(k >> 3) * 256 + c) * 8 + (k & 7)] = f2bf(w2[i]);
    } else {
        int i = (b - DB - 256) * 256 + tid;    // w3: 256x32
        int k = i >> 5, c = i & 31;
        w3p[((size_t)(k >> 3) * 32 + c) * 8 + (k & 7)] = f2bf(w3[i]);
    }
}

// ---- multi-block exclusive scan over deg[N] -> offs[N+1] ----
__global__ __launch_bounds__(1024) void k_scan1(const int* __restrict__ deg,
                                                int* __restrict__ bsum, int N) {
    int t = threadIdx.x;
    int i = blockIdx.x * 1024 + t;
    int v = (i < N) ? deg[i] : 0;
#pragma unroll
    for (int m = 32; m; m >>= 1) v += __shfl_xor(v, m);
    __shared__ int ws[16];
    if ((t & 63) == 0) ws[t >> 6] = v;
    __syncthreads();
    if (t < 16) {
        int s = ws[t];
#pragma unroll
        for (int m = 8; m; m >>= 1) s += __shfl_xor(s, m);
        if (t == 0) bsum[blockIdx.x] = s;
    }
}

__global__ void k_scan2(int* __restrict__ bsum, int B) {
    __shared__ int sm[256];
    int t = threadIdx.x;
    int v = (t < B) ? bsum[t] : 0;
    sm[t] = v;
    __syncthreads();
    for (int d = 1; d < 256; d <<= 1) {
        int x = (t >= d) ? sm[t - d] : 0;
        __syncthreads();
        sm[t] += x;
        __syncthreads();
    }
    if (t < B) bsum[t] = sm[t] - v;
}

__global__ __launch_bounds__(1024) void k_scan3(const int* __restrict__ deg,
                                                const int* __restrict__ bsum,
                                                int* __restrict__ offs, int N) {
    __shared__ int sm[1024];
    int t = threadIdx.x;
    int i = blockIdx.x * 1024 + t;
    int v = (i < N) ? deg[i] : 0;
    sm[t] = v;
    __syncthreads();
    for (int d = 1; d < 1024; d <<= 1) {
        int x = (t >= d) ? sm[t - d] : 0;
        __syncthreads();
        sm[t] += x;
        __syncthreads();
    }
    int pref = bsum[blockIdx.x] + sm[t] - v;
    if (i < N) offs[i] = pref;
    if (i == N - 1) offs[N] = pref + v;
}

// ---------------- atomic-free scatter: csr[offs[dst]+rank] = src ----------------
__global__ void k_scatter(const int* __restrict__ esrc, const int* __restrict__ edst,
                          const unsigned short* __restrict__ rank,
                          const int* __restrict__ offs, int* __restrict__ csr, int E) {
    int base = (blockIdx.x * 256 + threadIdx.x) * 4;
    if (base + 3 < E) {
        i32x4 s = *reinterpret_cast<const i32x4*>(&esrc[base]);
        i32x4 d = *reinterpret_cast<const i32x4*>(&edst[base]);
        u16x4 r = *reinterpret_cast<const u16x4*>(&rank[base]);
        csr[offs[d.x] + r.x] = s.x;
        csr[offs[d.y] + r.y] = s.y;
        csr[offs[d.z] + r.z] = s.z;
        csr[offs[d.w] + r.w] = s.w;
    } else {
        for (int e = base; e < E; ++e) csr[offs[edst[e]] + rank[e]] = esrc[e];
    }
}

// ---------------- L1 GEMM (VALU, K=21) -> h fp8 + scores ----------------
__global__ void k_gemm1(const float* __restrict__ x, const float* __restrict__ w,
                        const float* __restrict__ aw_s, const float* __restrict__ aw_d,
                        unsigned char* __restrict__ h8, float* __restrict__ asb,
                        float* __restrict__ adb, int N) {
    int tid = threadIdx.x;
    int row0 = blockIdx.x * 8;
    __shared__ float xs[8][21];
    int nrows = min(8, N - row0);
    for (int i = tid; i < nrows * 21; i += 256) xs[i / 21][i % 21] = x[row0 * 21 + i];
    __syncthreads();
    float wreg[21];
#pragma unroll
    for (int k = 0; k < 21; ++k) wreg[k] = w[k * 256 + tid];
    float avs = aw_s[tid], avd = aw_d[tid];
    int head = tid >> 6;
    for (int r = 0; r < nrows; ++r) {
        float acc = 0.f;
#pragma unroll
        for (int k = 0; k < 21; ++k) acc = fmaf(xs[r][k], wreg[k], acc);
        h8[(size_t)(row0 + r) * 256 + tid] = f2f8(acc);
        float s1 = acc * avs, s2 = acc * avd;
#pragma unroll
        for (int m = 32; m; m >>= 1) { s1 += __shfl_xor(s1, m); s2 += __shfl_xor(s2, m); }
        if ((tid & 63) == 0) {
            asb[(row0 + r) * 4 + head] = s1;
            adb[(row0 + r) * 4 + head] = s2;
        }
    }
}

// ---------------- L2 GEMM via MFMA: in bf16 -> h fp8 + scores ----------------
__global__ __launch_bounds__(256) void k_gemm2_mfma(
        const unsigned short* __restrict__ in, const unsigned short* __restrict__ w2p,
        const float* __restrict__ as2f, const float* __restrict__ ad2f,
        unsigned char* __restrict__ h8, float* __restrict__ asb,
        float* __restrict__ adb, int N) {
    int tid = threadIdx.x;
    int wave = tid >> 6, lane = tid & 63;
    int g = lane >> 4, q = lane & 15;
    int row0 = blockIdx.x * 64 + wave * 16;

    f32x4 acc[16];
#pragma unroll
    for (int ct = 0; ct < 16; ++ct) acc[ct] = (f32x4)0.f;

    const unsigned short* aptr = in + (size_t)(row0 + q) * 256 + g * 8;
    const unsigned short* bptr = w2p + ((size_t)g * 256 + q) * 8;

#pragma unroll
    for (int kt = 0; kt < 8; ++kt) {
        bf16x8 a = *reinterpret_cast<const bf16x8*>(aptr + kt * 32);
#pragma unroll
        for (int ct = 0; ct < 16; ++ct) {
            bf16x8 b = *reinterpret_cast<const bf16x8*>(bptr + (size_t)kt * 8192 + ct * 128);
            acc[ct] = __builtin_amdgcn_mfma_f32_16x16x32_bf16(a, b, acc[ct], 0, 0, 0);
        }
    }

#pragma unroll
    for (int ct = 0; ct < 16; ++ct) {
        int col = ct * 16 + q;
#pragma unroll
        for (int r = 0; r < 4; ++r) {
            int row = row0 + 4 * g + r;
            if (row < N) h8[(size_t)row * 256 + col] = f2f8(acc[ct][r]);
        }
    }

#pragma unroll
    for (int h = 0; h < 4; ++h) {
        float s1[4] = {0.f, 0.f, 0.f, 0.f}, s2[4] = {0.f, 0.f, 0.f, 0.f};
#pragma unroll
        for (int cc = 0; cc < 4; ++cc) {
            int ct = h * 4 + cc;
            int col = ct * 16 + q;
            float ws_ = as2f[col], wd_ = ad2f[col];
#pragma unroll
            for (int r = 0; r < 4; ++r) {
                s1[r] = fmaf(acc[ct][r], ws_, s1[r]);
                s2[r] = fmaf(acc[ct][r], wd_, s2[r]);
            }
        }
#pragma unroll
        for (int m = 1; m < 16; m <<= 1) {
#pragma unroll
            for (int r = 0; r < 4; ++r) {
                s1[r] += __shfl_xor(s1[r], m);
                s2[r] += __shfl_xor(s2[r], m);
            }
        }
        if (q == 0) {
#pragma unroll
            for (int r = 0; r < 4; ++r) {
                int row = row0 + 4 * g + r;
                if (row < N) { asb[row * 4 + h] = s1[r]; adb[row * 4 + h] = s2[r]; }
            }
        }
    }
}

// ---------------- L3 GEMM via MFMA -> h3 fp32 + scores ----------------
__global__ __launch_bounds__(256) void k_gemm3_mfma(
        const unsigned short* __restrict__ in, const unsigned short* __restrict__ w3p,
        const float* __restrict__ as3f, const float* __restrict__ ad3f,
        float* __restrict__ h3, float* __restrict__ asb, float* __restrict__ adb, int N) {
    int tid = threadIdx.x;
    int wave = tid >> 6, lane = tid & 63;
    int g = lane >> 4, q = lane & 15;
    int row0 = blockIdx.x * 64 + wave * 16;

    f32x4 acc[2];
    acc[0] = (f32x4)0.f; acc[1] = (f32x4)0.f;

    const unsigned short* aptr = in + (size_t)(row0 + q) * 256 + g * 8;
    const unsigned short* bptr = w3p + ((size_t)g * 32 + q) * 8;

#pragma unroll
    for (int kt = 0; kt < 8; ++kt) {
        bf16x8 a = *reinterpret_cast<const bf16x8*>(aptr + kt * 32);
#pragma unroll
        for (int ct = 0; ct < 2; ++ct) {
            bf16x8 b = *reinterpret_cast<const bf16x8*>(bptr + (size_t)kt * 1024 + ct * 128);
            acc[ct] = __builtin_amdgcn_mfma_f32_16x16x32_bf16(a, b, acc[ct], 0, 0, 0);
        }
    }

    float s1[4] = {0.f, 0.f, 0.f, 0.f}, s2[4] = {0.f, 0.f, 0.f, 0.f};
#pragma unroll
    for (int ct = 0; ct < 2; ++ct) {
        int col = ct * 16 + q;
        float ws_ = as3f[col], wd_ = ad3f[col];
#pragma unroll
        for (int r = 0; r < 4; ++r) {
            int row = row0 + 4 * g + r;
            if (row < N) h3[(size_t)row * 32 + col] = acc[ct][r];
            s1[r] = fmaf(acc[ct][r], ws_, s1[r]);
            s2[r] = fmaf(acc[ct][r], wd_, s2[r]);
        }
    }
#pragma unroll
    for (int m = 1; m < 16; m <<= 1) {
#pragma unroll
        for (int r = 0; r < 4; ++r) {
            s1[r] += __shfl_xor(s1[r], m);
            s2[r] += __shfl_xor(s2[r], m);
        }
    }
    if (q == 0) {
#pragma unroll
        for (int r = 0; r < 4; ++r) {
            int row = row0 + 4 * g + r;
            if (row < N) { asb[row] = s1[r]; adb[row] = s2[r]; }
        }
    }
}

// ---------------- gather (attention aggregate), F=256 fp8 -> bf16, 4 heads ----------------
__global__ void k_gather256(const unsigned int* __restrict__ h8,
                            const float* __restrict__ asb, const float* __restrict__ adb,
                            const int* __restrict__ offs, const int* __restrict__ csr,
                            const float* __restrict__ bias, unsigned short* __restrict__ out,
                            int N) {
    int tid = threadIdx.x;
    int lane = tid & 63;
    int v = blockIdx.x * 4 + (tid >> 6);
    if (v >= N) return;
    int head = lane >> 4;
    int j16 = lane & 15;
    int gbase = lane & 48;          // head-group base lane
    float ad = adb[v * 4 + head];
    float w0 = __expf(lrelu(asb[v * 4 + head] + ad));
    float den = w0;
    float a0, a1, a2, a3;
    {
        unsigned int hv = h8[(size_t)v * 64 + lane];
        f32x2 lo = __builtin_amdgcn_cvt_pk_f32_fp8(hv, false);
        f32x2 hi = __builtin_amdgcn_cvt_pk_f32_fp8(hv, true);
        a0 = w0 * lo.x; a1 = w0 * lo.y; a2 = w0 * hi.x; a3 = w0 * hi.y;
    }
    int beg = offs[v], end = offs[v + 1];
    for (int c = beg; c < end; c += 16) {
        int idx = c + j16;
        int u = 0;
        float w = 0.f;
        if (idx < end) {
            u = csr[idx];
            w = __expf(lrelu(asb[u * 4 + head] + ad));
        }
#pragma unroll
        for (int j = 0; j < 16; ++j) {
            float wj = __shfl(w, gbase | j);
            int   uj = __shfl(u, gbase | j);
            den += wj;
            unsigned int hv = h8[(size_t)uj * 64 + lane];
            f32x2 lo = __builtin_amdgcn_cvt_pk_f32_fp8(hv, false);
            f32x2 hi = __builtin_amdgcn_cvt_pk_f32_fp8(hv, true);
            a0 = fmaf(wj, lo.x, a0); a1 = fmaf(wj, lo.y, a1);
            a2 = fmaf(wj, hi.x, a2); a3 = fmaf(wj, hi.y, a3);
        }
    }
    float inv = 1.f / (den + 1e-16f);
    int f0 = 4 * lane;
    unsigned int w01 = (unsigned int)f2bf(eluf(a0 * inv + bias[f0 + 0]))
                     | ((unsigned int)f2bf(eluf(a1 * inv + bias[f0 + 1])) << 16);
    unsigned int w23 = (unsigned int)f2bf(eluf(a2 * inv + bias[f0 + 2]))
                     | ((unsigned int)f2bf(eluf(a3 * inv + bias[f0 + 3])) << 16);
    u32x2 o; o.x = w01; o.y = w23;
    __builtin_nontemporal_store(o, reinterpret_cast<u32x2*>(&out[(size_t)v * 256 + f0]));
}

// ---------------- gather, F=32 fp32, 1 head ----------------
__global__ void k_gather32(const float* __restrict__ h, const float* __restrict__ asb,
                           const float* __restrict__ adb, const int* __restrict__ offs,
                           const int* __restrict__ csr, const float* __restrict__ bias,
                           float* __restrict__ out, int N) {
    int tid = threadIdx.x;
    int v = blockIdx.x * 8 + (tid >> 5);
    int c = tid & 31;
    if (v >= N) return;
    float ad = adb[v];
    float w0 = __expf(lrelu(asb[v] + ad));
    float den = w0;
    float acc = w0 * h[(size_t)v * 32 + c];
    int beg = offs[v], end = offs[v + 1];
    for (int e = beg; e < end; ++e) {
        int u = csr[e];
        float wu = __expf(lrelu(asb[u] + ad));
        den += wu;
        acc = fmaf(wu, h[(size_t)u * 32 + c], acc);
    }
    float o = eluf(acc / (den + 1e-16f) + bias[c]);
    __builtin_nontemporal_store(o, &out[(size_t)v * 32 + c]);
}

// ---------------- fused mean-pool + MLP head ----------------
__global__ __launch_bounds__(256) void k_pool_head(
        const float* __restrict__ h, const int* __restrict__ batch, int N,
        const float* __restrict__ fw1, const float* __restrict__ fb1,
        const float* __restrict__ fw2, const float* __restrict__ fb2,
        const float* __restrict__ fw3, const float* __restrict__ fb3,
        float* __restrict__ out, int G) {
    int g = blockIdx.x;
    int tid = threadIdx.x;
    __shared__ int bounds[2];
    __shared__ float red[8][32];
    __shared__ float pooled[32];
    __shared__ float t1[64];
    __shared__ float t2[32];

    if (tid < 2) {
        int target = g + tid;
        int lo = 0, hi = N;
        while (lo < hi) {
            int mid = (lo + hi) >> 1;
            if (batch[mid] < target) lo = mid + 1; else hi = mid;
        }
        bounds[tid] = lo;
    }
    __syncthreads();
    int beg = bounds[0], end = bounds[1];

    int f = tid & 31, r = tid >> 5;
    float s = 0.f;
    for (int i = beg + r; i < end; i += 8) s += h[(size_t)i * 32 + f];
    red[r][f] = s;
    __syncthreads();

    if (tid < 32) {
        float t = 0.f;
#pragma unroll
        for (int k = 0; k < 8; ++k) t += red[k][tid];
        float invc = 1.f / fmaxf((float)(end - beg), 1.f);
        pooled[tid] = t * invc;
    }
    __syncthreads();

    if (tid < 64) {
        float a = fb1[tid];
#pragma unroll
        for (int k = 0; k < 32; ++k) a = fmaf(pooled[k], fw1[k * 64 + tid], a);
        t1[tid] = fmaxf(a, 0.f);
    }
    __syncthreads();
    if (tid < 32) {
        float a = fb2[tid];
#pragma unroll
        for (int k = 0; k < 64; ++k) a = fmaf(t1[k], fw2[k * 32 + tid], a);
        t2[tid] = fmaxf(a, 0.f);
    }
    __syncthreads();
    if (tid == 0) {
        float o = fb3[0];
#pragma unroll
        for (int k = 0; k < 32; ++k) o = fmaf(t2[k], fw3[k], o);
        out[g] = 1.f / (1.f + __expf(-o));
    }
}

// ---------------- host ----------------
extern "C" void kernel_launch(void* const* d_in, const int* in_sizes, int n_in,
                              void* d_out, int out_size, void* d_ws, size_t ws_size,
                              hipStream_t stream) {
    const float* x    = (const float*)d_in[0];
    const int*   ei   = (const int*)d_in[1];
    const int*   batch= (const int*)d_in[2];
    const float* w1   = (const float*)d_in[3];
    const float* as1  = (const float*)d_in[4];
    const float* ad1  = (const float*)d_in[5];
    const float* b1   = (const float*)d_in[6];
    const float* w2   = (const float*)d_in[7];
    const float* as2  = (const float*)d_in[8];
    const float* ad2  = (const float*)d_in[9];
    const float* b2   = (const float*)d_in[10];
    const float* w3   = (const float*)d_in[11];
    const float* as3  = (const float*)d_in[12];
    const float* ad3  = (const float*)d_in[13];
    const float* b3   = (const float*)d_in[14];
    const float* fw1  = (const float*)d_in[15];
    const float* fb1  = (const float*)d_in[16];
    const float* fw2  = (const float*)d_in[17];
    const float* fb2  = (const float*)d_in[18];
    const float* fw3  = (const float*)d_in[19];
    const float* fb3  = (const float*)d_in[20];
    float* outp = (float*)d_out;

    const int N = in_sizes[0] / 21;
    const int E = in_sizes[1] / 2;
    const int G = out_size;

    // ---- workspace carve ----
    char* p = (char*)d_ws;
    auto alloc = [&](size_t bytes) -> void* {
        void* r = (void*)p;
        p += (bytes + 255) & ~(size_t)255;
        return r;
    };
    int*   deg  = (int*)alloc((size_t)N * 4);
    int*   offs = (int*)alloc((size_t)(N + 1) * 4);
    int*   csr  = (int*)alloc((size_t)E * 4);
    unsigned short* rank = (unsigned short*)alloc((size_t)E * 2);
    int*   bsum = (int*)alloc((size_t)256 * 4);
    unsigned char*  h8  = (unsigned char*)alloc((size_t)N * 256);       // fp8 gather operand
    unsigned short* hbf = (unsigned short*)alloc((size_t)N * 256 * 2);  // bf16 gather output
    float* h3   = (float*)alloc((size_t)N * 32 * 4);
    float* hP   = (float*)alloc((size_t)N * 32 * 4);
    float* asb  = (float*)alloc((size_t)N * 4 * 4);
    float* adb  = (float*)alloc((size_t)N * 4 * 4);
    unsigned short* w2p = (unsigned short*)alloc((size_t)256 * 256 * 2);
    unsigned short* w3p = (unsigned short*)alloc((size_t)256 * 32 * 2);

    const int* esrc = ei;
    const int* edst = ei + E;

    (void)hipMemsetAsync(deg, 0, (size_t)N * 4, stream);

    const int sb = (N + 1023) / 1024;          // scan blocks (<= 256)
    const int DB = (E + 1023) / 1024;          // deg blocks (4 edges/thread)
    const int SB = (E + 1023) / 1024;          // scatter blocks (4 edges/thread)

    // ---- CSR build: deg+rank+packs, scan, atomic-free scatter ----
    k_deg_pack<<<DB + 256 + 32, 256, 0, stream>>>(edst, deg, rank, E, DB, w2, w2p, w3, w3p);
    k_scan1<<<sb, 1024, 0, stream>>>(deg, bsum, N);
    k_scan2<<<1, 256, 0, stream>>>(bsum, sb);
    k_scan3<<<sb, 1024, 0, stream>>>(deg, bsum, offs, N);
    k_scatter<<<SB, 256, 0, stream>>>(esrc, edst, rank, offs, csr, E);

    const int gblk = (N + 63) / 64;

    // ---- layer 1 ----
    k_gemm1<<<(N + 7) / 8, 256, 0, stream>>>(x, w1, as1, ad1, h8, asb, adb, N);
    k_gather256<<<(N + 3) / 4, 256, 0, stream>>>((const unsigned int*)h8, asb, adb, offs, csr, b1, hbf, N);

    // ---- layer 2 ----
    k_gemm2_mfma<<<gblk, 256, 0, stream>>>(hbf, w2p, as2, ad2, h8, asb, adb, N);
    k_gather256<<<(N + 3) / 4, 256, 0, stream>>>((const unsigned int*)h8, asb, adb, offs, csr, b2, hbf, N);

    // ---- layer 3 ----
    k_gemm3_mfma<<<gblk, 256, 0, stream>>>(hbf, w3p, as3, ad3, h3, asb, adb, N);
    k_gather32<<<(N + 7) / 8, 256, 0, stream>>>(h3, asb, adb, offs, csr, b3, hP, N);

    // ---- fused pool + head ----
    k_pool_head<<<G, 256, 0, stream>>>(hP, batch, N, fw1, fb1, fw2, fb2, fw3, fb3, outp, G);
}

// Round 11
// 503.502 us; speedup vs baseline: 4.2139x; 1.1019x over previous
//
#include <hip/hip_runtime.h>
#include <math.h>

typedef float f4 __attribute__((ext_vector_type(4)));
typedef float f32x4 __attribute__((ext_vector_type(4)));
typedef float f32x2 __attribute__((ext_vector_type(2)));
typedef short bf16x8 __attribute__((ext_vector_type(8)));
typedef unsigned int u32x2 __attribute__((ext_vector_type(2)));
typedef int i32x4 __attribute__((ext_vector_type(4)));
typedef unsigned short u16x4 __attribute__((ext_vector_type(4)));

// ---------------- device helpers ----------------
__device__ __forceinline__ float lrelu(float x) { return x >= 0.f ? x : 0.2f * x; }
__device__ __forceinline__ float eluf(float x)  { return x > 0.f ? x : __expf(x) - 1.f; }

__device__ __forceinline__ float bf2f(unsigned short u) {
    union { unsigned int i; float f; } c; c.i = ((unsigned int)u) << 16; return c.f;
}
__device__ __forceinline__ unsigned short f2bf(float f) {
    union { float f; unsigned int i; } c; c.f = f;
    unsigned int r = c.i + 0x7fffu + ((c.i >> 16) & 1u);   // RNE
    return (unsigned short)(r >> 16);
}
__device__ __forceinline__ unsigned char f2f8(float f) {
    return (unsigned char)(__builtin_amdgcn_cvt_pk_fp8_f32(f, f, 0u, false) & 0xffu);
}

// ---------------- fused: deg histogram + rank capture + weight packs ----------------
__global__ void k_deg_pack(const int* __restrict__ edst, int* __restrict__ deg,
                           unsigned short* __restrict__ rank, int E, int DB,
                           const float* __restrict__ w2, unsigned short* __restrict__ w2p,
                           const float* __restrict__ w3, unsigned short* __restrict__ w3p) {
    int b = blockIdx.x;
    int tid = threadIdx.x;
    if (b < DB) {
        int base = (b * 256 + tid) * 4;
        if (base + 3 < E) {
            i32x4 d = *reinterpret_cast<const i32x4*>(&edst[base]);
            u16x4 r;
            r.x = (unsigned short)atomicAdd(&deg[d.x], 1);
            r.y = (unsigned short)atomicAdd(&deg[d.y], 1);
            r.z = (unsigned short)atomicAdd(&deg[d.z], 1);
            r.w = (unsigned short)atomicAdd(&deg[d.w], 1);
            *reinterpret_cast<u16x4*>(&rank[base]) = r;
        } else {
            for (int e = base; e < E; ++e)
                rank[e] = (unsigned short)atomicAdd(&deg[edst[e]], 1);
        }
    } else if (b < DB + 256) {
        int i = (b - DB) * 256 + tid;          // w2: 256x256
        int k = i >> 8, c = i & 255;
        w2p[((size_t)(k >> 3) * 256 + c) * 8 + (k & 7)] = f2bf(w2[i]);
    } else {
        int i = (b - DB - 256) * 256 + tid;    // w3: 256x32
        int k = i >> 5, c = i & 31;
        w3p[((size_t)(k >> 3) * 32 + c) * 8 + (k & 7)] = f2bf(w3[i]);
    }
}

// ---- multi-block exclusive scan over deg[N] -> offs[N+1] ----
__global__ __launch_bounds__(1024) void k_scan1(const int* __restrict__ deg,
                                                int* __restrict__ bsum, int N) {
    int t = threadIdx.x;
    int i = blockIdx.x * 1024 + t;
    int v = (i < N) ? deg[i] : 0;
#pragma unroll
    for (int m = 32; m; m >>= 1) v += __shfl_xor(v, m);
    __shared__ int ws[16];
    if ((t & 63) == 0) ws[t >> 6] = v;
    __syncthreads();
    if (t < 16) {
        int s = ws[t];
#pragma unroll
        for (int m = 8; m; m >>= 1) s += __shfl_xor(s, m);
        if (t == 0) bsum[blockIdx.x] = s;
    }
}

__global__ void k_scan2(int* __restrict__ bsum, int B) {
    __shared__ int sm[256];
    int t = threadIdx.x;
    int v = (t < B) ? bsum[t] : 0;
    sm[t] = v;
    __syncthreads();
    for (int d = 1; d < 256; d <<= 1) {
        int x = (t >= d) ? sm[t - d] : 0;
        __syncthreads();
        sm[t] += x;
        __syncthreads();
    }
    if (t < B) bsum[t] = sm[t] - v;
}

__global__ __launch_bounds__(1024) void k_scan3(const int* __restrict__ deg,
                                                const int* __restrict__ bsum,
                                                int* __restrict__ offs, int N) {
    __shared__ int sm[1024];
    int t = threadIdx.x;
    int i = blockIdx.x * 1024 + t;
    int v = (i < N) ? deg[i] : 0;
    sm[t] = v;
    __syncthreads();
    for (int d = 1; d < 1024; d <<= 1) {
        int x = (t >= d) ? sm[t - d] : 0;
        __syncthreads();
        sm[t] += x;
        __syncthreads();
    }
    int pref = bsum[blockIdx.x] + sm[t] - v;
    if (i < N) offs[i] = pref;
    if (i == N - 1) offs[N] = pref + v;
}

// ---------------- atomic-free scatter: csr[offs[dst]+rank] = src ----------------
__global__ void k_scatter(const int* __restrict__ esrc, const int* __restrict__ edst,
                          const unsigned short* __restrict__ rank,
                          const int* __restrict__ offs, int* __restrict__ csr, int E) {
    int base = (blockIdx.x * 256 + threadIdx.x) * 4;
    if (base + 3 < E) {
        i32x4 s = *reinterpret_cast<const i32x4*>(&esrc[base]);
        i32x4 d = *reinterpret_cast<const i32x4*>(&edst[base]);
        u16x4 r = *reinterpret_cast<const u16x4*>(&rank[base]);
        csr[offs[d.x] + r.x] = s.x;
        csr[offs[d.y] + r.y] = s.y;
        csr[offs[d.z] + r.z] = s.z;
        csr[offs[d.w] + r.w] = s.w;
    } else {
        for (int e = base; e < E; ++e) csr[offs[edst[e]] + rank[e]] = esrc[e];
    }
}

// ---------------- L1 GEMM (VALU, K=21) -> h fp8 + scores ----------------
__global__ void k_gemm1(const float* __restrict__ x, const float* __restrict__ w,
                        const float* __restrict__ aw_s, const float* __restrict__ aw_d,
                        unsigned char* __restrict__ h8, float* __restrict__ asb,
                        float* __restrict__ adb, int N) {
    int tid = threadIdx.x;
    int row0 = blockIdx.x * 8;
    __shared__ float xs[8][21];
    int nrows = min(8, N - row0);
    for (int i = tid; i < nrows * 21; i += 256) xs[i / 21][i % 21] = x[row0 * 21 + i];
    __syncthreads();
    float wreg[21];
#pragma unroll
    for (int k = 0; k < 21; ++k) wreg[k] = w[k * 256 + tid];
    float avs = aw_s[tid], avd = aw_d[tid];
    int head = tid >> 6;
    for (int r = 0; r < nrows; ++r) {
        float acc = 0.f;
#pragma unroll
        for (int k = 0; k < 21; ++k) acc = fmaf(xs[r][k], wreg[k], acc);
        h8[(size_t)(row0 + r) * 256 + tid] = f2f8(acc);
        float s1 = acc * avs, s2 = acc * avd;
#pragma unroll
        for (int m = 32; m; m >>= 1) { s1 += __shfl_xor(s1, m); s2 += __shfl_xor(s2, m); }
        if ((tid & 63) == 0) {
            asb[(row0 + r) * 4 + head] = s1;
            adb[(row0 + r) * 4 + head] = s2;
        }
    }
}

// ---------------- L2 GEMM via MFMA: in bf16 -> h fp8 + scores ----------------
__global__ __launch_bounds__(256) void k_gemm2_mfma(
        const unsigned short* __restrict__ in, const unsigned short* __restrict__ w2p,
        const float* __restrict__ as2f, const float* __restrict__ ad2f,
        unsigned char* __restrict__ h8, float* __restrict__ asb,
        float* __restrict__ adb, int N) {
    int tid = threadIdx.x;
    int wave = tid >> 6, lane = tid & 63;
    int g = lane >> 4, q = lane & 15;
    int row0 = blockIdx.x * 64 + wave * 16;

    f32x4 acc[16];
#pragma unroll
    for (int ct = 0; ct < 16; ++ct) acc[ct] = (f32x4)0.f;

    const unsigned short* aptr = in + (size_t)(row0 + q) * 256 + g * 8;
    const unsigned short* bptr = w2p + ((size_t)g * 256 + q) * 8;

#pragma unroll
    for (int kt = 0; kt < 8; ++kt) {
        bf16x8 a = *reinterpret_cast<const bf16x8*>(aptr + kt * 32);
#pragma unroll
        for (int ct = 0; ct < 16; ++ct) {
            bf16x8 b = *reinterpret_cast<const bf16x8*>(bptr + (size_t)kt * 8192 + ct * 128);
            acc[ct] = __builtin_amdgcn_mfma_f32_16x16x32_bf16(a, b, acc[ct], 0, 0, 0);
        }
    }

#pragma unroll
    for (int ct = 0; ct < 16; ++ct) {
        int col = ct * 16 + q;
#pragma unroll
        for (int r = 0; r < 4; ++r) {
            int row = row0 + 4 * g + r;
            if (row < N) h8[(size_t)row * 256 + col] = f2f8(acc[ct][r]);
        }
    }

#pragma unroll
    for (int h = 0; h < 4; ++h) {
        float s1[4] = {0.f, 0.f, 0.f, 0.f}, s2[4] = {0.f, 0.f, 0.f, 0.f};
#pragma unroll
        for (int cc = 0; cc < 4; ++cc) {
            int ct = h * 4 + cc;
            int col = ct * 16 + q;
            float ws_ = as2f[col], wd_ = ad2f[col];
#pragma unroll
            for (int r = 0; r < 4; ++r) {
                s1[r] = fmaf(acc[ct][r], ws_, s1[r]);
                s2[r] = fmaf(acc[ct][r], wd_, s2[r]);
            }
        }
#pragma unroll
        for (int m = 1; m < 16; m <<= 1) {
#pragma unroll
            for (int r = 0; r < 4; ++r) {
                s1[r] += __shfl_xor(s1[r], m);
                s2[r] += __shfl_xor(s2[r], m);
            }
        }
        if (q == 0) {
#pragma unroll
            for (int r = 0; r < 4; ++r) {
                int row = row0 + 4 * g + r;
                if (row < N) { asb[row * 4 + h] = s1[r]; adb[row * 4 + h] = s2[r]; }
            }
        }
    }
}

// ---------------- L3 GEMM via MFMA -> h3 fp32 + scores ----------------
__global__ __launch_bounds__(256) void k_gemm3_mfma(
        const unsigned short* __restrict__ in, const unsigned short* __restrict__ w3p,
        const float* __restrict__ as3f, const float* __restrict__ ad3f,
        float* __restrict__ h3, float* __restrict__ asb, float* __restrict__ adb, int N) {
    int tid = threadIdx.x;
    int wave = tid >> 6, lane = tid & 63;
    int g = lane >> 4, q = lane & 15;
    int row0 = blockIdx.x * 64 + wave * 16;

    f32x4 acc[2];
    acc[0] = (f32x4)0.f; acc[1] = (f32x4)0.f;

    const unsigned short* aptr = in + (size_t)(row0 + q) * 256 + g * 8;
    const unsigned short* bptr = w3p + ((size_t)g * 32 + q) * 8;

#pragma unroll
    for (int kt = 0; kt < 8; ++kt) {
        bf16x8 a = *reinterpret_cast<const bf16x8*>(aptr + kt * 32);
#pragma unroll
        for (int ct = 0; ct < 2; ++ct) {
            bf16x8 b = *reinterpret_cast<const bf16x8*>(bptr + (size_t)kt * 1024 + ct * 128);
            acc[ct] = __builtin_amdgcn_mfma_f32_16x16x32_bf16(a, b, acc[ct], 0, 0, 0);
        }
    }

    float s1[4] = {0.f, 0.f, 0.f, 0.f}, s2[4] = {0.f, 0.f, 0.f, 0.f};
#pragma unroll
    for (int ct = 0; ct < 2; ++ct) {
        int col = ct * 16 + q;
        float ws_ = as3f[col], wd_ = ad3f[col];
#pragma unroll
        for (int r = 0; r < 4; ++r) {
            int row = row0 + 4 * g + r;
            if (row < N) h3[(size_t)row * 32 + col] = acc[ct][r];
            s1[r] = fmaf(acc[ct][r], ws_, s1[r]);
            s2[r] = fmaf(acc[ct][r], wd_, s2[r]);
        }
    }
#pragma unroll
    for (int m = 1; m < 16; m <<= 1) {
#pragma unroll
        for (int r = 0; r < 4; ++r) {
            s1[r] += __shfl_xor(s1[r], m);
            s2[r] += __shfl_xor(s2[r], m);
        }
    }
    if (q == 0) {
#pragma unroll
        for (int r = 0; r < 4; ++r) {
            int row = row0 + 4 * g + r;
            if (row < N) { asb[row] = s1[r]; adb[row] = s2[r]; }
        }
    }
}

// ---------------- gather (attention aggregate), F=256 fp8 -> bf16, 4 heads ----------------
__global__ void k_gather256(const unsigned int* __restrict__ h8,
                            const float* __restrict__ asb, const float* __restrict__ adb,
                            const int* __restrict__ offs, const int* __restrict__ csr,
                            const float* __restrict__ bias, unsigned short* __restrict__ out,
                            int N) {
    int tid = threadIdx.x;
    int lane = tid & 63;
    int v = blockIdx.x * 4 + (tid >> 6);
    if (v >= N) return;
    int head = lane >> 4;
    int j16 = lane & 15;
    int gbase = lane & 48;          // head-group base lane
    float ad = adb[v * 4 + head];
    float w0 = __expf(lrelu(asb[v * 4 + head] + ad));
    float den = w0;
    float a0, a1, a2, a3;
    {
        unsigned int hv = h8[(size_t)v * 64 + lane];
        f32x2 lo = __builtin_amdgcn_cvt_pk_f32_fp8(hv, false);
        f32x2 hi = __builtin_amdgcn_cvt_pk_f32_fp8(hv, true);
        a0 = w0 * lo.x; a1 = w0 * lo.y; a2 = w0 * hi.x; a3 = w0 * hi.y;
    }
    int beg = offs[v], end = offs[v + 1];
    for (int c = beg; c < end; c += 16) {
        int idx = c + j16;
        int u = 0;
        float w = 0.f;
        if (idx < end) {
            u = csr[idx];
            w = __expf(lrelu(asb[u * 4 + head] + ad));
        }
#pragma unroll
        for (int j = 0; j < 16; ++j) {
            float wj = __shfl(w, gbase | j);
            int   uj = __shfl(u, gbase | j);
            den += wj;
            unsigned int hv = h8[(size_t)uj * 64 + lane];
            f32x2 lo = __builtin_amdgcn_cvt_pk_f32_fp8(hv, false);
            f32x2 hi = __builtin_amdgcn_cvt_pk_f32_fp8(hv, true);
            a0 = fmaf(wj, lo.x, a0); a1 = fmaf(wj, lo.y, a1);
            a2 = fmaf(wj, hi.x, a2); a3 = fmaf(wj, hi.y, a3);
        }
    }
    float inv = 1.f / (den + 1e-16f);
    int f0 = 4 * lane;
    unsigned int w01 = (unsigned int)f2bf(eluf(a0 * inv + bias[f0 + 0]))
                     | ((unsigned int)f2bf(eluf(a1 * inv + bias[f0 + 1])) << 16);
    unsigned int w23 = (unsigned int)f2bf(eluf(a2 * inv + bias[f0 + 2]))
                     | ((unsigned int)f2bf(eluf(a3 * inv + bias[f0 + 3])) << 16);
    u32x2 o; o.x = w01; o.y = w23;
    __builtin_nontemporal_store(o, reinterpret_cast<u32x2*>(&out[(size_t)v * 256 + f0]));
}

// ---------------- gather, F=32 fp32, 1 head — chunked ILP (32 edges/chunk) ----------------
__global__ void k_gather32(const float* __restrict__ h, const float* __restrict__ asb,
                           const float* __restrict__ adb, const int* __restrict__ offs,
                           const int* __restrict__ csr, const float* __restrict__ bias,
                           float* __restrict__ out, int N) {
    int tid = threadIdx.x;
    int v = blockIdx.x * 8 + (tid >> 5);
    int c = tid & 31;
    int gbase = tid & 32;           // 32-lane group base within the wave
    if (v >= N) return;
    float ad = adb[v];
    float w0 = __expf(lrelu(asb[v] + ad));
    float den = w0;
    float acc = w0 * h[(size_t)v * 32 + c];
    int beg = offs[v], end = offs[v + 1];
    for (int e0 = beg; e0 < end; e0 += 32) {
        int idx = e0 + c;
        int u = 0;
        float w = 0.f;
        if (idx < end) {
            u = csr[idx];
            w = __expf(lrelu(asb[u] + ad));
        }
#pragma unroll
        for (int j = 0; j < 32; ++j) {
            float wj = __shfl(w, gbase | j);
            int   uj = __shfl(u, gbase | j);
            den += wj;
            acc = fmaf(wj, h[(size_t)uj * 32 + c], acc);
        }
    }
    float o = eluf(acc / (den + 1e-16f) + bias[c]);
    __builtin_nontemporal_store(o, &out[(size_t)v * 32 + c]);
}

// ---------------- fused mean-pool + MLP head ----------------
__global__ __launch_bounds__(256) void k_pool_head(
        const float* __restrict__ h, const int* __restrict__ batch, int N,
        const float* __restrict__ fw1, const float* __restrict__ fb1,
        const float* __restrict__ fw2, const float* __restrict__ fb2,
        const float* __restrict__ fw3, const float* __restrict__ fb3,
        float* __restrict__ out, int G) {
    int g = blockIdx.x;
    int tid = threadIdx.x;
    __shared__ int bounds[2];
    __shared__ float red[8][32];
    __shared__ float pooled[32];
    __shared__ float t1[64];
    __shared__ float t2[32];

    if (tid < 2) {
        int target = g + tid;
        int lo = 0, hi = N;
        while (lo < hi) {
            int mid = (lo + hi) >> 1;
            if (batch[mid] < target) lo = mid + 1; else hi = mid;
        }
        bounds[tid] = lo;
    }
    __syncthreads();
    int beg = bounds[0], end = bounds[1];

    int f = tid & 31, r = tid >> 5;
    float s = 0.f;
    for (int i = beg + r; i < end; i += 8) s += h[(size_t)i * 32 + f];
    red[r][f] = s;
    __syncthreads();

    if (tid < 32) {
        float t = 0.f;
#pragma unroll
        for (int k = 0; k < 8; ++k) t += red[k][tid];
        float invc = 1.f / fmaxf((float)(end - beg), 1.f);
        pooled[tid] = t * invc;
    }
    __syncthreads();

    if (tid < 64) {
        float a = fb1[tid];
#pragma unroll
        for (int k = 0; k < 32; ++k) a = fmaf(pooled[k], fw1[k * 64 + tid], a);
        t1[tid] = fmaxf(a, 0.f);
    }
    __syncthreads();
    if (tid < 32) {
        float a = fb2[tid];
#pragma unroll
        for (int k = 0; k < 64; ++k) a = fmaf(t1[k], fw2[k * 32 + tid], a);
        t2[tid] = fmaxf(a, 0.f);
    }
    __syncthreads();
    if (tid == 0) {
        float o = fb3[0];
#pragma unroll
        for (int k = 0; k < 32; ++k) o = fmaf(t2[k], fw3[k], o);
        out[g] = 1.f / (1.f + __expf(-o));
    }
}

// ---------------- host ----------------
extern "C" void kernel_launch(void* const* d_in, const int* in_sizes, int n_in,
                              void* d_out, int out_size, void* d_ws, size_t ws_size,
                              hipStream_t stream) {
    const float* x    = (const float*)d_in[0];
    const int*   ei   = (const int*)d_in[1];
    const int*   batch= (const int*)d_in[2];
    const float* w1   = (const float*)d_in[3];
    const float* as1  = (const float*)d_in[4];
    const float* ad1  = (const float*)d_in[5];
    const float* b1   = (const float*)d_in[6];
    const float* w2   = (const float*)d_in[7];
    const float* as2  = (const float*)d_in[8];
    const float* ad2  = (const float*)d_in[9];
    const float* b2   = (const float*)d_in[10];
    const float* w3   = (const float*)d_in[11];
    const float* as3  = (const float*)d_in[12];
    const float* ad3  = (const float*)d_in[13];
    const float* b3   = (const float*)d_in[14];
    const float* fw1  = (const float*)d_in[15];
    const float* fb1  = (const float*)d_in[16];
    const float* fw2  = (const float*)d_in[17];
    const float* fb2  = (const float*)d_in[18];
    const float* fw3  = (const float*)d_in[19];
    const float* fb3  = (const float*)d_in[20];
    float* outp = (float*)d_out;

    const int N = in_sizes[0] / 21;
    const int E = in_sizes[1] / 2;
    const int G = out_size;

    // ---- workspace carve ----
    char* p = (char*)d_ws;
    auto alloc = [&](size_t bytes) -> void* {
        void* r = (void*)p;
        p += (bytes + 255) & ~(size_t)255;
        return r;
    };
    int*   deg  = (int*)alloc((size_t)N * 4);
    int*   offs = (int*)alloc((size_t)(N + 1) * 4);
    int*   csr  = (int*)alloc((size_t)E * 4);
    unsigned short* rank = (unsigned short*)alloc((size_t)E * 2);
    int*   bsum = (int*)alloc((size_t)256 * 4);
    unsigned char*  h8  = (unsigned char*)alloc((size_t)N * 256);       // fp8 gather operand
    unsigned short* hbf = (unsigned short*)alloc((size_t)N * 256 * 2);  // bf16 gather output
    float* h3   = (float*)alloc((size_t)N * 32 * 4);
    float* hP   = (float*)alloc((size_t)N * 32 * 4);
    float* asb  = (float*)alloc((size_t)N * 4 * 4);
    float* adb  = (float*)alloc((size_t)N * 4 * 4);
    unsigned short* w2p = (unsigned short*)alloc((size_t)256 * 256 * 2);
    unsigned short* w3p = (unsigned short*)alloc((size_t)256 * 32 * 2);

    const int* esrc = ei;
    const int* edst = ei + E;

    (void)hipMemsetAsync(deg, 0, (size_t)N * 4, stream);

    const int sb = (N + 1023) / 1024;          // scan blocks (<= 256)
    const int DB = (E + 1023) / 1024;          // deg blocks (4 edges/thread)
    const int SB = (E + 1023) / 1024;          // scatter blocks (4 edges/thread)

    // ---- CSR build: deg+rank+packs, scan, atomic-free scatter ----
    k_deg_pack<<<DB + 256 + 32, 256, 0, stream>>>(edst, deg, rank, E, DB, w2, w2p, w3, w3p);
    k_scan1<<<sb, 1024, 0, stream>>>(deg, bsum, N);
    k_scan2<<<1, 256, 0, stream>>>(bsum, sb);
    k_scan3<<<sb, 1024, 0, stream>>>(deg, bsum, offs, N);
    k_scatter<<<SB, 256, 0, stream>>>(esrc, edst, rank, offs, csr, E);

    const int gblk = (N + 63) / 64;

    // ---- layer 1 ----
    k_gemm1<<<(N + 7) / 8, 256, 0, stream>>>(x, w1, as1, ad1, h8, asb, adb, N);
    k_gather256<<<(N + 3) / 4, 256, 0, stream>>>((const unsigned int*)h8, asb, adb, offs, csr, b1, hbf, N);

    // ---- layer 2 ----
    k_gemm2_mfma<<<gblk, 256, 0, stream>>>(hbf, w2p, as2, ad2, h8, asb, adb, N);
    k_gather256<<<(N + 3) / 4, 256, 0, stream>>>((const unsigned int*)h8, asb, adb, offs, csr, b2, hbf, N);

    // ---- layer 3 ----
    k_gemm3_mfma<<<gblk, 256, 0, stream>>>(hbf, w3p, as3, ad3, h3, asb, adb, N);
    k_gather32<<<(N + 7) / 8, 256, 0, stream>>>(h3, asb, adb, offs, csr, b3, hP, N);

    // ---- fused pool + head ----
    k_pool_head<<<G, 256, 0, stream>>>(hP, batch, N, fw1, fb1, fw2, fb2, fw3, fb3, outp, G);
}

// Round 12
// 455.824 us; speedup vs baseline: 4.6547x; 1.1046x over previous
//
#include <hip/hip_runtime.h>
#include <math.h>

typedef float f4 __attribute__((ext_vector_type(4)));
typedef float f32x4 __attribute__((ext_vector_type(4)));
typedef float f32x2 __attribute__((ext_vector_type(2)));
typedef short bf16x8 __attribute__((ext_vector_type(8)));
typedef unsigned int u32x2 __attribute__((ext_vector_type(2)));
typedef int i32x4 __attribute__((ext_vector_type(4)));
typedef unsigned short u16x4 __attribute__((ext_vector_type(4)));

// ---------------- device helpers ----------------
__device__ __forceinline__ float lrelu(float x) { return x >= 0.f ? x : 0.2f * x; }
__device__ __forceinline__ float eluf(float x)  { return x > 0.f ? x : __expf(x) - 1.f; }

__device__ __forceinline__ float bf2f(unsigned short u) {
    union { unsigned int i; float f; } c; c.i = ((unsigned int)u) << 16; return c.f;
}
__device__ __forceinline__ unsigned short f2bf(float f) {
    union { float f; unsigned int i; } c; c.f = f;
    unsigned int r = c.i + 0x7fffu + ((c.i >> 16) & 1u);   // RNE
    return (unsigned short)(r >> 16);
}
__device__ __forceinline__ unsigned char f2f8(float f) {
    return (unsigned char)(__builtin_amdgcn_cvt_pk_fp8_f32(f, f, 0u, false) & 0xffu);
}

// ---------------- fused: deg+rank, weight packs, L1 combined score weights ----------------
// cw[k][j] (21x8): j=2h -> sum_c w1[k][64h+c]*as1[h][c]; j=2h+1 -> same with ad1.
// Scores of layer 1 are then x @ cw  (scores are linear in h = x@W1).
__global__ void k_deg_pack(const int* __restrict__ edst, int* __restrict__ deg,
                           unsigned short* __restrict__ rank, int E, int DB,
                           const float* __restrict__ w2, unsigned short* __restrict__ w2p,
                           const float* __restrict__ w3, unsigned short* __restrict__ w3p,
                           const float* __restrict__ w1, const float* __restrict__ as1,
                           const float* __restrict__ ad1, float* __restrict__ cw) {
    int b = blockIdx.x;
    int tid = threadIdx.x;
    if (b < DB) {
        int base = (b * 256 + tid) * 4;
        if (base + 3 < E) {
            i32x4 d = *reinterpret_cast<const i32x4*>(&edst[base]);
            u16x4 r;
            r.x = (unsigned short)atomicAdd(&deg[d.x], 1);
            r.y = (unsigned short)atomicAdd(&deg[d.y], 1);
            r.z = (unsigned short)atomicAdd(&deg[d.z], 1);
            r.w = (unsigned short)atomicAdd(&deg[d.w], 1);
            *reinterpret_cast<u16x4*>(&rank[base]) = r;
        } else {
            for (int e = base; e < E; ++e)
                rank[e] = (unsigned short)atomicAdd(&deg[edst[e]], 1);
        }
    } else if (b < DB + 256) {
        int i = (b - DB) * 256 + tid;          // w2: 256x256
        int k = i >> 8, c = i & 255;
        w2p[((size_t)(k >> 3) * 256 + c) * 8 + (k & 7)] = f2bf(w2[i]);
    } else if (b < DB + 256 + 32) {
        int i = (b - DB - 256) * 256 + tid;    // w3: 256x32
        int k = i >> 5, c = i & 31;
        w3p[((size_t)(k >> 3) * 32 + c) * 8 + (k & 7)] = f2bf(w3[i]);
    } else {
        if (tid < 168) {                       // cw: 21x8 combined score weights
            int k = tid >> 3, j = tid & 7;
            int h = j >> 1;
            const float* av = (j & 1) ? ad1 : as1;
            float s = 0.f;
            for (int c = 0; c < 64; ++c)
                s = fmaf(w1[k * 256 + h * 64 + c], av[h * 64 + c], s);
            cw[k * 8 + j] = s;
        }
    }
}

// ---- multi-block exclusive scan over deg[N] -> offs[N+1] ----
__global__ __launch_bounds__(1024) void k_scan1(const int* __restrict__ deg,
                                                int* __restrict__ bsum, int N) {
    int t = threadIdx.x;
    int i = blockIdx.x * 1024 + t;
    int v = (i < N) ? deg[i] : 0;
#pragma unroll
    for (int m = 32; m; m >>= 1) v += __shfl_xor(v, m);
    __shared__ int ws[16];
    if ((t & 63) == 0) ws[t >> 6] = v;
    __syncthreads();
    if (t < 16) {
        int s = ws[t];
#pragma unroll
        for (int m = 8; m; m >>= 1) s += __shfl_xor(s, m);
        if (t == 0) bsum[blockIdx.x] = s;
    }
}

__global__ void k_scan2(int* __restrict__ bsum, int B) {
    __shared__ int sm[256];
    int t = threadIdx.x;
    int v = (t < B) ? bsum[t] : 0;
    sm[t] = v;
    __syncthreads();
    for (int d = 1; d < 256; d <<= 1) {
        int x = (t >= d) ? sm[t - d] : 0;
        __syncthreads();
        sm[t] += x;
        __syncthreads();
    }
    if (t < B) bsum[t] = sm[t] - v;
}

__global__ __launch_bounds__(1024) void k_scan3(const int* __restrict__ deg,
                                                const int* __restrict__ bsum,
                                                int* __restrict__ offs, int N) {
    __shared__ int sm[1024];
    int t = threadIdx.x;
    int i = blockIdx.x * 1024 + t;
    int v = (i < N) ? deg[i] : 0;
    sm[t] = v;
    __syncthreads();
    for (int d = 1; d < 1024; d <<= 1) {
        int x = (t >= d) ? sm[t - d] : 0;
        __syncthreads();
        sm[t] += x;
        __syncthreads();
    }
    int pref = bsum[blockIdx.x] + sm[t] - v;
    if (i < N) offs[i] = pref;
    if (i == N - 1) offs[N] = pref + v;
}

// ---------------- atomic-free scatter: csr[offs[dst]+rank] = src ----------------
__global__ void k_scatter(const int* __restrict__ esrc, const int* __restrict__ edst,
                          const unsigned short* __restrict__ rank,
                          const int* __restrict__ offs, int* __restrict__ csr, int E) {
    int base = (blockIdx.x * 256 + threadIdx.x) * 4;
    if (base + 3 < E) {
        i32x4 s = *reinterpret_cast<const i32x4*>(&esrc[base]);
        i32x4 d = *reinterpret_cast<const i32x4*>(&edst[base]);
        u16x4 r = *reinterpret_cast<const u16x4*>(&rank[base]);
        csr[offs[d.x] + r.x] = s.x;
        csr[offs[d.y] + r.y] = s.y;
        csr[offs[d.z] + r.z] = s.z;
        csr[offs[d.w] + r.w] = s.w;
    } else {
        for (int e = base; e < E; ++e) csr[offs[edst[e]] + rank[e]] = esrc[e];
    }
}

// ---------------- L1 GEMM (VALU, K=21) -> h fp8; scores via x @ cw (no reductions) ----------------
__global__ void k_gemm1(const float* __restrict__ x, const float* __restrict__ w,
                        const float* __restrict__ cw,
                        unsigned char* __restrict__ h8, float* __restrict__ asb,
                        float* __restrict__ adb, int N) {
    int tid = threadIdx.x;
    int row0 = blockIdx.x * 8;
    __shared__ float xs[8][21];
    int nrows = min(8, N - row0);
    for (int i = tid; i < nrows * 21; i += 256) xs[i / 21][i % 21] = x[row0 * 21 + i];
    __syncthreads();
    float wreg[21];
#pragma unroll
    for (int k = 0; k < 21; ++k) wreg[k] = w[k * 256 + tid];
    for (int r = 0; r < nrows; ++r) {
        float acc = 0.f;
#pragma unroll
        for (int k = 0; k < 21; ++k) acc = fmaf(xs[r][k], wreg[k], acc);
        h8[(size_t)(row0 + r) * 256 + tid] = f2f8(acc);
    }
    // scores: 64 threads, one (row, head, s/d) slot each — 21-FMA dot from LDS
    if (tid < 64) {
        int r = tid >> 3, j = tid & 7;
        if (r < nrows) {
            float s = 0.f;
#pragma unroll
            for (int k = 0; k < 21; ++k) s = fmaf(xs[r][k], cw[k * 8 + j], s);
            int row = row0 + r;
            if (j & 1) adb[row * 4 + (j >> 1)] = s;
            else       asb[row * 4 + (j >> 1)] = s;
        }
    }
}

// ---------------- L2 GEMM via MFMA: in bf16 -> h fp8 + scores ----------------
__global__ __launch_bounds__(256) void k_gemm2_mfma(
        const unsigned short* __restrict__ in, const unsigned short* __restrict__ w2p,
        const float* __restrict__ as2f, const float* __restrict__ ad2f,
        unsigned char* __restrict__ h8, float* __restrict__ asb,
        float* __restrict__ adb, int N) {
    int tid = threadIdx.x;
    int wave = tid >> 6, lane = tid & 63;
    int g = lane >> 4, q = lane & 15;
    int row0 = blockIdx.x * 64 + wave * 16;

    f32x4 acc[16];
#pragma unroll
    for (int ct = 0; ct < 16; ++ct) acc[ct] = (f32x4)0.f;

    const unsigned short* aptr = in + (size_t)(row0 + q) * 256 + g * 8;
    const unsigned short* bptr = w2p + ((size_t)g * 256 + q) * 8;

#pragma unroll
    for (int kt = 0; kt < 8; ++kt) {
        bf16x8 a = *reinterpret_cast<const bf16x8*>(aptr + kt * 32);
#pragma unroll
        for (int ct = 0; ct < 16; ++ct) {
            bf16x8 b = *reinterpret_cast<const bf16x8*>(bptr + (size_t)kt * 8192 + ct * 128);
            acc[ct] = __builtin_amdgcn_mfma_f32_16x16x32_bf16(a, b, acc[ct], 0, 0, 0);
        }
    }

#pragma unroll
    for (int ct = 0; ct < 16; ++ct) {
        int col = ct * 16 + q;
#pragma unroll
        for (int r = 0; r < 4; ++r) {
            int row = row0 + 4 * g + r;
            if (row < N) h8[(size_t)row * 256 + col] = f2f8(acc[ct][r]);
        }
    }

#pragma unroll
    for (int h = 0; h < 4; ++h) {
        float s1[4] = {0.f, 0.f, 0.f, 0.f}, s2[4] = {0.f, 0.f, 0.f, 0.f};
#pragma unroll
        for (int cc = 0; cc < 4; ++cc) {
            int ct = h * 4 + cc;
            int col = ct * 16 + q;
            float ws_ = as2f[col], wd_ = ad2f[col];
#pragma unroll
            for (int r = 0; r < 4; ++r) {
                s1[r] = fmaf(acc[ct][r], ws_, s1[r]);
                s2[r] = fmaf(acc[ct][r], wd_, s2[r]);
            }
        }
#pragma unroll
        for (int m = 1; m < 16; m <<= 1) {
#pragma unroll
            for (int r = 0; r < 4; ++r) {
                s1[r] += __shfl_xor(s1[r], m);
                s2[r] += __shfl_xor(s2[r], m);
            }
        }
        if (q == 0) {
#pragma unroll
            for (int r = 0; r < 4; ++r) {
                int row = row0 + 4 * g + r;
                if (row < N) { asb[row * 4 + h] = s1[r]; adb[row * 4 + h] = s2[r]; }
            }
        }
    }
}

// ---------------- L3 GEMM via MFMA -> h3 fp32 + scores ----------------
__global__ __launch_bounds__(256) void k_gemm3_mfma(
        const unsigned short* __restrict__ in, const unsigned short* __restrict__ w3p,
        const float* __restrict__ as3f, const float* __restrict__ ad3f,
        float* __restrict__ h3, float* __restrict__ asb, float* __restrict__ adb, int N) {
    int tid = threadIdx.x;
    int wave = tid >> 6, lane = tid & 63;
    int g = lane >> 4, q = lane & 15;
    int row0 = blockIdx.x * 64 + wave * 16;

    f32x4 acc[2];
    acc[0] = (f32x4)0.f; acc[1] = (f32x4)0.f;

    const unsigned short* aptr = in + (size_t)(row0 + q) * 256 + g * 8;
    const unsigned short* bptr = w3p + ((size_t)g * 32 + q) * 8;

#pragma unroll
    for (int kt = 0; kt < 8; ++kt) {
        bf16x8 a = *reinterpret_cast<const bf16x8*>(aptr + kt * 32);
#pragma unroll
        for (int ct = 0; ct < 2; ++ct) {
            bf16x8 b = *reinterpret_cast<const bf16x8*>(bptr + (size_t)kt * 1024 + ct * 128);
            acc[ct] = __builtin_amdgcn_mfma_f32_16x16x32_bf16(a, b, acc[ct], 0, 0, 0);
        }
    }

    float s1[4] = {0.f, 0.f, 0.f, 0.f}, s2[4] = {0.f, 0.f, 0.f, 0.f};
#pragma unroll
    for (int ct = 0; ct < 2; ++ct) {
        int col = ct * 16 + q;
        float ws_ = as3f[col], wd_ = ad3f[col];
#pragma unroll
        for (int r = 0; r < 4; ++r) {
            int row = row0 + 4 * g + r;
            if (row < N) h3[(size_t)row * 32 + col] = acc[ct][r];
            s1[r] = fmaf(acc[ct][r], ws_, s1[r]);
            s2[r] = fmaf(acc[ct][r], wd_, s2[r]);
        }
    }
#pragma unroll
    for (int m = 1; m < 16; m <<= 1) {
#pragma unroll
        for (int r = 0; r < 4; ++r) {
            s1[r] += __shfl_xor(s1[r], m);
            s2[r] += __shfl_xor(s2[r], m);
        }
    }
    if (q == 0) {
#pragma unroll
        for (int r = 0; r < 4; ++r) {
            int row = row0 + 4 * g + r;
            if (row < N) { asb[row] = s1[r]; adb[row] = s2[r]; }
        }
    }
}

// ---------------- gather (attention aggregate), F=256 fp8 -> bf16, 4 heads ----------------
__global__ void k_gather256(const unsigned int* __restrict__ h8,
                            const float* __restrict__ asb, const float* __restrict__ adb,
                            const int* __restrict__ offs, const int* __restrict__ csr,
                            const float* __restrict__ bias, unsigned short* __restrict__ out,
                            int N) {
    int tid = threadIdx.x;
    int lane = tid & 63;
    int v = blockIdx.x * 4 + (tid >> 6);
    if (v >= N) return;
    int head = lane >> 4;
    int j16 = lane & 15;
    int gbase = lane & 48;          // head-group base lane
    float ad = adb[v * 4 + head];
    float w0 = __expf(lrelu(asb[v * 4 + head] + ad));
    float den = w0;
    float a0, a1, a2, a3;
    {
        unsigned int hv = h8[(size_t)v * 64 + lane];
        f32x2 lo = __builtin_amdgcn_cvt_pk_f32_fp8(hv, false);
        f32x2 hi = __builtin_amdgcn_cvt_pk_f32_fp8(hv, true);
        a0 = w0 * lo.x; a1 = w0 * lo.y; a2 = w0 * hi.x; a3 = w0 * hi.y;
    }
    int beg = offs[v], end = offs[v + 1];
    for (int c = beg; c < end; c += 16) {
        int idx = c + j16;
        int u = 0;
        float w = 0.f;
        if (idx < end) {
            u = csr[idx];
            w = __expf(lrelu(asb[u * 4 + head] + ad));
        }
#pragma unroll
        for (int j = 0; j < 16; ++j) {
            float wj = __shfl(w, gbase | j);
            int   uj = __shfl(u, gbase | j);
            den += wj;
            unsigned int hv = h8[(size_t)uj * 64 + lane];
            f32x2 lo = __builtin_amdgcn_cvt_pk_f32_fp8(hv, false);
            f32x2 hi = __builtin_amdgcn_cvt_pk_f32_fp8(hv, true);
            a0 = fmaf(wj, lo.x, a0); a1 = fmaf(wj, lo.y, a1);
            a2 = fmaf(wj, hi.x, a2); a3 = fmaf(wj, hi.y, a3);
        }
    }
    float inv = 1.f / (den + 1e-16f);
    int f0 = 4 * lane;
    unsigned int w01 = (unsigned int)f2bf(eluf(a0 * inv + bias[f0 + 0]))
                     | ((unsigned int)f2bf(eluf(a1 * inv + bias[f0 + 1])) << 16);
    unsigned int w23 = (unsigned int)f2bf(eluf(a2 * inv + bias[f0 + 2]))
                     | ((unsigned int)f2bf(eluf(a3 * inv + bias[f0 + 3])) << 16);
    u32x2 o; o.x = w01; o.y = w23;
    __builtin_nontemporal_store(o, reinterpret_cast<u32x2*>(&out[(size_t)v * 256 + f0]));
}

// ---------------- gather, F=32 fp32, 1 head — chunked ILP (32 edges/chunk) ----------------
__global__ void k_gather32(const float* __restrict__ h, const float* __restrict__ asb,
                           const float* __restrict__ adb, const int* __restrict__ offs,
                           const int* __restrict__ csr, const float* __restrict__ bias,
                           float* __restrict__ out, int N) {
    int tid = threadIdx.x;
    int v = blockIdx.x * 8 + (tid >> 5);
    int c = tid & 31;
    int gbase = tid & 32;           // 32-lane group base within the wave
    if (v >= N) return;
    float ad = adb[v];
    float w0 = __expf(lrelu(asb[v] + ad));
    float den = w0;
    float acc = w0 * h[(size_t)v * 32 + c];
    int beg = offs[v], end = offs[v + 1];
    for (int e0 = beg; e0 < end; e0 += 32) {
        int idx = e0 + c;
        int u = 0;
        float w = 0.f;
        if (idx < end) {
            u = csr[idx];
            w = __expf(lrelu(asb[u] + ad));
        }
#pragma unroll
        for (int j = 0; j < 32; ++j) {
            float wj = __shfl(w, gbase | j);
            int   uj = __shfl(u, gbase | j);
            den += wj;
            acc = fmaf(wj, h[(size_t)uj * 32 + c], acc);
        }
    }
    float o = eluf(acc / (den + 1e-16f) + bias[c]);
    __builtin_nontemporal_store(o, &out[(size_t)v * 32 + c]);
}

// ---------------- fused mean-pool + MLP head ----------------
__global__ __launch_bounds__(256) void k_pool_head(
        const float* __restrict__ h, const int* __restrict__ batch, int N,
        const float* __restrict__ fw1, const float* __restrict__ fb1,
        const float* __restrict__ fw2, const float* __restrict__ fb2,
        const float* __restrict__ fw3, const float* __restrict__ fb3,
        float* __restrict__ out, int G) {
    int g = blockIdx.x;
    int tid = threadIdx.x;
    __shared__ int bounds[2];
    __shared__ float red[8][32];
    __shared__ float pooled[32];
    __shared__ float t1[64];
    __shared__ float t2[32];

    if (tid < 2) {
        int target = g + tid;
        int lo = 0, hi = N;
        while (lo < hi) {
            int mid = (lo + hi) >> 1;
            if (batch[mid] < target) lo = mid + 1; else hi = mid;
        }
        bounds[tid] = lo;
    }
    __syncthreads();
    int beg = bounds[0], end = bounds[1];

    int f = tid & 31, r = tid >> 5;
    float s = 0.f;
    for (int i = beg + r; i < end; i += 8) s += h[(size_t)i * 32 + f];
    red[r][f] = s;
    __syncthreads();

    if (tid < 32) {
        float t = 0.f;
#pragma unroll
        for (int k = 0; k < 8; ++k) t += red[k][tid];
        float invc = 1.f / fmaxf((float)(end - beg), 1.f);
        pooled[tid] = t * invc;
    }
    __syncthreads();

    if (tid < 64) {
        float a = fb1[tid];
#pragma unroll
        for (int k = 0; k < 32; ++k) a = fmaf(pooled[k], fw1[k * 64 + tid], a);
        t1[tid] = fmaxf(a, 0.f);
    }
    __syncthreads();
    if (tid < 32) {
        float a = fb2[tid];
#pragma unroll
        for (int k = 0; k < 64; ++k) a = fmaf(t1[k], fw2[k * 32 + tid], a);
        t2[tid] = fmaxf(a, 0.f);
    }
    __syncthreads();
    if (tid == 0) {
        float o = fb3[0];
#pragma unroll
        for (int k = 0; k < 32; ++k) o = fmaf(t2[k], fw3[k], o);
        out[g] = 1.f / (1.f + __expf(-o));
    }
}

// ---------------- host ----------------
extern "C" void kernel_launch(void* const* d_in, const int* in_sizes, int n_in,
                              void* d_out, int out_size, void* d_ws, size_t ws_size,
                              hipStream_t stream) {
    const float* x    = (const float*)d_in[0];
    const int*   ei   = (const int*)d_in[1];
    const int*   batch= (const int*)d_in[2];
    const float* w1   = (const float*)d_in[3];
    const float* as1  = (const float*)d_in[4];
    const float* ad1  = (const float*)d_in[5];
    const float* b1   = (const float*)d_in[6];
    const float* w2   = (const float*)d_in[7];
    const float* as2  = (const float*)d_in[8];
    const float* ad2  = (const float*)d_in[9];
    const float* b2   = (const float*)d_in[10];
    const float* w3   = (const float*)d_in[11];
    const float* as3  = (const float*)d_in[12];
    const float* ad3  = (const float*)d_in[13];
    const float* b3   = (const float*)d_in[14];
    const float* fw1  = (const float*)d_in[15];
    const float* fb1  = (const float*)d_in[16];
    const float* fw2  = (const float*)d_in[17];
    const float* fb2  = (const float*)d_in[18];
    const float* fw3  = (const float*)d_in[19];
    const float* fb3  = (const float*)d_in[20];
    float* outp = (float*)d_out;

    const int N = in_sizes[0] / 21;
    const int E = in_sizes[1] / 2;
    const int G = out_size;

    // ---- workspace carve ----
    char* p = (char*)d_ws;
    auto alloc = [&](size_t bytes) -> void* {
        void* r = (void*)p;
        p += (bytes + 255) & ~(size_t)255;
        return r;
    };
    int*   deg  = (int*)alloc((size_t)N * 4);
    int*   offs = (int*)alloc((size_t)(N + 1) * 4);
    int*   csr  = (int*)alloc((size_t)E * 4);
    unsigned short* rank = (unsigned short*)alloc((size_t)E * 2);
    int*   bsum = (int*)alloc((size_t)256 * 4);
    unsigned char*  h8  = (unsigned char*)alloc((size_t)N * 256);       // fp8 gather operand
    unsigned short* hbf = (unsigned short*)alloc((size_t)N * 256 * 2);  // bf16 gather output
    float* h3   = (float*)alloc((size_t)N * 32 * 4);
    float* hP   = (float*)alloc((size_t)N * 32 * 4);
    float* asb  = (float*)alloc((size_t)N * 4 * 4);
    float* adb  = (float*)alloc((size_t)N * 4 * 4);
    unsigned short* w2p = (unsigned short*)alloc((size_t)256 * 256 * 2);
    unsigned short* w3p = (unsigned short*)alloc((size_t)256 * 32 * 2);
    float* cw   = (float*)alloc((size_t)21 * 8 * 4);                    // L1 combined score weights

    const int* esrc = ei;
    const int* edst = ei + E;

    (void)hipMemsetAsync(deg, 0, (size_t)N * 4, stream);

    const int sb = (N + 1023) / 1024;          // scan blocks (<= 256)
    const int DB = (E + 1023) / 1024;          // deg blocks (4 edges/thread)
    const int SB = (E + 1023) / 1024;          // scatter blocks (4 edges/thread)

    // ---- CSR build: deg+rank+packs+cw, scan, atomic-free scatter ----
    k_deg_pack<<<DB + 256 + 32 + 1, 256, 0, stream>>>(edst, deg, rank, E, DB,
                                                      w2, w2p, w3, w3p, w1, as1, ad1, cw);
    k_scan1<<<sb, 1024, 0, stream>>>(deg, bsum, N);
    k_scan2<<<1, 256, 0, stream>>>(bsum, sb);
    k_scan3<<<sb, 1024, 0, stream>>>(deg, bsum, offs, N);
    k_scatter<<<SB, 256, 0, stream>>>(esrc, edst, rank, offs, csr, E);

    const int gblk = (N + 63) / 64;

    // ---- layer 1 ----
    k_gemm1<<<(N + 7) / 8, 256, 0, stream>>>(x, w1, cw, h8, asb, adb, N);
    k_gather256<<<(N + 3) / 4, 256, 0, stream>>>((const unsigned int*)h8, asb, adb, offs, csr, b1, hbf, N);

    // ---- layer 2 ----
    k_gemm2_mfma<<<gblk, 256, 0, stream>>>(hbf, w2p, as2, ad2, h8, asb, adb, N);
    k_gather256<<<(N + 3) / 4, 256, 0, stream>>>((const unsigned int*)h8, asb, adb, offs, csr, b2, hbf, N);

    // ---- layer 3 ----
    k_gemm3_mfma<<<gblk, 256, 0, stream>>>(hbf, w3p, as3, ad3, h3, asb, adb, N);
    k_gather32<<<(N + 7) / 8, 256, 0, stream>>>(h3, asb, adb, offs, csr, b3, hP, N);

    // ---- fused pool + head ----
    k_pool_head<<<G, 256, 0, stream>>>(hP, batch, N, fw1, fb1, fw2, fb2, fw3, fb3, outp, G);
}

// Round 13
// 438.425 us; speedup vs baseline: 4.8394x; 1.0397x over previous
//
#include <hip/hip_runtime.h>
#include <math.h>

typedef float f4 __attribute__((ext_vector_type(4)));
typedef float f32x4 __attribute__((ext_vector_type(4)));
typedef float f32x2 __attribute__((ext_vector_type(2)));
typedef short bf16x8 __attribute__((ext_vector_type(8)));
typedef unsigned int u32x2 __attribute__((ext_vector_type(2)));
typedef int i32x4 __attribute__((ext_vector_type(4)));
typedef unsigned short u16x4 __attribute__((ext_vector_type(4)));

// ---------------- device helpers ----------------
__device__ __forceinline__ float lrelu(float x) { return x >= 0.f ? x : 0.2f * x; }
__device__ __forceinline__ float eluf(float x)  { return x > 0.f ? x : __expf(x) - 1.f; }

__device__ __forceinline__ float bf2f(unsigned short u) {
    union { unsigned int i; float f; } c; c.i = ((unsigned int)u) << 16; return c.f;
}
__device__ __forceinline__ unsigned short f2bf(float f) {
    union { float f; unsigned int i; } c; c.f = f;
    unsigned int r = c.i + 0x7fffu + ((c.i >> 16) & 1u);   // RNE
    return (unsigned short)(r >> 16);
}
__device__ __forceinline__ unsigned char f2f8(float f) {
    return (unsigned char)(__builtin_amdgcn_cvt_pk_fp8_f32(f, f, 0u, false) & 0xffu);
}

// ---------------- fused: deg+rank, weight packs, L1 combined score weights ----------------
__global__ void k_deg_pack(const int* __restrict__ edst, int* __restrict__ deg,
                           unsigned short* __restrict__ rank, int E, int DB,
                           const float* __restrict__ w2, unsigned short* __restrict__ w2p,
                           const float* __restrict__ w3, unsigned short* __restrict__ w3p,
                           const float* __restrict__ w1, const float* __restrict__ as1,
                           const float* __restrict__ ad1, float* __restrict__ cw) {
    int b = blockIdx.x;
    int tid = threadIdx.x;
    if (b < DB) {
        int base = (b * 256 + tid) * 4;
        if (base + 3 < E) {
            i32x4 d = *reinterpret_cast<const i32x4*>(&edst[base]);
            u16x4 r;
            r.x = (unsigned short)atomicAdd(&deg[d.x], 1);
            r.y = (unsigned short)atomicAdd(&deg[d.y], 1);
            r.z = (unsigned short)atomicAdd(&deg[d.z], 1);
            r.w = (unsigned short)atomicAdd(&deg[d.w], 1);
            *reinterpret_cast<u16x4*>(&rank[base]) = r;
        } else {
            for (int e = base; e < E; ++e)
                rank[e] = (unsigned short)atomicAdd(&deg[edst[e]], 1);
        }
    } else if (b < DB + 256) {
        int i = (b - DB) * 256 + tid;          // w2: 256x256
        int k = i >> 8, c = i & 255;
        w2p[((size_t)(k >> 3) * 256 + c) * 8 + (k & 7)] = f2bf(w2[i]);
    } else if (b < DB + 256 + 32) {
        int i = (b - DB - 256) * 256 + tid;    // w3: 256x32
        int k = i >> 5, c = i & 31;
        w3p[((size_t)(k >> 3) * 32 + c) * 8 + (k & 7)] = f2bf(w3[i]);
    } else {
        if (tid < 168) {                       // cw: 21x8 combined score weights
            int k = tid >> 3, j = tid & 7;
            int h = j >> 1;
            const float* av = (j & 1) ? ad1 : as1;
            float s = 0.f;
            for (int c = 0; c < 64; ++c)
                s = fmaf(w1[k * 256 + h * 64 + c], av[h * 64 + c], s);
            cw[k * 8 + j] = s;
        }
    }
}

// ---- multi-block exclusive scan over deg[N] -> offs[N+1] ----
__global__ __launch_bounds__(1024) void k_scan1(const int* __restrict__ deg,
                                                int* __restrict__ bsum, int N) {
    int t = threadIdx.x;
    int i = blockIdx.x * 1024 + t;
    int v = (i < N) ? deg[i] : 0;
#pragma unroll
    for (int m = 32; m; m >>= 1) v += __shfl_xor(v, m);
    __shared__ int ws[16];
    if ((t & 63) == 0) ws[t >> 6] = v;
    __syncthreads();
    if (t < 16) {
        int s = ws[t];
#pragma unroll
        for (int m = 8; m; m >>= 1) s += __shfl_xor(s, m);
        if (t == 0) bsum[blockIdx.x] = s;
    }
}

__global__ void k_scan2(int* __restrict__ bsum, int B) {
    __shared__ int sm[256];
    int t = threadIdx.x;
    int v = (t < B) ? bsum[t] : 0;
    sm[t] = v;
    __syncthreads();
    for (int d = 1; d < 256; d <<= 1) {
        int x = (t >= d) ? sm[t - d] : 0;
        __syncthreads();
        sm[t] += x;
        __syncthreads();
    }
    if (t < B) bsum[t] = sm[t] - v;
}

__global__ __launch_bounds__(1024) void k_scan3(const int* __restrict__ deg,
                                                const int* __restrict__ bsum,
                                                int* __restrict__ offs, int N) {
    __shared__ int sm[1024];
    int t = threadIdx.x;
    int i = blockIdx.x * 1024 + t;
    int v = (i < N) ? deg[i] : 0;
    sm[t] = v;
    __syncthreads();
    for (int d = 1; d < 1024; d <<= 1) {
        int x = (t >= d) ? sm[t - d] : 0;
        __syncthreads();
        sm[t] += x;
        __syncthreads();
    }
    int pref = bsum[blockIdx.x] + sm[t] - v;
    if (i < N) offs[i] = pref;
    if (i == N - 1) offs[N] = pref + v;
}

// ---------------- atomic-free scatter: csr[offs[dst]+rank] = src ----------------
__global__ void k_scatter(const int* __restrict__ esrc, const int* __restrict__ edst,
                          const unsigned short* __restrict__ rank,
                          const int* __restrict__ offs, int* __restrict__ csr, int E) {
    int base = (blockIdx.x * 256 + threadIdx.x) * 4;
    if (base + 3 < E) {
        i32x4 s = *reinterpret_cast<const i32x4*>(&esrc[base]);
        i32x4 d = *reinterpret_cast<const i32x4*>(&edst[base]);
        u16x4 r = *reinterpret_cast<const u16x4*>(&rank[base]);
        csr[offs[d.x] + r.x] = s.x;
        csr[offs[d.y] + r.y] = s.y;
        csr[offs[d.z] + r.z] = s.z;
        csr[offs[d.w] + r.w] = s.w;
    } else {
        for (int e = base; e < E; ++e) csr[offs[edst[e]] + rank[e]] = esrc[e];
    }
}

// ---------------- L1 GEMM (VALU, K=21) -> h fp8; scores via x @ cw ----------------
__global__ void k_gemm1(const float* __restrict__ x, const float* __restrict__ w,
                        const float* __restrict__ cw,
                        unsigned char* __restrict__ h8, float* __restrict__ asb,
                        float* __restrict__ adb, int N) {
    int tid = threadIdx.x;
    int row0 = blockIdx.x * 8;
    __shared__ float xs[8][21];
    int nrows = min(8, N - row0);
    for (int i = tid; i < nrows * 21; i += 256) xs[i / 21][i % 21] = x[row0 * 21 + i];
    __syncthreads();
    float wreg[21];
#pragma unroll
    for (int k = 0; k < 21; ++k) wreg[k] = w[k * 256 + tid];
    for (int r = 0; r < nrows; ++r) {
        float acc = 0.f;
#pragma unroll
        for (int k = 0; k < 21; ++k) acc = fmaf(xs[r][k], wreg[k], acc);
        h8[(size_t)(row0 + r) * 256 + tid] = f2f8(acc);
    }
    if (tid < 64) {
        int r = tid >> 3, j = tid & 7;
        if (r < nrows) {
            float s = 0.f;
#pragma unroll
            for (int k = 0; k < 21; ++k) s = fmaf(xs[r][k], cw[k * 8 + j], s);
            int row = row0 + r;
            if (j & 1) adb[row * 4 + (j >> 1)] = s;
            else       asb[row * 4 + (j >> 1)] = s;
        }
    }
}

// ---------------- L2 GEMM via MFMA (col-split waves): wave owns 64 cols x 64 rows ----------------
// Per kt: 4 A-loads + 4 B-loads -> 16 independent MFMAs; B-frags reused 4x in-register.
__global__ __launch_bounds__(256) void k_gemm2_mfma(
        const unsigned short* __restrict__ in, const unsigned short* __restrict__ w2p,
        const float* __restrict__ as2f, const float* __restrict__ ad2f,
        unsigned char* __restrict__ h8, float* __restrict__ asb,
        float* __restrict__ adb, int N) {
    int tid = threadIdx.x;
    int wave = tid >> 6, lane = tid & 63;
    int g = lane >> 4, q = lane & 15;
    int row0 = blockIdx.x * 64;

    f32x4 acc[4][4];   // [row-group][cc]
#pragma unroll
    for (int rg = 0; rg < 4; ++rg)
#pragma unroll
        for (int cc = 0; cc < 4; ++cc) acc[rg][cc] = (f32x4)0.f;

    const unsigned short* aptr = in + (size_t)(row0 + q) * 256 + g * 8;
    const unsigned short* bptr = w2p + ((size_t)g * 256 + q) * 8 + wave * 512;  // ct = wave*4+cc

#pragma unroll
    for (int kt = 0; kt < 8; ++kt) {
        bf16x8 a[4];
#pragma unroll
        for (int rg = 0; rg < 4; ++rg)
            a[rg] = *reinterpret_cast<const bf16x8*>(aptr + (size_t)rg * 16 * 256 + kt * 32);
#pragma unroll
        for (int cc = 0; cc < 4; ++cc) {
            bf16x8 b = *reinterpret_cast<const bf16x8*>(bptr + (size_t)kt * 8192 + cc * 128);
#pragma unroll
            for (int rg = 0; rg < 4; ++rg)
                acc[rg][cc] = __builtin_amdgcn_mfma_f32_16x16x32_bf16(a[rg], b, acc[rg][cc], 0, 0, 0);
        }
    }

    // fp8 output
#pragma unroll
    for (int rg = 0; rg < 4; ++rg) {
#pragma unroll
        for (int cc = 0; cc < 4; ++cc) {
            int col = (wave * 4 + cc) * 16 + q;
#pragma unroll
            for (int r = 0; r < 4; ++r) {
                int row = row0 + rg * 16 + 4 * g + r;
                if (row < N) h8[(size_t)row * 256 + col] = f2f8(acc[rg][cc][r]);
            }
        }
    }

    // scores: wave == head (cols wave*64 .. wave*64+63)
#pragma unroll
    for (int rg = 0; rg < 4; ++rg) {
        float s1[4] = {0.f, 0.f, 0.f, 0.f}, s2[4] = {0.f, 0.f, 0.f, 0.f};
#pragma unroll
        for (int cc = 0; cc < 4; ++cc) {
            int col = (wave * 4 + cc) * 16 + q;
            float ws_ = as2f[col], wd_ = ad2f[col];
#pragma unroll
            for (int r = 0; r < 4; ++r) {
                s1[r] = fmaf(acc[rg][cc][r], ws_, s1[r]);
                s2[r] = fmaf(acc[rg][cc][r], wd_, s2[r]);
            }
        }
#pragma unroll
        for (int m = 1; m < 16; m <<= 1) {
#pragma unroll
            for (int r = 0; r < 4; ++r) {
                s1[r] += __shfl_xor(s1[r], m);
                s2[r] += __shfl_xor(s2[r], m);
            }
        }
        if (q == 0) {
#pragma unroll
            for (int r = 0; r < 4; ++r) {
                int row = row0 + rg * 16 + 4 * g + r;
                if (row < N) { asb[row * 4 + wave] = s1[r]; adb[row * 4 + wave] = s2[r]; }
            }
        }
    }
}

// ---------------- L3 GEMM via MFMA -> h3 fp32 + scores ----------------
__global__ __launch_bounds__(256) void k_gemm3_mfma(
        const unsigned short* __restrict__ in, const unsigned short* __restrict__ w3p,
        const float* __restrict__ as3f, const float* __restrict__ ad3f,
        float* __restrict__ h3, float* __restrict__ asb, float* __restrict__ adb, int N) {
    int tid = threadIdx.x;
    int wave = tid >> 6, lane = tid & 63;
    int g = lane >> 4, q = lane & 15;
    int row0 = blockIdx.x * 64 + wave * 16;

    f32x4 acc[2];
    acc[0] = (f32x4)0.f; acc[1] = (f32x4)0.f;

    const unsigned short* aptr = in + (size_t)(row0 + q) * 256 + g * 8;
    const unsigned short* bptr = w3p + ((size_t)g * 32 + q) * 8;

#pragma unroll
    for (int kt = 0; kt < 8; ++kt) {
        bf16x8 a = *reinterpret_cast<const bf16x8*>(aptr + kt * 32);
#pragma unroll
        for (int ct = 0; ct < 2; ++ct) {
            bf16x8 b = *reinterpret_cast<const bf16x8*>(bptr + (size_t)kt * 1024 + ct * 128);
            acc[ct] = __builtin_amdgcn_mfma_f32_16x16x32_bf16(a, b, acc[ct], 0, 0, 0);
        }
    }

    float s1[4] = {0.f, 0.f, 0.f, 0.f}, s2[4] = {0.f, 0.f, 0.f, 0.f};
#pragma unroll
    for (int ct = 0; ct < 2; ++ct) {
        int col = ct * 16 + q;
        float ws_ = as3f[col], wd_ = ad3f[col];
#pragma unroll
        for (int r = 0; r < 4; ++r) {
            int row = row0 + 4 * g + r;
            if (row < N) h3[(size_t)row * 32 + col] = acc[ct][r];
            s1[r] = fmaf(acc[ct][r], ws_, s1[r]);
            s2[r] = fmaf(acc[ct][r], wd_, s2[r]);
        }
    }
#pragma unroll
    for (int m = 1; m < 16; m <<= 1) {
#pragma unroll
        for (int r = 0; r < 4; ++r) {
            s1[r] += __shfl_xor(s1[r], m);
            s2[r] += __shfl_xor(s2[r], m);
        }
    }
    if (q == 0) {
#pragma unroll
        for (int r = 0; r < 4; ++r) {
            int row = row0 + 4 * g + r;
            if (row < N) { asb[row] = s1[r]; adb[row] = s2[r]; }
        }
    }
}

// ---------------- gather (attention aggregate), F=256 fp8 -> bf16, 4 heads ----------------
__global__ void k_gather256(const unsigned int* __restrict__ h8,
                            const float* __restrict__ asb, const float* __restrict__ adb,
                            const int* __restrict__ offs, const int* __restrict__ csr,
                            const float* __restrict__ bias, unsigned short* __restrict__ out,
                            int N) {
    int tid = threadIdx.x;
    int lane = tid & 63;
    int v = blockIdx.x * 4 + (tid >> 6);
    if (v >= N) return;
    int head = lane >> 4;
    int j16 = lane & 15;
    int gbase = lane & 48;          // head-group base lane
    float ad = adb[v * 4 + head];
    float w0 = __expf(lrelu(asb[v * 4 + head] + ad));
    float den = w0;
    float a0, a1, a2, a3;
    {
        unsigned int hv = h8[(size_t)v * 64 + lane];
        f32x2 lo = __builtin_amdgcn_cvt_pk_f32_fp8(hv, false);
        f32x2 hi = __builtin_amdgcn_cvt_pk_f32_fp8(hv, true);
        a0 = w0 * lo.x; a1 = w0 * lo.y; a2 = w0 * hi.x; a3 = w0 * hi.y;
    }
    int beg = offs[v], end = offs[v + 1];
    for (int c = beg; c < end; c += 16) {
        int idx = c + j16;
        int u = 0;
        float w = 0.f;
        if (idx < end) {
            u = csr[idx];
            w = __expf(lrelu(asb[u * 4 + head] + ad));
        }
#pragma unroll
        for (int j = 0; j < 16; ++j) {
            float wj = __shfl(w, gbase | j);
            int   uj = __shfl(u, gbase | j);
            den += wj;
            unsigned int hv = h8[(size_t)uj * 64 + lane];
            f32x2 lo = __builtin_amdgcn_cvt_pk_f32_fp8(hv, false);
            f32x2 hi = __builtin_amdgcn_cvt_pk_f32_fp8(hv, true);
            a0 = fmaf(wj, lo.x, a0); a1 = fmaf(wj, lo.y, a1);
            a2 = fmaf(wj, hi.x, a2); a3 = fmaf(wj, hi.y, a3);
        }
    }
    float inv = 1.f / (den + 1e-16f);
    int f0 = 4 * lane;
    unsigned int w01 = (unsigned int)f2bf(eluf(a0 * inv + bias[f0 + 0]))
                     | ((unsigned int)f2bf(eluf(a1 * inv + bias[f0 + 1])) << 16);
    unsigned int w23 = (unsigned int)f2bf(eluf(a2 * inv + bias[f0 + 2]))
                     | ((unsigned int)f2bf(eluf(a3 * inv + bias[f0 + 3])) << 16);
    u32x2 o; o.x = w01; o.y = w23;
    __builtin_nontemporal_store(o, reinterpret_cast<u32x2*>(&out[(size_t)v * 256 + f0]));
}

// ---------------- gather, F=32 fp32, 1 head — chunked ILP (32 edges/chunk) ----------------
__global__ void k_gather32(const float* __restrict__ h, const float* __restrict__ asb,
                           const float* __restrict__ adb, const int* __restrict__ offs,
                           const int* __restrict__ csr, const float* __restrict__ bias,
                           float* __restrict__ out, int N) {
    int tid = threadIdx.x;
    int v = blockIdx.x * 8 + (tid >> 5);
    int c = tid & 31;
    int gbase = tid & 32;           // 32-lane group base within the wave
    if (v >= N) return;
    float ad = adb[v];
    float w0 = __expf(lrelu(asb[v] + ad));
    float den = w0;
    float acc = w0 * h[(size_t)v * 32 + c];
    int beg = offs[v], end = offs[v + 1];
    for (int e0 = beg; e0 < end; e0 += 32) {
        int idx = e0 + c;
        int u = 0;
        float w = 0.f;
        if (idx < end) {
            u = csr[idx];
            w = __expf(lrelu(asb[u] + ad));
        }
#pragma unroll
        for (int j = 0; j < 32; ++j) {
            float wj = __shfl(w, gbase | j);
            int   uj = __shfl(u, gbase | j);
            den += wj;
            acc = fmaf(wj, h[(size_t)uj * 32 + c], acc);
        }
    }
    float o = eluf(acc / (den + 1e-16f) + bias[c]);
    __builtin_nontemporal_store(o, &out[(size_t)v * 32 + c]);
}

// ---------------- fused mean-pool + MLP head ----------------
__global__ __launch_bounds__(256) void k_pool_head(
        const float* __restrict__ h, const int* __restrict__ batch, int N,
        const float* __restrict__ fw1, const float* __restrict__ fb1,
        const float* __restrict__ fw2, const float* __restrict__ fb2,
        const float* __restrict__ fw3, const float* __restrict__ fb3,
        float* __restrict__ out, int G) {
    int g = blockIdx.x;
    int tid = threadIdx.x;
    __shared__ int bounds[2];
    __shared__ float red[8][32];
    __shared__ float pooled[32];
    __shared__ float t1[64];
    __shared__ float t2[32];

    if (tid < 2) {
        int target = g + tid;
        int lo = 0, hi = N;
        while (lo < hi) {
            int mid = (lo + hi) >> 1;
            if (batch[mid] < target) lo = mid + 1; else hi = mid;
        }
        bounds[tid] = lo;
    }
    __syncthreads();
    int beg = bounds[0], end = bounds[1];

    int f = tid & 31, r = tid >> 5;
    float s = 0.f;
    for (int i = beg + r; i < end; i += 8) s += h[(size_t)i * 32 + f];
    red[r][f] = s;
    __syncthreads();

    if (tid < 32) {
        float t = 0.f;
#pragma unroll
        for (int k = 0; k < 8; ++k) t += red[k][tid];
        float invc = 1.f / fmaxf((float)(end - beg), 1.f);
        pooled[tid] = t * invc;
    }
    __syncthreads();

    if (tid < 64) {
        float a = fb1[tid];
#pragma unroll
        for (int k = 0; k < 32; ++k) a = fmaf(pooled[k], fw1[k * 64 + tid], a);
        t1[tid] = fmaxf(a, 0.f);
    }
    __syncthreads();
    if (tid < 32) {
        float a = fb2[tid];
#pragma unroll
        for (int k = 0; k < 64; ++k) a = fmaf(t1[k], fw2[k * 32 + tid], a);
        t2[tid] = fmaxf(a, 0.f);
    }
    __syncthreads();
    if (tid == 0) {
        float o = fb3[0];
#pragma unroll
        for (int k = 0; k < 32; ++k) o = fmaf(t2[k], fw3[k], o);
        out[g] = 1.f / (1.f + __expf(-o));
    }
}

// ---------------- host ----------------
extern "C" void kernel_launch(void* const* d_in, const int* in_sizes, int n_in,
                              void* d_out, int out_size, void* d_ws, size_t ws_size,
                              hipStream_t stream) {
    const float* x    = (const float*)d_in[0];
    const int*   ei   = (const int*)d_in[1];
    const int*   batch= (const int*)d_in[2];
    const float* w1   = (const float*)d_in[3];
    const float* as1  = (const float*)d_in[4];
    const float* ad1  = (const float*)d_in[5];
    const float* b1   = (const float*)d_in[6];
    const float* w2   = (const float*)d_in[7];
    const float* as2  = (const float*)d_in[8];
    const float* ad2  = (const float*)d_in[9];
    const float* b2   = (const float*)d_in[10];
    const float* w3   = (const float*)d_in[11];
    const float* as3  = (const float*)d_in[12];
    const float* ad3  = (const float*)d_in[13];
    const float* b3   = (const float*)d_in[14];
    const float* fw1  = (const float*)d_in[15];
    const float* fb1  = (const float*)d_in[16];
    const float* fw2  = (const float*)d_in[17];
    const float* fb2  = (const float*)d_in[18];
    const float* fw3  = (const float*)d_in[19];
    const float* fb3  = (const float*)d_in[20];
    float* outp = (float*)d_out;

    const int N = in_sizes[0] / 21;
    const int E = in_sizes[1] / 2;
    const int G = out_size;

    // ---- workspace carve ----
    char* p = (char*)d_ws;
    auto alloc = [&](size_t bytes) -> void* {
        void* r = (void*)p;
        p += (bytes + 255) & ~(size_t)255;
        return r;
    };
    int*   deg  = (int*)alloc((size_t)N * 4);
    int*   offs = (int*)alloc((size_t)(N + 1) * 4);
    int*   csr  = (int*)alloc((size_t)E * 4);
    unsigned short* rank = (unsigned short*)alloc((size_t)E * 2);
    int*   bsum = (int*)alloc((size_t)256 * 4);
    unsigned char*  h8  = (unsigned char*)alloc((size_t)N * 256);       // fp8 gather operand
    unsigned short* hbf = (unsigned short*)alloc((size_t)N * 256 * 2);  // bf16 gather output
    float* h3   = (float*)alloc((size_t)N * 32 * 4);
    float* hP   = (float*)alloc((size_t)N * 32 * 4);
    float* asb  = (float*)alloc((size_t)N * 4 * 4);
    float* adb  = (float*)alloc((size_t)N * 4 * 4);
    unsigned short* w2p = (unsigned short*)alloc((size_t)256 * 256 * 2);
    unsigned short* w3p = (unsigned short*)alloc((size_t)256 * 32 * 2);
    float* cw   = (float*)alloc((size_t)21 * 8 * 4);                    // L1 combined score weights

    const int* esrc = ei;
    const int* edst = ei + E;

    (void)hipMemsetAsync(deg, 0, (size_t)N * 4, stream);

    const int sb = (N + 1023) / 1024;          // scan blocks (<= 256)
    const int DB = (E + 1023) / 1024;          // deg blocks (4 edges/thread)
    const int SB = (E + 1023) / 1024;          // scatter blocks (4 edges/thread)

    // ---- CSR build: deg+rank+packs+cw, scan, atomic-free scatter ----
    k_deg_pack<<<DB + 256 + 32 + 1, 256, 0, stream>>>(edst, deg, rank, E, DB,
                                                      w2, w2p, w3, w3p, w1, as1, ad1, cw);
    k_scan1<<<sb, 1024, 0, stream>>>(deg, bsum, N);
    k_scan2<<<1, 256, 0, stream>>>(bsum, sb);
    k_scan3<<<sb, 1024, 0, stream>>>(deg, bsum, offs, N);
    k_scatter<<<SB, 256, 0, stream>>>(esrc, edst, rank, offs, csr, E);

    const int gblk = (N + 63) / 64;

    // ---- layer 1 ----
    k_gemm1<<<(N + 7) / 8, 256, 0, stream>>>(x, w1, cw, h8, asb, adb, N);
    k_gather256<<<(N + 3) / 4, 256, 0, stream>>>((const unsigned int*)h8, asb, adb, offs, csr, b1, hbf, N);

    // ---- layer 2 ----
    k_gemm2_mfma<<<gblk, 256, 0, stream>>>(hbf, w2p, as2, ad2, h8, asb, adb, N);
    k_gather256<<<(N + 3) / 4, 256, 0, stream>>>((const unsigned int*)h8, asb, adb, offs, csr, b2, hbf, N);

    // ---- layer 3 ----
    k_gemm3_mfma<<<gblk, 256, 0, stream>>>(hbf, w3p, as3, ad3, h3, asb, adb, N);
    k_gather32<<<(N + 7) / 8, 256, 0, stream>>>(h3, asb, adb, offs, csr, b3, hP, N);

    // ---- fused pool + head ----
    k_pool_head<<<G, 256, 0, stream>>>(hP, batch, N, fw1, fb1, fw2, fb2, fw3, fb3, outp, G);
}